// Round 4
// baseline (1674.365 us; speedup 1.0000x reference)
//
#include <hip/hip_runtime.h>
#include <hip/hip_bf16.h>
#include <math.h>

#define N_TOK   16384
#define D_IN    1024
#define D_MODEL 1024
#define HID     256
#define NEXP    10
#define D_OUT   1024

// Expert routing: pad each expert's list to a multiple of EPAD so every
// 128-row tile is single-expert. Static capacity => static grid (graph-safe).
#define EPAD 128
#define A_CAP (2*N_TOK + NEXP*EPAD)   // 34048 = 266 * 128

typedef __attribute__((ext_vector_type(8))) __bf16 bf16x8;
typedef __attribute__((ext_vector_type(4))) float floatx4;

// ---------------------------------------------------------------------------
// XCD-chunked block swizzle (bijective for any nwg): hardware dispatch
// round-robins linear block ids across the 8 XCDs; this remap gives XCD c a
// CONTIGUOUS chunk of logical tile ids, so the 8 col-blocks sharing an A
// row-tile all hit the same XCD's L2 (R6 counters: FETCH 290MB vs ~70MB ideal
// = 4.3x A over-fetch from cross-XCD dispatch).
// ---------------------------------------------------------------------------
__device__ __forceinline__ int xcd_chunk(int orig, int nwg)
{
    const int q = nwg >> 3, r = nwg & 7;
    const int c = orig & 7, j = orig >> 3;
    return (c < r ? c * (q + 1) : r * (q + 1) + (c - r) * q) + j;
}

// ---------------------------------------------------------------------------
// LDS tile layout (per 128x64-short tile): row = 128 bytes = 8 chunks of 16B.
// Chunk g of row r is stored at position g ^ (r&7); staging applies the inverse
// swizzle on the per-lane *global* source address, so the LDS store is simply
// rowgroup_base + lane*16B.
// ---------------------------------------------------------------------------
__device__ __forceinline__ bf16x8 lds_frag(const short* base, int row, int chunk)
{
    return *(const bf16x8*)(base + row * 64 + (chunk << 3));
}

// plain bf16: tile covers K-step 64 (chunks 0..7 = k 0..63)
__device__ __forceinline__ void tile_plain(const short* As, const short* Bs,
                                           int wm, int wn, int lane, floatx4 acc[4][4])
{
    const int m15 = lane & 15, quad = lane >> 4, sw = m15 & 7;
#pragma unroll
    for (int kk = 0; kk < 2; ++kk) {
        bf16x8 af[4], bfr[4];
#pragma unroll
        for (int i = 0; i < 4; ++i)
            af[i] = lds_frag(As, wm * 64 + i * 16 + m15, ((kk << 2) + quad) ^ sw);
#pragma unroll
        for (int j = 0; j < 4; ++j)
            bfr[j] = lds_frag(Bs, wn * 64 + j * 16 + m15, ((kk << 2) + quad) ^ sw);
#pragma unroll
        for (int i = 0; i < 4; ++i)
#pragma unroll
            for (int j = 0; j < 4; ++j)
                acc[i][j] = __builtin_amdgcn_mfma_f32_16x16x32_bf16(af[i], bfr[j],
                                                                    acc[i][j], 0, 0, 0);
    }
}

// split bf16: tile covers K-step 32; chunks 0..3 = hi plane, 4..7 = lo plane.
// acc += Ah*Bh + Ah*Bl + Al*Bh  (Al*Bl ~ 2^-18, dropped)
__device__ __forceinline__ void tile_split(const short* As, const short* Bs,
                                           int wm, int wn, int lane, floatx4 acc[4][4])
{
    const int m15 = lane & 15, quad = lane >> 4, sw = m15 & 7;
    bf16x8 ah[4], al[4], bh[4], bl[4];
#pragma unroll
    for (int i = 0; i < 4; ++i) {
        int r = wm * 64 + i * 16 + m15;
        ah[i] = lds_frag(As, r, quad ^ sw);
        al[i] = lds_frag(As, r, (4 + quad) ^ sw);
    }
#pragma unroll
    for (int j = 0; j < 4; ++j) {
        int r = wn * 64 + j * 16 + m15;
        bh[j] = lds_frag(Bs, r, quad ^ sw);
        bl[j] = lds_frag(Bs, r, (4 + quad) ^ sw);
    }
#pragma unroll
    for (int i = 0; i < 4; ++i)
#pragma unroll
        for (int j = 0; j < 4; ++j) {
            floatx4 c = acc[i][j];
            c = __builtin_amdgcn_mfma_f32_16x16x32_bf16(ah[i], bh[j], c, 0, 0, 0);
            c = __builtin_amdgcn_mfma_f32_16x16x32_bf16(ah[i], bl[j], c, 0, 0, 0);
            c = __builtin_amdgcn_mfma_f32_16x16x32_bf16(al[i], bh[j], c, 0, 0, 0);
            acc[i][j] = c;
        }
}

// ---------------------------------------------------------------------------
// Split-bf16 GEMM: C = A @ Bt^T + bias, inputs as hi/lo bf16 planes [M][K] and
// [N][K]; output hi (+ optional lo) bf16 planes. ~fp32 accuracy.
// R7: XCD-chunked swizzle + register prefetch of the next K-step (loads issued
// BEFORE tile compute so the vmcnt drain is covered by 48 MFMA + 16 ds_read).
// ---------------------------------------------------------------------------
__global__ __launch_bounds__(256, 4)
void gemm_split_kernel(const __hip_bfloat16* Ahi_, const __hip_bfloat16* Alo_,
                       const __hip_bfloat16* Bhi_, const __hip_bfloat16* Blo_,
                       const float* __restrict__ bias,
                       __hip_bfloat16* Chi_, __hip_bfloat16* Clo_, int K, int N)
{
    __shared__ __align__(16) short As[128 * 64];
    __shared__ __align__(16) short Bs[128 * 64];
    const short* Ahi = (const short*)Ahi_;
    const short* Alo = (const short*)Alo_;
    const short* Bhi = (const short*)Bhi_;
    const short* Blo = (const short*)Blo_;

    const int tid = threadIdx.x, lane = tid & 63, w = tid >> 6;
    const int wm = w & 1, wn = w >> 1;
    // logical tile from swizzled id: contiguous logical ids share a row-tile
    const int lin = blockIdx.y * gridDim.x + blockIdx.x;
    const int lgc = xcd_chunk(lin, gridDim.x * gridDim.y);
    const int row0 = (lgc / gridDim.x) * 128, col0 = (lgc % gridDim.x) * 128;
    const int lr = lane >> 3;
    const int g = (lane & 7) ^ lr;          // swizzled source chunk (const per lane)
    const int plane = g >> 2, colel = (g & 3) * 8;

    const short* pA[4];
    const short* pB[4];
#pragma unroll
    for (int i = 0; i < 4; ++i) {
        int r = w * 32 + i * 8 + lr;
        pA[i] = (plane ? Alo : Ahi) + (size_t)(row0 + r) * K + colel;
        pB[i] = (plane ? Blo : Bhi) + (size_t)(col0 + r) * K + colel;
    }

    floatx4 acc[4][4];
#pragma unroll
    for (int i = 0; i < 4; ++i)
#pragma unroll
        for (int j = 0; j < 4; ++j) acc[i][j] = (floatx4)(0.f);

    // prologue: prefetch K-step 0
    bf16x8 va[4], vb[4];
#pragma unroll
    for (int i = 0; i < 4; ++i) {
        va[i] = *(const bf16x8*)(pA[i]);
        vb[i] = *(const bf16x8*)(pB[i]);
    }

    for (int k0 = 0; k0 < K; k0 += 32) {
        __syncthreads();
#pragma unroll
        for (int i = 0; i < 4; ++i) {
            *(bf16x8*)(&As[(w * 32 + i * 8) * 64 + lane * 8]) = va[i];
            *(bf16x8*)(&Bs[(w * 32 + i * 8) * 64 + lane * 8]) = vb[i];
        }
        __syncthreads();
        if (k0 + 32 < K) {
#pragma unroll
            for (int i = 0; i < 4; ++i) {
                va[i] = *(const bf16x8*)(pA[i] + k0 + 32);
                vb[i] = *(const bf16x8*)(pB[i] + k0 + 32);
            }
        }
        tile_split(As, Bs, wm, wn, lane, acc);
    }

    const int m15 = lane & 15, quad = lane >> 4;
#pragma unroll
    for (int i = 0; i < 4; ++i) {
#pragma unroll
        for (int t = 0; t < 4; ++t) {
            int row = row0 + wm * 64 + i * 16 + quad * 4 + t;
            size_t rb = (size_t)row * N;
#pragma unroll
            for (int j = 0; j < 4; ++j) {
                int col = col0 + wn * 64 + j * 16 + m15;
                float v = acc[i][j][t] + bias[col];
                __hip_bfloat16 hi = __float2bfloat16(v);
                Chi_[rb + col] = hi;
                if (Clo_) Clo_[rb + col] = __float2bfloat16(v - __bfloat162float(hi));
            }
        }
    }
}

// ---------------------------------------------------------------------------
// Expert layer 1: hid[slot] = relu(a[token(slot)] @ W1t[e]^T + b1[e])
// R7: swizzle + prefetch (same rationale as gemm_split).
// ---------------------------------------------------------------------------
__global__ __launch_bounds__(256, 4)
void expert1_kernel(const __hip_bfloat16* a_, const __hip_bfloat16* W1t_,
                    const float* __restrict__ b1,
                    const int* __restrict__ assign_token, const int* __restrict__ offs,
                    const __hip_bfloat16* zrow_, __hip_bfloat16* hid_)
{
    __shared__ __align__(16) short As[128 * 64];
    __shared__ __align__(16) short Bs[128 * 64];
    const short* A = (const short*)a_;
    const short* zrow = (const short*)zrow_;

    const int tid = threadIdx.x, lane = tid & 63, w = tid >> 6;
    const int wm = w & 1, wn = w >> 1;
    const int lin = blockIdx.y * gridDim.x + blockIdx.x;
    const int lgc = xcd_chunk(lin, gridDim.x * gridDim.y);
    const int row0 = (lgc / gridDim.x) * 128, col0 = (lgc % gridDim.x) * 128;
    const int lr = lane >> 3, g = (lane & 7) ^ lr, colel = g * 8;

    int e = NEXP - 1;
    for (int q = 0; q < NEXP; ++q) { if (row0 < offs[q + 1]) { e = q; break; } }
    const short* B = (const short*)W1t_ + (size_t)e * HID * D_MODEL;

    const short* pA[4];
    const short* pB[4];
#pragma unroll
    for (int i = 0; i < 4; ++i) {
        int r = w * 32 + i * 8 + lr;
        int tok = assign_token[row0 + r];
        pA[i] = (tok >= 0 ? A + (size_t)tok * D_MODEL : zrow) + colel;
        pB[i] = B + (size_t)(col0 + r) * D_MODEL + colel;
    }

    floatx4 acc[4][4];
#pragma unroll
    for (int i = 0; i < 4; ++i)
#pragma unroll
        for (int j = 0; j < 4; ++j) acc[i][j] = (floatx4)(0.f);

    bf16x8 va[4], vb[4];
#pragma unroll
    for (int i = 0; i < 4; ++i) {
        va[i] = *(const bf16x8*)(pA[i]);
        vb[i] = *(const bf16x8*)(pB[i]);
    }

    for (int k0 = 0; k0 < D_MODEL; k0 += 64) {
        __syncthreads();
#pragma unroll
        for (int i = 0; i < 4; ++i) {
            *(bf16x8*)(&As[(w * 32 + i * 8) * 64 + lane * 8]) = va[i];
            *(bf16x8*)(&Bs[(w * 32 + i * 8) * 64 + lane * 8]) = vb[i];
        }
        __syncthreads();
        if (k0 + 64 < D_MODEL) {
#pragma unroll
            for (int i = 0; i < 4; ++i) {
                va[i] = *(const bf16x8*)(pA[i] + k0 + 64);
                vb[i] = *(const bf16x8*)(pB[i] + k0 + 64);
            }
        }
        tile_plain(As, Bs, wm, wn, lane, acc);
    }

    const int m15 = lane & 15, quad = lane >> 4;
#pragma unroll
    for (int i = 0; i < 4; ++i) {
#pragma unroll
        for (int t = 0; t < 4; ++t) {
            int row = row0 + wm * 64 + i * 16 + quad * 4 + t;
            size_t rb = (size_t)row * HID;
#pragma unroll
            for (int j = 0; j < 4; ++j) {
                int col = col0 + wn * 64 + j * 16 + m15;
                float v = acc[i][j][t] + b1[(size_t)e * HID + col];
                hid_[rb + col] = __float2bfloat16(fmaxf(v, 0.f));
            }
        }
    }
}

// ---------------------------------------------------------------------------
// Expert layer 2: exp_out[slot] = hid[slot] @ W2t[e]^T
// R7: swizzle + prefetch.
// ---------------------------------------------------------------------------
__global__ __launch_bounds__(256, 4)
void expert2_kernel(const __hip_bfloat16* hid_, const __hip_bfloat16* W2t_,
                    const int* __restrict__ offs, __hip_bfloat16* exp_out_)
{
    __shared__ __align__(16) short As[128 * 64];
    __shared__ __align__(16) short Bs[128 * 64];
    const short* A = (const short*)hid_;

    const int tid = threadIdx.x, lane = tid & 63, w = tid >> 6;
    const int wm = w & 1, wn = w >> 1;
    const int lin = blockIdx.y * gridDim.x + blockIdx.x;
    const int lgc = xcd_chunk(lin, gridDim.x * gridDim.y);
    const int row0 = (lgc / gridDim.x) * 128, col0 = (lgc % gridDim.x) * 128;
    const int lr = lane >> 3, g = (lane & 7) ^ lr, colel = g * 8;

    int e = NEXP - 1;
    for (int q = 0; q < NEXP; ++q) { if (row0 < offs[q + 1]) { e = q; break; } }
    const short* B = (const short*)W2t_ + (size_t)e * D_OUT * HID;

    const short* pA[4];
    const short* pB[4];
#pragma unroll
    for (int i = 0; i < 4; ++i) {
        int r = w * 32 + i * 8 + lr;
        pA[i] = A + (size_t)(row0 + r) * HID + colel;
        pB[i] = B + (size_t)(col0 + r) * HID + colel;
    }

    floatx4 acc[4][4];
#pragma unroll
    for (int i = 0; i < 4; ++i)
#pragma unroll
        for (int j = 0; j < 4; ++j) acc[i][j] = (floatx4)(0.f);

    bf16x8 va[4], vb[4];
#pragma unroll
    for (int i = 0; i < 4; ++i) {
        va[i] = *(const bf16x8*)(pA[i]);
        vb[i] = *(const bf16x8*)(pB[i]);
    }

    for (int k0 = 0; k0 < HID; k0 += 64) {
        __syncthreads();
#pragma unroll
        for (int i = 0; i < 4; ++i) {
            *(bf16x8*)(&As[(w * 32 + i * 8) * 64 + lane * 8]) = va[i];
            *(bf16x8*)(&Bs[(w * 32 + i * 8) * 64 + lane * 8]) = vb[i];
        }
        __syncthreads();
        if (k0 + 64 < HID) {
#pragma unroll
            for (int i = 0; i < 4; ++i) {
                va[i] = *(const bf16x8*)(pA[i] + k0 + 64);
                vb[i] = *(const bf16x8*)(pB[i] + k0 + 64);
            }
        }
        tile_plain(As, Bs, wm, wn, lane, acc);
    }

    const int m15 = lane & 15, quad = lane >> 4;
#pragma unroll
    for (int i = 0; i < 4; ++i) {
#pragma unroll
        for (int t = 0; t < 4; ++t) {
            int row = row0 + wm * 64 + i * 16 + quad * 4 + t;
            size_t rb = (size_t)row * D_OUT;
#pragma unroll
            for (int j = 0; j < 4; ++j) {
                int col = col0 + wn * 64 + j * 16 + m15;
                exp_out_[rb + col] = __float2bfloat16(acc[i][j][t]);
            }
        }
    }
}

// ---------------------------------------------------------------------------
// FUSED x-convert + gate (R6, atomic-free; confirmed: removing the 32768
// same-line counts atomics collapsed this kernel from 383us out of the top-5).
// One token per wave; pure streaming + L2-resident MgT dot + top-2 route.
// ---------------------------------------------------------------------------
__global__ __launch_bounds__(256)
void convert_gate_kernel(const float* __restrict__ x, const float* __restrict__ MgT,
                         const float* __restrict__ bgeff,
                         __hip_bfloat16* __restrict__ x_hi, __hip_bfloat16* __restrict__ x_lo,
                         int* __restrict__ route_e, float* __restrict__ route_w)
{
    const int wave = threadIdx.x >> 6, lane = threadIdx.x & 63;
    const int n = blockIdx.x * 4 + wave;
    const float* xrow = x + (size_t)n * D_IN;

    float4 v[4];
#pragma unroll
    for (int it = 0; it < 4; ++it)
        v[it] = *(const float4*)(xrow + it * 256 + lane * 4);

    float p[NEXP];
#pragma unroll
    for (int e = 0; e < NEXP; ++e) p[e] = 0.f;

#pragma unroll
    for (int it = 0; it < 4; ++it) {
        const int d = it * 256 + lane * 4;
        union { __hip_bfloat16 b[4]; short4 s; } uh, ul;
        uh.b[0] = __float2bfloat16(v[it].x); ul.b[0] = __float2bfloat16(v[it].x - __bfloat162float(uh.b[0]));
        uh.b[1] = __float2bfloat16(v[it].y); ul.b[1] = __float2bfloat16(v[it].y - __bfloat162float(uh.b[1]));
        uh.b[2] = __float2bfloat16(v[it].z); ul.b[2] = __float2bfloat16(v[it].z - __bfloat162float(uh.b[2]));
        uh.b[3] = __float2bfloat16(v[it].w); ul.b[3] = __float2bfloat16(v[it].w - __bfloat162float(uh.b[3]));
        *(short4*)(x_hi + (size_t)n * D_IN + d) = uh.s;
        *(short4*)(x_lo + (size_t)n * D_IN + d) = ul.s;
#pragma unroll
        for (int e = 0; e < NEXP; ++e) {
            const float4 m = *(const float4*)(MgT + (size_t)e * 1024 + d);
            p[e] += v[it].x * m.x + v[it].y * m.y + v[it].z * m.z + v[it].w * m.w;
        }
    }

#pragma unroll
    for (int e = 0; e < NEXP; ++e) {
        float t = p[e];
        for (int off = 32; off > 0; off >>= 1) t += __shfl_down(t, off);
        p[e] = t;
    }
    if (lane == 0) {
        float lg[NEXP];
#pragma unroll
        for (int e = 0; e < NEXP; ++e) lg[e] = p[e] + bgeff[e];
        int e0 = 0; float v0 = lg[0];
        for (int e = 1; e < NEXP; ++e) if (lg[e] > v0) { v0 = lg[e]; e0 = e; }
        int e1 = -1; float v1 = -3.0e38f;
        for (int e = 0; e < NEXP; ++e) {
            if (e == e0) continue;
            if (lg[e] > v1) { v1 = lg[e]; e1 = e; }
        }
        float w0 = 1.f / (1.f + expf(v1 - v0));   // softmax + top-2 renorm
        float w1 = 1.f - w0;
        route_e[n * 2]     = e0;
        route_e[n * 2 + 1] = e1;
        route_w[n * 2]     = w0;
        route_w[n * 2 + 1] = w1;
    }
}

// ---------------------------------------------------------------------------
// Histogram of route_e into counts[NEXP]: per-block LDS histogram, then 10
// global atomics per block (64 blocks -> 640 global atomics total).
// ---------------------------------------------------------------------------
__global__ __launch_bounds__(256)
void count_kernel(const int* __restrict__ route_e, int* __restrict__ counts)
{
    __shared__ int h[NEXP];
    if (threadIdx.x < NEXP) h[threadIdx.x] = 0;
    __syncthreads();
    const int i = blockIdx.x * 512 + threadIdx.x;   // 64 blocks * 512 = 32768
    atomicAdd(&h[route_e[i]], 1);
    atomicAdd(&h[route_e[i + 256]], 1);
    __syncthreads();
    if (threadIdx.x < NEXP) atomicAdd(&counts[threadIdx.x], h[threadIdx.x]);
}

// ---------------------------------------------------------------------------
// fp32 [R][C] -> transposed bf16 [C][R] hi (+ optional lo); batched over z.
// ---------------------------------------------------------------------------
__global__ __launch_bounds__(256)
void transpose_cvt_kernel(const float* __restrict__ in, __hip_bfloat16* out_hi,
                          __hip_bfloat16* out_lo, int R, int C)
{
    __shared__ float t[32][33];
    const size_t zoff = (size_t)blockIdx.z * R * C;
    in += zoff; out_hi += zoff; if (out_lo) out_lo += zoff;
    const int c0 = blockIdx.x * 32, r0 = blockIdx.y * 32;
    const int tx = threadIdx.x & 31, ty = threadIdx.x >> 5;
#pragma unroll
    for (int i = 0; i < 4; ++i)
        t[ty + i * 8][tx] = in[(size_t)(r0 + ty + i * 8) * C + (c0 + tx)];
    __syncthreads();
#pragma unroll
    for (int i = 0; i < 4; ++i) {
        float v = t[tx][ty + i * 8];
        size_t o = (size_t)(c0 + ty + i * 8) * R + (r0 + tx);
        __hip_bfloat16 hi = __float2bfloat16(v);
        out_hi[o] = hi;
        if (out_lo) out_lo[o] = __float2bfloat16(v - __bfloat162float(hi));
    }
}

// ---------------------------------------------------------------------------
// Thin fp32 GEMM for gate-matrix chain: Cm = A[1024][1024] @ B[1024][10];
// trans=0 -> Cm[m][10]; trans=1 -> Cm[e][1024] (transposed write for MgT).
// ---------------------------------------------------------------------------
__global__ __launch_bounds__(256)
void wchain_kernel(const float* __restrict__ A, const float* __restrict__ B,
                   float* __restrict__ Cm, int trans)
{
    const int wave = threadIdx.x >> 6, lane = threadIdx.x & 63;
    const int m = blockIdx.x * 4 + wave;
    float acc[NEXP];
#pragma unroll
    for (int e = 0; e < NEXP; ++e) acc[e] = 0.f;
    const float* ar = A + (size_t)m * 1024;
    for (int d = lane; d < 1024; d += 64) {
        float av = ar[d];
        const float* br = B + (size_t)d * NEXP;
#pragma unroll
        for (int e = 0; e < NEXP; ++e) acc[e] += av * br[e];
    }
#pragma unroll
    for (int e = 0; e < NEXP; ++e) {
        float v = acc[e];
        for (int off = 32; off > 0; off >>= 1) v += __shfl_down(v, off);
        if (lane == 0) Cm[trans ? ((size_t)e * 1024 + m) : ((size_t)m * NEXP + e)] = v;
    }
}

// ---------------------------------------------------------------------------
// bg_eff = bg + bo@Wg + bv@t1 + bp@t2    (single block)
// ---------------------------------------------------------------------------
__global__ __launch_bounds__(256)
void bias_eff_kernel(const float* __restrict__ bp, const float* __restrict__ bv,
                     const float* __restrict__ bo, const float* __restrict__ bg,
                     const float* __restrict__ Wg, const float* __restrict__ t1,
                     const float* __restrict__ t2, float* __restrict__ bgeff)
{
    __shared__ float red[256];
    const int tid = threadIdx.x;
    float acc[NEXP];
#pragma unroll
    for (int e = 0; e < NEXP; ++e) acc[e] = 0.f;
    for (int d = tid; d < 1024; d += 256) {
        float o = bo[d], v = bv[d], p = bp[d];
#pragma unroll
        for (int e = 0; e < NEXP; ++e)
            acc[e] += o * Wg[d * NEXP + e] + v * t1[d * NEXP + e] + p * t2[d * NEXP + e];
    }
    for (int e = 0; e < NEXP; ++e) {
        red[tid] = acc[e];
        __syncthreads();
        for (int s = 128; s > 0; s >>= 1) {
            if (tid < s) red[tid] += red[tid + s];
            __syncthreads();
        }
        if (tid == 0) bgeff[e] = red[0] + bg[e];
        __syncthreads();
    }
}

// ---------------------------------------------------------------------------
__global__ __launch_bounds__(256)
void init_kernel(int* __restrict__ counts, int* __restrict__ cursors,
                 int* __restrict__ assign_token, int* __restrict__ zrow_i)
{
    int i = blockIdx.x * 256 + threadIdx.x;
    if (i < NEXP) { counts[i] = 0; cursors[i] = 0; }
    if (i < 512) zrow_i[i] = 0;                 // 1024 bf16 zeros
    if (i < A_CAP) assign_token[i] = -1;
}

__global__ void offsets_kernel(const int* __restrict__ counts, int* __restrict__ offs)
{
    if (threadIdx.x == 0 && blockIdx.x == 0) {
        int acc = 0;
        for (int e = 0; e < NEXP; ++e) {
            offs[e] = acc;
            acc += (counts[e] + EPAD - 1) / EPAD * EPAD;
        }
        offs[NEXP] = acc;
    }
}

// ---------------------------------------------------------------------------
// Scatter with WAVE-AGGREGATED cursor atomics (R6): <=10 atomics/wave via
// ballot+popcount vs 32768 contended return-value atomics before.
// ---------------------------------------------------------------------------
__global__ __launch_bounds__(256)
void scatter_kernel(const int* __restrict__ route_e,
                    const int* __restrict__ offs, int* __restrict__ cursors,
                    int* __restrict__ assign_token, int* __restrict__ slot_of)
{
    const int i = blockIdx.x * 256 + threadIdx.x;
    const int lane = threadIdx.x & 63;
    const int e = route_e[i];
    int slot = 0;
#pragma unroll
    for (int q = 0; q < NEXP; ++q) {
        unsigned long long mask = __ballot(e == q);
        if (e == q) {
            const int leader = (int)__ffsll((long long)mask) - 1;
            const int rank = (int)__popcll(mask & ((1ull << lane) - 1ull));
            int base = 0;
            if (lane == leader) base = atomicAdd(&cursors[q], (int)__popcll(mask));
            base = __shfl(base, leader);
            slot = offs[q] + base + rank;
        }
    }
    assign_token[slot] = i >> 1;
    slot_of[i] = slot;
}

// ---------------------------------------------------------------------------
// Combine (gather): out[n] = w0*(row(s0)+b2[e0]) + w1*(row(s1)+b2[e1])
// ---------------------------------------------------------------------------
__global__ __launch_bounds__(256)
void combine_kernel(const __hip_bfloat16* __restrict__ exp_out,
                    const int* __restrict__ slot_of, const int* __restrict__ route_e,
                    const float* __restrict__ route_w, const float* __restrict__ b2,
                    float* __restrict__ out)
{
    const int n = blockIdx.x;
    const int c = threadIdx.x * 4;
    const int s0 = slot_of[n * 2],  s1 = slot_of[n * 2 + 1];
    const int e0 = route_e[n * 2],  e1 = route_e[n * 2 + 1];
    const float w0 = route_w[n * 2], w1 = route_w[n * 2 + 1];

    union U { float2 f2; __hip_bfloat16 b[4]; } u0, u1;
    u0.f2 = *(const float2*)(exp_out + (size_t)s0 * D_OUT + c);
    u1.f2 = *(const float2*)(exp_out + (size_t)s1 * D_OUT + c);
    const float4 bb0 = *(const float4*)(b2 + (size_t)e0 * D_OUT + c);
    const float4 bb1 = *(const float4*)(b2 + (size_t)e1 * D_OUT + c);

    float4 o;
    o.x = w0 * (__bfloat162float(u0.b[0]) + bb0.x) + w1 * (__bfloat162float(u1.b[0]) + bb1.x);
    o.y = w0 * (__bfloat162float(u0.b[1]) + bb0.y) + w1 * (__bfloat162float(u1.b[1]) + bb1.y);
    o.z = w0 * (__bfloat162float(u0.b[2]) + bb0.z) + w1 * (__bfloat162float(u1.b[2]) + bb1.z);
    o.w = w0 * (__bfloat162float(u0.b[3]) + bb0.w) + w1 * (__bfloat162float(u1.b[3]) + bb1.w);
    *(float4*)(out + (size_t)n * D_OUT + c) = o;
}

// ---------------------------------------------------------------------------
extern "C" void kernel_launch(void* const* d_in, const int* in_sizes, int n_in,
                              void* d_out, int out_size, void* d_ws, size_t ws_size,
                              hipStream_t stream)
{
    const float* x  = (const float*)d_in[0];
    const float* Wp = (const float*)d_in[2];
    const float* bp = (const float*)d_in[3];
    const float* Wv = (const float*)d_in[4];
    const float* bv = (const float*)d_in[5];
    const float* Wo = (const float*)d_in[6];
    const float* bo = (const float*)d_in[7];
    const float* Wg = (const float*)d_in[8];
    const float* bg = (const float*)d_in[9];
    const float* W1 = (const float*)d_in[10];
    const float* b1 = (const float*)d_in[11];
    const float* W2 = (const float*)d_in[12];
    const float* b2 = (const float*)d_in[13];
    float* out = (float*)d_out;

    // ---- workspace layout (bytes); lifetime-based aliasing, total ~150.6 MiB ----
    char* W = (char*)d_ws;
    typedef __hip_bfloat16 bf;
    bf* x_hi  = (bf*)(W + 0);                  // [N,D]  dead after gemm1
    bf* x_lo  = (bf*)(W + 33554432);           //        dead after gemm1
    bf* h_hi  = (bf*)(W + 67108864);           // dead after gemm2
    bf* h_lo  = (bf*)(W + 100663296);          // dead after gemm2
    bf* hv_hi = (bf*)(W + 0);                  // aliases x (dead) ; dead after gemm3
    bf* hv_lo = (bf*)(W + 33554432);
    bf* a_bf  = (bf*)(W + 100663296);          // aliases h_lo (dead); read by expert1
    bf* exp_out = (bf*)(W + 0);                // [A_CAP,D_OUT] 69.7MB; hv dead by then
    bf* hid   = (bf*)(W + 69730304);           // [A_CAP,HID] in dead h_hi region
    // weights (alive whole run)
    bf* Wpt_hi = (bf*)(W + 134217728);
    bf* Wpt_lo = (bf*)(W + 136314880);
    bf* Wvt_hi = (bf*)(W + 138412032);
    bf* Wvt_lo = (bf*)(W + 140509184);
    bf* Wot_hi = (bf*)(W + 142606336);
    bf* Wot_lo = (bf*)(W + 144703488);
    bf* W1t    = (bf*)(W + 146800640);         // [E][HID][D]
    bf* W2t    = (bf*)(W + 152043520);         // [E][D_OUT][HID]
    // small buffers
    bf*    zrow         = (bf*)(W + 157286400);       // 1024 bf16 zeros
    int*   route_e      = (int*)(W + 157288448);
    float* route_w      = (float*)(W + 157419520);
    int*   slot_of      = (int*)(W + 157550592);
    int*   assign_token = (int*)(W + 157681664);
    int*   counts       = (int*)(W + 157817856);
    int*   offs         = (int*)(W + 157817920);
    int*   cursors      = (int*)(W + 157817984);
    float* MgT          = (float*)(W + 157818048);    // [10][1024] transposed
    float* t1           = (float*)(W + 157859008);
    float* t2           = (float*)(W + 157899968);
    float* bgeff        = (float*)(W + 157940928);

    dim3 blk(256);

    // ---- weight conversions ----
    transpose_cvt_kernel<<<dim3(32, 32, 1), blk, 0, stream>>>(Wp, Wpt_hi, Wpt_lo, D_IN, D_MODEL);
    transpose_cvt_kernel<<<dim3(32, 32, 1), blk, 0, stream>>>(Wv, Wvt_hi, Wvt_lo, D_MODEL, D_MODEL);
    transpose_cvt_kernel<<<dim3(32, 32, 1), blk, 0, stream>>>(Wo, Wot_hi, Wot_lo, D_MODEL, D_MODEL);
    transpose_cvt_kernel<<<dim3(HID / 32, D_MODEL / 32, NEXP), blk, 0, stream>>>(W1, W1t, nullptr, D_MODEL, HID);
    transpose_cvt_kernel<<<dim3(D_OUT / 32, HID / 32, NEXP), blk, 0, stream>>>(W2, W2t, nullptr, HID, D_OUT);

    // ---- gate matrix chain (fp32, exactness-preserving associativity) ----
    wchain_kernel<<<256, blk, 0, stream>>>(Wo, Wg, t1, 0);   // t1 = Wo@Wg
    wchain_kernel<<<256, blk, 0, stream>>>(Wv, t1, t2, 0);   // t2 = Wv@t1
    wchain_kernel<<<256, blk, 0, stream>>>(Wp, t2, MgT, 1);  // MgT = (Wp@t2)^T
    bias_eff_kernel<<<1, blk, 0, stream>>>(bp, bv, bo, bg, Wg, t1, t2, bgeff);

    // ---- routing init + fused convert/gate (atomic-free) + count + scatter ----
    init_kernel<<<(A_CAP + 255) / 256, blk, 0, stream>>>(counts, cursors, assign_token,
                                                         (int*)zrow);
    convert_gate_kernel<<<N_TOK / 4, blk, 0, stream>>>(x, MgT, bgeff, x_hi, x_lo,
                                                       route_e, route_w);
    count_kernel<<<2 * N_TOK / 512, blk, 0, stream>>>(route_e, counts);
    offsets_kernel<<<1, 64, 0, stream>>>(counts, offs);
    scatter_kernel<<<2 * N_TOK / 256, blk, 0, stream>>>(route_e, offs, cursors,
                                                        assign_token, slot_of);

    // ---- main chain: split-bf16 MFMA (~fp32 accuracy) ----
    dim3 cgrid(D_MODEL / 128, N_TOK / 128);   // (8, 128)
    gemm_split_kernel<<<cgrid, blk, 0, stream>>>(x_hi, x_lo, Wpt_hi, Wpt_lo, bp,
                                                 h_hi, h_lo, D_IN, D_MODEL);
    gemm_split_kernel<<<cgrid, blk, 0, stream>>>(h_hi, h_lo, Wvt_hi, Wvt_lo, bv,
                                                 hv_hi, hv_lo, D_MODEL, D_MODEL);
    gemm_split_kernel<<<cgrid, blk, 0, stream>>>(hv_hi, hv_lo, Wot_hi, Wot_lo, bo,
                                                 a_bf, nullptr, D_MODEL, D_MODEL);

    // ---- experts: plain bf16 MFMA, grouped by expert ----
    expert1_kernel<<<dim3(HID / 128, A_CAP / 128), blk, 0, stream>>>(
        a_bf, W1t, b1, assign_token, offs, zrow, hid);
    expert2_kernel<<<dim3(D_OUT / 128, A_CAP / 128), blk, 0, stream>>>(
        hid, W2t, offs, exp_out);
    combine_kernel<<<N_TOK, blk, 0, stream>>>(exp_out, slot_of, route_e, route_w, b2, out);
}

// Round 5
// 683.741 us; speedup vs baseline: 2.4488x; 2.4488x over previous
//
#include <hip/hip_runtime.h>
#include <hip/hip_bf16.h>
#include <math.h>

#define N_TOK   16384
#define D_IN    1024
#define D_MODEL 1024
#define HID     256
#define NEXP    10
#define D_OUT   1024

// Expert routing: pad each expert's list to a multiple of EPAD so every
// 128-row tile is single-expert. Static capacity => static grid (graph-safe).
#define EPAD 128
#define A_CAP (2*N_TOK + NEXP*EPAD)   // 34048 = 266 * 128

typedef __attribute__((ext_vector_type(8))) __bf16 bf16x8;
typedef __attribute__((ext_vector_type(4))) float floatx4;

// ---------------------------------------------------------------------------
// XCD-chunked block swizzle (bijective for any nwg): hardware dispatch
// round-robins linear block ids across the 8 XCDs; this remap gives XCD c a
// CONTIGUOUS chunk of logical tile ids, so the 8 col-blocks sharing an A
// row-tile all hit the same XCD's L2 (R6 counters: FETCH 290MB vs ~70MB ideal
// = 4.3x A over-fetch from cross-XCD dispatch).
// ---------------------------------------------------------------------------
__device__ __forceinline__ int xcd_chunk(int orig, int nwg)
{
    const int q = nwg >> 3, r = nwg & 7;
    const int c = orig & 7, j = orig >> 3;
    return (c < r ? c * (q + 1) : r * (q + 1) + (c - r) * q) + j;
}

// ---------------------------------------------------------------------------
// LDS tile layout (per 128x64-short tile): row = 128 bytes = 8 chunks of 16B.
// Chunk g of row r is stored at position g ^ (r&7); staging applies the inverse
// swizzle on the per-lane *global* source address, so the LDS store is simply
// rowgroup_base + lane*16B.
// ---------------------------------------------------------------------------
__device__ __forceinline__ bf16x8 lds_frag(const short* base, int row, int chunk)
{
    return *(const bf16x8*)(base + row * 64 + (chunk << 3));
}

// plain bf16: tile covers K-step 64 (chunks 0..7 = k 0..63)
__device__ __forceinline__ void tile_plain(const short* As, const short* Bs,
                                           int wm, int wn, int lane, floatx4 acc[4][4])
{
    const int m15 = lane & 15, quad = lane >> 4, sw = m15 & 7;
#pragma unroll
    for (int kk = 0; kk < 2; ++kk) {
        bf16x8 af[4], bfr[4];
#pragma unroll
        for (int i = 0; i < 4; ++i)
            af[i] = lds_frag(As, wm * 64 + i * 16 + m15, ((kk << 2) + quad) ^ sw);
#pragma unroll
        for (int j = 0; j < 4; ++j)
            bfr[j] = lds_frag(Bs, wn * 64 + j * 16 + m15, ((kk << 2) + quad) ^ sw);
#pragma unroll
        for (int i = 0; i < 4; ++i)
#pragma unroll
            for (int j = 0; j < 4; ++j)
                acc[i][j] = __builtin_amdgcn_mfma_f32_16x16x32_bf16(af[i], bfr[j],
                                                                    acc[i][j], 0, 0, 0);
    }
}

// split bf16: tile covers K-step 32; chunks 0..3 = hi plane, 4..7 = lo plane.
// acc += Ah*Bh + Ah*Bl + Al*Bh  (Al*Bl ~ 2^-18, dropped)
__device__ __forceinline__ void tile_split(const short* As, const short* Bs,
                                           int wm, int wn, int lane, floatx4 acc[4][4])
{
    const int m15 = lane & 15, quad = lane >> 4, sw = m15 & 7;
    bf16x8 ah[4], al[4], bh[4], bl[4];
#pragma unroll
    for (int i = 0; i < 4; ++i) {
        int r = wm * 64 + i * 16 + m15;
        ah[i] = lds_frag(As, r, quad ^ sw);
        al[i] = lds_frag(As, r, (4 + quad) ^ sw);
    }
#pragma unroll
    for (int j = 0; j < 4; ++j) {
        int r = wn * 64 + j * 16 + m15;
        bh[j] = lds_frag(Bs, r, quad ^ sw);
        bl[j] = lds_frag(Bs, r, (4 + quad) ^ sw);
    }
#pragma unroll
    for (int i = 0; i < 4; ++i)
#pragma unroll
        for (int j = 0; j < 4; ++j) {
            floatx4 c = acc[i][j];
            c = __builtin_amdgcn_mfma_f32_16x16x32_bf16(ah[i], bh[j], c, 0, 0, 0);
            c = __builtin_amdgcn_mfma_f32_16x16x32_bf16(ah[i], bl[j], c, 0, 0, 0);
            c = __builtin_amdgcn_mfma_f32_16x16x32_bf16(al[i], bh[j], c, 0, 0, 0);
            acc[i][j] = c;
        }
}

// ---------------------------------------------------------------------------
// Split-bf16 GEMM: C = A @ Bt^T + bias, inputs as hi/lo bf16 planes [M][K] and
// [N][K]; output hi (+ optional lo) bf16 planes. ~fp32 accuracy.
// R8: swizzle + prefetch kept from R7; __launch_bounds__ min-waves REMOVED.
// R7's (256,4) capped VGPR at 128 < the ~130-150 the prefetch schedule needs
// -> acc spilled to scratch (VGPR 64, WRITE_SIZE 65MB->1.24GB, MfmaUtil 9%).
// ---------------------------------------------------------------------------
__global__ __launch_bounds__(256)
void gemm_split_kernel(const __hip_bfloat16* Ahi_, const __hip_bfloat16* Alo_,
                       const __hip_bfloat16* Bhi_, const __hip_bfloat16* Blo_,
                       const float* __restrict__ bias,
                       __hip_bfloat16* Chi_, __hip_bfloat16* Clo_, int K, int N)
{
    __shared__ __align__(16) short As[128 * 64];
    __shared__ __align__(16) short Bs[128 * 64];
    const short* Ahi = (const short*)Ahi_;
    const short* Alo = (const short*)Alo_;
    const short* Bhi = (const short*)Bhi_;
    const short* Blo = (const short*)Blo_;

    const int tid = threadIdx.x, lane = tid & 63, w = tid >> 6;
    const int wm = w & 1, wn = w >> 1;
    // logical tile from swizzled id: contiguous logical ids share a row-tile
    const int lin = blockIdx.y * gridDim.x + blockIdx.x;
    const int lgc = xcd_chunk(lin, gridDim.x * gridDim.y);
    const int row0 = (lgc / gridDim.x) * 128, col0 = (lgc % gridDim.x) * 128;
    const int lr = lane >> 3;
    const int g = (lane & 7) ^ lr;          // swizzled source chunk (const per lane)
    const int plane = g >> 2, colel = (g & 3) * 8;

    const short* pA[4];
    const short* pB[4];
#pragma unroll
    for (int i = 0; i < 4; ++i) {
        int r = w * 32 + i * 8 + lr;
        pA[i] = (plane ? Alo : Ahi) + (size_t)(row0 + r) * K + colel;
        pB[i] = (plane ? Blo : Bhi) + (size_t)(col0 + r) * K + colel;
    }

    floatx4 acc[4][4];
#pragma unroll
    for (int i = 0; i < 4; ++i)
#pragma unroll
        for (int j = 0; j < 4; ++j) acc[i][j] = (floatx4)(0.f);

    // prologue: prefetch K-step 0
    bf16x8 va[4], vb[4];
#pragma unroll
    for (int i = 0; i < 4; ++i) {
        va[i] = *(const bf16x8*)(pA[i]);
        vb[i] = *(const bf16x8*)(pB[i]);
    }

    for (int k0 = 0; k0 < K; k0 += 32) {
        __syncthreads();
#pragma unroll
        for (int i = 0; i < 4; ++i) {
            *(bf16x8*)(&As[(w * 32 + i * 8) * 64 + lane * 8]) = va[i];
            *(bf16x8*)(&Bs[(w * 32 + i * 8) * 64 + lane * 8]) = vb[i];
        }
        __syncthreads();
        if (k0 + 32 < K) {
#pragma unroll
            for (int i = 0; i < 4; ++i) {
                va[i] = *(const bf16x8*)(pA[i] + k0 + 32);
                vb[i] = *(const bf16x8*)(pB[i] + k0 + 32);
            }
        }
        tile_split(As, Bs, wm, wn, lane, acc);
    }

    const int m15 = lane & 15, quad = lane >> 4;
#pragma unroll
    for (int i = 0; i < 4; ++i) {
#pragma unroll
        for (int t = 0; t < 4; ++t) {
            int row = row0 + wm * 64 + i * 16 + quad * 4 + t;
            size_t rb = (size_t)row * N;
#pragma unroll
            for (int j = 0; j < 4; ++j) {
                int col = col0 + wn * 64 + j * 16 + m15;
                float v = acc[i][j][t] + bias[col];
                __hip_bfloat16 hi = __float2bfloat16(v);
                Chi_[rb + col] = hi;
                if (Clo_) Clo_[rb + col] = __float2bfloat16(v - __bfloat162float(hi));
            }
        }
    }
}

// ---------------------------------------------------------------------------
// Expert layer 1: hid[slot] = relu(a[token(slot)] @ W1t[e]^T + b1[e])
// R8: swizzle + prefetch, no min-waves bound (spill fix, see gemm_split).
// ---------------------------------------------------------------------------
__global__ __launch_bounds__(256)
void expert1_kernel(const __hip_bfloat16* a_, const __hip_bfloat16* W1t_,
                    const float* __restrict__ b1,
                    const int* __restrict__ assign_token, const int* __restrict__ offs,
                    const __hip_bfloat16* zrow_, __hip_bfloat16* hid_)
{
    __shared__ __align__(16) short As[128 * 64];
    __shared__ __align__(16) short Bs[128 * 64];
    const short* A = (const short*)a_;
    const short* zrow = (const short*)zrow_;

    const int tid = threadIdx.x, lane = tid & 63, w = tid >> 6;
    const int wm = w & 1, wn = w >> 1;
    const int lin = blockIdx.y * gridDim.x + blockIdx.x;
    const int lgc = xcd_chunk(lin, gridDim.x * gridDim.y);
    const int row0 = (lgc / gridDim.x) * 128, col0 = (lgc % gridDim.x) * 128;
    const int lr = lane >> 3, g = (lane & 7) ^ lr, colel = g * 8;

    int e = NEXP - 1;
    for (int q = 0; q < NEXP; ++q) { if (row0 < offs[q + 1]) { e = q; break; } }
    const short* B = (const short*)W1t_ + (size_t)e * HID * D_MODEL;

    const short* pA[4];
    const short* pB[4];
#pragma unroll
    for (int i = 0; i < 4; ++i) {
        int r = w * 32 + i * 8 + lr;
        int tok = assign_token[row0 + r];
        pA[i] = (tok >= 0 ? A + (size_t)tok * D_MODEL : zrow) + colel;
        pB[i] = B + (size_t)(col0 + r) * D_MODEL + colel;
    }

    floatx4 acc[4][4];
#pragma unroll
    for (int i = 0; i < 4; ++i)
#pragma unroll
        for (int j = 0; j < 4; ++j) acc[i][j] = (floatx4)(0.f);

    bf16x8 va[4], vb[4];
#pragma unroll
    for (int i = 0; i < 4; ++i) {
        va[i] = *(const bf16x8*)(pA[i]);
        vb[i] = *(const bf16x8*)(pB[i]);
    }

    for (int k0 = 0; k0 < D_MODEL; k0 += 64) {
        __syncthreads();
#pragma unroll
        for (int i = 0; i < 4; ++i) {
            *(bf16x8*)(&As[(w * 32 + i * 8) * 64 + lane * 8]) = va[i];
            *(bf16x8*)(&Bs[(w * 32 + i * 8) * 64 + lane * 8]) = vb[i];
        }
        __syncthreads();
        if (k0 + 64 < D_MODEL) {
#pragma unroll
            for (int i = 0; i < 4; ++i) {
                va[i] = *(const bf16x8*)(pA[i] + k0 + 64);
                vb[i] = *(const bf16x8*)(pB[i] + k0 + 64);
            }
        }
        tile_plain(As, Bs, wm, wn, lane, acc);
    }

    const int m15 = lane & 15, quad = lane >> 4;
#pragma unroll
    for (int i = 0; i < 4; ++i) {
#pragma unroll
        for (int t = 0; t < 4; ++t) {
            int row = row0 + wm * 64 + i * 16 + quad * 4 + t;
            size_t rb = (size_t)row * HID;
#pragma unroll
            for (int j = 0; j < 4; ++j) {
                int col = col0 + wn * 64 + j * 16 + m15;
                float v = acc[i][j][t] + b1[(size_t)e * HID + col];
                hid_[rb + col] = __float2bfloat16(fmaxf(v, 0.f));
            }
        }
    }
}

// ---------------------------------------------------------------------------
// Expert layer 2: exp_out[slot] = hid[slot] @ W2t[e]^T
// R8: swizzle + prefetch, no min-waves bound.
// ---------------------------------------------------------------------------
__global__ __launch_bounds__(256)
void expert2_kernel(const __hip_bfloat16* hid_, const __hip_bfloat16* W2t_,
                    const int* __restrict__ offs, __hip_bfloat16* exp_out_)
{
    __shared__ __align__(16) short As[128 * 64];
    __shared__ __align__(16) short Bs[128 * 64];
    const short* A = (const short*)hid_;

    const int tid = threadIdx.x, lane = tid & 63, w = tid >> 6;
    const int wm = w & 1, wn = w >> 1;
    const int lin = blockIdx.y * gridDim.x + blockIdx.x;
    const int lgc = xcd_chunk(lin, gridDim.x * gridDim.y);
    const int row0 = (lgc / gridDim.x) * 128, col0 = (lgc % gridDim.x) * 128;
    const int lr = lane >> 3, g = (lane & 7) ^ lr, colel = g * 8;

    int e = NEXP - 1;
    for (int q = 0; q < NEXP; ++q) { if (row0 < offs[q + 1]) { e = q; break; } }
    const short* B = (const short*)W2t_ + (size_t)e * D_OUT * HID;

    const short* pA[4];
    const short* pB[4];
#pragma unroll
    for (int i = 0; i < 4; ++i) {
        int r = w * 32 + i * 8 + lr;
        pA[i] = A + (size_t)(row0 + r) * HID + colel;
        pB[i] = B + (size_t)(col0 + r) * HID + colel;
    }

    floatx4 acc[4][4];
#pragma unroll
    for (int i = 0; i < 4; ++i)
#pragma unroll
        for (int j = 0; j < 4; ++j) acc[i][j] = (floatx4)(0.f);

    bf16x8 va[4], vb[4];
#pragma unroll
    for (int i = 0; i < 4; ++i) {
        va[i] = *(const bf16x8*)(pA[i]);
        vb[i] = *(const bf16x8*)(pB[i]);
    }

    for (int k0 = 0; k0 < HID; k0 += 64) {
        __syncthreads();
#pragma unroll
        for (int i = 0; i < 4; ++i) {
            *(bf16x8*)(&As[(w * 32 + i * 8) * 64 + lane * 8]) = va[i];
            *(bf16x8*)(&Bs[(w * 32 + i * 8) * 64 + lane * 8]) = vb[i];
        }
        __syncthreads();
        if (k0 + 64 < HID) {
#pragma unroll
            for (int i = 0; i < 4; ++i) {
                va[i] = *(const bf16x8*)(pA[i] + k0 + 64);
                vb[i] = *(const bf16x8*)(pB[i] + k0 + 64);
            }
        }
        tile_plain(As, Bs, wm, wn, lane, acc);
    }

    const int m15 = lane & 15, quad = lane >> 4;
#pragma unroll
    for (int i = 0; i < 4; ++i) {
#pragma unroll
        for (int t = 0; t < 4; ++t) {
            int row = row0 + wm * 64 + i * 16 + quad * 4 + t;
            size_t rb = (size_t)row * D_OUT;
#pragma unroll
            for (int j = 0; j < 4; ++j) {
                int col = col0 + wn * 64 + j * 16 + m15;
                exp_out_[rb + col] = __float2bfloat16(acc[i][j][t]);
            }
        }
    }
}

// ---------------------------------------------------------------------------
// FUSED x-convert + gate (R6, atomic-free; confirmed: removing the 32768
// same-line counts atomics collapsed this kernel from 383us out of the top-5).
// One token per wave; pure streaming + L2-resident MgT dot + top-2 route.
// ---------------------------------------------------------------------------
__global__ __launch_bounds__(256)
void convert_gate_kernel(const float* __restrict__ x, const float* __restrict__ MgT,
                         const float* __restrict__ bgeff,
                         __hip_bfloat16* __restrict__ x_hi, __hip_bfloat16* __restrict__ x_lo,
                         int* __restrict__ route_e, float* __restrict__ route_w)
{
    const int wave = threadIdx.x >> 6, lane = threadIdx.x & 63;
    const int n = blockIdx.x * 4 + wave;
    const float* xrow = x + (size_t)n * D_IN;

    float4 v[4];
#pragma unroll
    for (int it = 0; it < 4; ++it)
        v[it] = *(const float4*)(xrow + it * 256 + lane * 4);

    float p[NEXP];
#pragma unroll
    for (int e = 0; e < NEXP; ++e) p[e] = 0.f;

#pragma unroll
    for (int it = 0; it < 4; ++it) {
        const int d = it * 256 + lane * 4;
        union { __hip_bfloat16 b[4]; short4 s; } uh, ul;
        uh.b[0] = __float2bfloat16(v[it].x); ul.b[0] = __float2bfloat16(v[it].x - __bfloat162float(uh.b[0]));
        uh.b[1] = __float2bfloat16(v[it].y); ul.b[1] = __float2bfloat16(v[it].y - __bfloat162float(uh.b[1]));
        uh.b[2] = __float2bfloat16(v[it].z); ul.b[2] = __float2bfloat16(v[it].z - __bfloat162float(uh.b[2]));
        uh.b[3] = __float2bfloat16(v[it].w); ul.b[3] = __float2bfloat16(v[it].w - __bfloat162float(uh.b[3]));
        *(short4*)(x_hi + (size_t)n * D_IN + d) = uh.s;
        *(short4*)(x_lo + (size_t)n * D_IN + d) = ul.s;
#pragma unroll
        for (int e = 0; e < NEXP; ++e) {
            const float4 m = *(const float4*)(MgT + (size_t)e * 1024 + d);
            p[e] += v[it].x * m.x + v[it].y * m.y + v[it].z * m.z + v[it].w * m.w;
        }
    }

#pragma unroll
    for (int e = 0; e < NEXP; ++e) {
        float t = p[e];
        for (int off = 32; off > 0; off >>= 1) t += __shfl_down(t, off);
        p[e] = t;
    }
    if (lane == 0) {
        float lg[NEXP];
#pragma unroll
        for (int e = 0; e < NEXP; ++e) lg[e] = p[e] + bgeff[e];
        int e0 = 0; float v0 = lg[0];
        for (int e = 1; e < NEXP; ++e) if (lg[e] > v0) { v0 = lg[e]; e0 = e; }
        int e1 = -1; float v1 = -3.0e38f;
        for (int e = 0; e < NEXP; ++e) {
            if (e == e0) continue;
            if (lg[e] > v1) { v1 = lg[e]; e1 = e; }
        }
        float w0 = 1.f / (1.f + expf(v1 - v0));   // softmax + top-2 renorm
        float w1 = 1.f - w0;
        route_e[n * 2]     = e0;
        route_e[n * 2 + 1] = e1;
        route_w[n * 2]     = w0;
        route_w[n * 2 + 1] = w1;
    }
}

// ---------------------------------------------------------------------------
// Histogram of route_e into counts[NEXP]: per-block LDS histogram, then 10
// global atomics per block (64 blocks -> 640 global atomics total).
// ---------------------------------------------------------------------------
__global__ __launch_bounds__(256)
void count_kernel(const int* __restrict__ route_e, int* __restrict__ counts)
{
    __shared__ int h[NEXP];
    if (threadIdx.x < NEXP) h[threadIdx.x] = 0;
    __syncthreads();
    const int i = blockIdx.x * 512 + threadIdx.x;   // 64 blocks * 512 = 32768
    atomicAdd(&h[route_e[i]], 1);
    atomicAdd(&h[route_e[i + 256]], 1);
    __syncthreads();
    if (threadIdx.x < NEXP) atomicAdd(&counts[threadIdx.x], h[threadIdx.x]);
}

// ---------------------------------------------------------------------------
// fp32 [R][C] -> transposed bf16 [C][R] hi (+ optional lo); batched over z.
// ---------------------------------------------------------------------------
__global__ __launch_bounds__(256)
void transpose_cvt_kernel(const float* __restrict__ in, __hip_bfloat16* out_hi,
                          __hip_bfloat16* out_lo, int R, int C)
{
    __shared__ float t[32][33];
    const size_t zoff = (size_t)blockIdx.z * R * C;
    in += zoff; out_hi += zoff; if (out_lo) out_lo += zoff;
    const int c0 = blockIdx.x * 32, r0 = blockIdx.y * 32;
    const int tx = threadIdx.x & 31, ty = threadIdx.x >> 5;
#pragma unroll
    for (int i = 0; i < 4; ++i)
        t[ty + i * 8][tx] = in[(size_t)(r0 + ty + i * 8) * C + (c0 + tx)];
    __syncthreads();
#pragma unroll
    for (int i = 0; i < 4; ++i) {
        float v = t[tx][ty + i * 8];
        size_t o = (size_t)(c0 + ty + i * 8) * R + (r0 + tx);
        __hip_bfloat16 hi = __float2bfloat16(v);
        out_hi[o] = hi;
        if (out_lo) out_lo[o] = __float2bfloat16(v - __bfloat162float(hi));
    }
}

// ---------------------------------------------------------------------------
// Thin fp32 GEMM for gate-matrix chain: Cm = A[1024][1024] @ B[1024][10];
// trans=0 -> Cm[m][10]; trans=1 -> Cm[e][1024] (transposed write for MgT).
// ---------------------------------------------------------------------------
__global__ __launch_bounds__(256)
void wchain_kernel(const float* __restrict__ A, const float* __restrict__ B,
                   float* __restrict__ Cm, int trans)
{
    const int wave = threadIdx.x >> 6, lane = threadIdx.x & 63;
    const int m = blockIdx.x * 4 + wave;
    float acc[NEXP];
#pragma unroll
    for (int e = 0; e < NEXP; ++e) acc[e] = 0.f;
    const float* ar = A + (size_t)m * 1024;
    for (int d = lane; d < 1024; d += 64) {
        float av = ar[d];
        const float* br = B + (size_t)d * NEXP;
#pragma unroll
        for (int e = 0; e < NEXP; ++e) acc[e] += av * br[e];
    }
#pragma unroll
    for (int e = 0; e < NEXP; ++e) {
        float v = acc[e];
        for (int off = 32; off > 0; off >>= 1) v += __shfl_down(v, off);
        if (lane == 0) Cm[trans ? ((size_t)e * 1024 + m) : ((size_t)m * NEXP + e)] = v;
    }
}

// ---------------------------------------------------------------------------
// bg_eff = bg + bo@Wg + bv@t1 + bp@t2    (single block)
// ---------------------------------------------------------------------------
__global__ __launch_bounds__(256)
void bias_eff_kernel(const float* __restrict__ bp, const float* __restrict__ bv,
                     const float* __restrict__ bo, const float* __restrict__ bg,
                     const float* __restrict__ Wg, const float* __restrict__ t1,
                     const float* __restrict__ t2, float* __restrict__ bgeff)
{
    __shared__ float red[256];
    const int tid = threadIdx.x;
    float acc[NEXP];
#pragma unroll
    for (int e = 0; e < NEXP; ++e) acc[e] = 0.f;
    for (int d = tid; d < 1024; d += 256) {
        float o = bo[d], v = bv[d], p = bp[d];
#pragma unroll
        for (int e = 0; e < NEXP; ++e)
            acc[e] += o * Wg[d * NEXP + e] + v * t1[d * NEXP + e] + p * t2[d * NEXP + e];
    }
    for (int e = 0; e < NEXP; ++e) {
        red[tid] = acc[e];
        __syncthreads();
        for (int s = 128; s > 0; s >>= 1) {
            if (tid < s) red[tid] += red[tid + s];
            __syncthreads();
        }
        if (tid == 0) bgeff[e] = red[0] + bg[e];
        __syncthreads();
    }
}

// ---------------------------------------------------------------------------
__global__ __launch_bounds__(256)
void init_kernel(int* __restrict__ counts, int* __restrict__ cursors,
                 int* __restrict__ assign_token, int* __restrict__ zrow_i)
{
    int i = blockIdx.x * 256 + threadIdx.x;
    if (i < NEXP) { counts[i] = 0; cursors[i] = 0; }
    if (i < 512) zrow_i[i] = 0;                 // 1024 bf16 zeros
    if (i < A_CAP) assign_token[i] = -1;
}

__global__ void offsets_kernel(const int* __restrict__ counts, int* __restrict__ offs)
{
    if (threadIdx.x == 0 && blockIdx.x == 0) {
        int acc = 0;
        for (int e = 0; e < NEXP; ++e) {
            offs[e] = acc;
            acc += (counts[e] + EPAD - 1) / EPAD * EPAD;
        }
        offs[NEXP] = acc;
    }
}

// ---------------------------------------------------------------------------
// Scatter with WAVE-AGGREGATED cursor atomics (R6): <=10 atomics/wave via
// ballot+popcount vs 32768 contended return-value atomics before.
// ---------------------------------------------------------------------------
__global__ __launch_bounds__(256)
void scatter_kernel(const int* __restrict__ route_e,
                    const int* __restrict__ offs, int* __restrict__ cursors,
                    int* __restrict__ assign_token, int* __restrict__ slot_of)
{
    const int i = blockIdx.x * 256 + threadIdx.x;
    const int lane = threadIdx.x & 63;
    const int e = route_e[i];
    int slot = 0;
#pragma unroll
    for (int q = 0; q < NEXP; ++q) {
        unsigned long long mask = __ballot(e == q);
        if (e == q) {
            const int leader = (int)__ffsll((long long)mask) - 1;
            const int rank = (int)__popcll(mask & ((1ull << lane) - 1ull));
            int base = 0;
            if (lane == leader) base = atomicAdd(&cursors[q], (int)__popcll(mask));
            base = __shfl(base, leader);
            slot = offs[q] + base + rank;
        }
    }
    assign_token[slot] = i >> 1;
    slot_of[i] = slot;
}

// ---------------------------------------------------------------------------
// Combine (gather): out[n] = w0*(row(s0)+b2[e0]) + w1*(row(s1)+b2[e1])
// ---------------------------------------------------------------------------
__global__ __launch_bounds__(256)
void combine_kernel(const __hip_bfloat16* __restrict__ exp_out,
                    const int* __restrict__ slot_of, const int* __restrict__ route_e,
                    const float* __restrict__ route_w, const float* __restrict__ b2,
                    float* __restrict__ out)
{
    const int n = blockIdx.x;
    const int c = threadIdx.x * 4;
    const int s0 = slot_of[n * 2],  s1 = slot_of[n * 2 + 1];
    const int e0 = route_e[n * 2],  e1 = route_e[n * 2 + 1];
    const float w0 = route_w[n * 2], w1 = route_w[n * 2 + 1];

    union U { float2 f2; __hip_bfloat16 b[4]; } u0, u1;
    u0.f2 = *(const float2*)(exp_out + (size_t)s0 * D_OUT + c);
    u1.f2 = *(const float2*)(exp_out + (size_t)s1 * D_OUT + c);
    const float4 bb0 = *(const float4*)(b2 + (size_t)e0 * D_OUT + c);
    const float4 bb1 = *(const float4*)(b2 + (size_t)e1 * D_OUT + c);

    float4 o;
    o.x = w0 * (__bfloat162float(u0.b[0]) + bb0.x) + w1 * (__bfloat162float(u1.b[0]) + bb1.x);
    o.y = w0 * (__bfloat162float(u0.b[1]) + bb0.y) + w1 * (__bfloat162float(u1.b[1]) + bb1.y);
    o.z = w0 * (__bfloat162float(u0.b[2]) + bb0.z) + w1 * (__bfloat162float(u1.b[2]) + bb1.z);
    o.w = w0 * (__bfloat162float(u0.b[3]) + bb0.w) + w1 * (__bfloat162float(u1.b[3]) + bb1.w);
    *(float4*)(out + (size_t)n * D_OUT + c) = o;
}

// ---------------------------------------------------------------------------
extern "C" void kernel_launch(void* const* d_in, const int* in_sizes, int n_in,
                              void* d_out, int out_size, void* d_ws, size_t ws_size,
                              hipStream_t stream)
{
    const float* x  = (const float*)d_in[0];
    const float* Wp = (const float*)d_in[2];
    const float* bp = (const float*)d_in[3];
    const float* Wv = (const float*)d_in[4];
    const float* bv = (const float*)d_in[5];
    const float* Wo = (const float*)d_in[6];
    const float* bo = (const float*)d_in[7];
    const float* Wg = (const float*)d_in[8];
    const float* bg = (const float*)d_in[9];
    const float* W1 = (const float*)d_in[10];
    const float* b1 = (const float*)d_in[11];
    const float* W2 = (const float*)d_in[12];
    const float* b2 = (const float*)d_in[13];
    float* out = (float*)d_out;

    // ---- workspace layout (bytes); lifetime-based aliasing, total ~150.6 MiB ----
    char* W = (char*)d_ws;
    typedef __hip_bfloat16 bf;
    bf* x_hi  = (bf*)(W + 0);                  // [N,D]  dead after gemm1
    bf* x_lo  = (bf*)(W + 33554432);           //        dead after gemm1
    bf* h_hi  = (bf*)(W + 67108864);           // dead after gemm2
    bf* h_lo  = (bf*)(W + 100663296);          // dead after gemm2
    bf* hv_hi = (bf*)(W + 0);                  // aliases x (dead) ; dead after gemm3
    bf* hv_lo = (bf*)(W + 33554432);
    bf* a_bf  = (bf*)(W + 100663296);          // aliases h_lo (dead); read by expert1
    bf* exp_out = (bf*)(W + 0);                // [A_CAP,D_OUT] 69.7MB; hv dead by then
    bf* hid   = (bf*)(W + 69730304);           // [A_CAP,HID] in dead h_hi region
    // weights (alive whole run)
    bf* Wpt_hi = (bf*)(W + 134217728);
    bf* Wpt_lo = (bf*)(W + 136314880);
    bf* Wvt_hi = (bf*)(W + 138412032);
    bf* Wvt_lo = (bf*)(W + 140509184);
    bf* Wot_hi = (bf*)(W + 142606336);
    bf* Wot_lo = (bf*)(W + 144703488);
    bf* W1t    = (bf*)(W + 146800640);         // [E][HID][D]
    bf* W2t    = (bf*)(W + 152043520);         // [E][D_OUT][HID]
    // small buffers
    bf*    zrow         = (bf*)(W + 157286400);       // 1024 bf16 zeros
    int*   route_e      = (int*)(W + 157288448);
    float* route_w      = (float*)(W + 157419520);
    int*   slot_of      = (int*)(W + 157550592);
    int*   assign_token = (int*)(W + 157681664);
    int*   counts       = (int*)(W + 157817856);
    int*   offs         = (int*)(W + 157817920);
    int*   cursors      = (int*)(W + 157817984);
    float* MgT          = (float*)(W + 157818048);    // [10][1024] transposed
    float* t1           = (float*)(W + 157859008);
    float* t2           = (float*)(W + 157899968);
    float* bgeff        = (float*)(W + 157940928);

    dim3 blk(256);

    // ---- weight conversions ----
    transpose_cvt_kernel<<<dim3(32, 32, 1), blk, 0, stream>>>(Wp, Wpt_hi, Wpt_lo, D_IN, D_MODEL);
    transpose_cvt_kernel<<<dim3(32, 32, 1), blk, 0, stream>>>(Wv, Wvt_hi, Wvt_lo, D_MODEL, D_MODEL);
    transpose_cvt_kernel<<<dim3(32, 32, 1), blk, 0, stream>>>(Wo, Wot_hi, Wot_lo, D_MODEL, D_MODEL);
    transpose_cvt_kernel<<<dim3(HID / 32, D_MODEL / 32, NEXP), blk, 0, stream>>>(W1, W1t, nullptr, D_MODEL, HID);
    transpose_cvt_kernel<<<dim3(D_OUT / 32, HID / 32, NEXP), blk, 0, stream>>>(W2, W2t, nullptr, HID, D_OUT);

    // ---- gate matrix chain (fp32, exactness-preserving associativity) ----
    wchain_kernel<<<256, blk, 0, stream>>>(Wo, Wg, t1, 0);   // t1 = Wo@Wg
    wchain_kernel<<<256, blk, 0, stream>>>(Wv, t1, t2, 0);   // t2 = Wv@t1
    wchain_kernel<<<256, blk, 0, stream>>>(Wp, t2, MgT, 1);  // MgT = (Wp@t2)^T
    bias_eff_kernel<<<1, blk, 0, stream>>>(bp, bv, bo, bg, Wg, t1, t2, bgeff);

    // ---- routing init + fused convert/gate (atomic-free) + count + scatter ----
    init_kernel<<<(A_CAP + 255) / 256, blk, 0, stream>>>(counts, cursors, assign_token,
                                                         (int*)zrow);
    convert_gate_kernel<<<N_TOK / 4, blk, 0, stream>>>(x, MgT, bgeff, x_hi, x_lo,
                                                       route_e, route_w);
    count_kernel<<<2 * N_TOK / 512, blk, 0, stream>>>(route_e, counts);
    offsets_kernel<<<1, 64, 0, stream>>>(counts, offs);
    scatter_kernel<<<2 * N_TOK / 256, blk, 0, stream>>>(route_e, offs, cursors,
                                                        assign_token, slot_of);

    // ---- main chain: split-bf16 MFMA (~fp32 accuracy) ----
    dim3 cgrid(D_MODEL / 128, N_TOK / 128);   // (8, 128)
    gemm_split_kernel<<<cgrid, blk, 0, stream>>>(x_hi, x_lo, Wpt_hi, Wpt_lo, bp,
                                                 h_hi, h_lo, D_IN, D_MODEL);
    gemm_split_kernel<<<cgrid, blk, 0, stream>>>(h_hi, h_lo, Wvt_hi, Wvt_lo, bv,
                                                 hv_hi, hv_lo, D_MODEL, D_MODEL);
    gemm_split_kernel<<<cgrid, blk, 0, stream>>>(hv_hi, hv_lo, Wot_hi, Wot_lo, bo,
                                                 a_bf, nullptr, D_MODEL, D_MODEL);

    // ---- experts: plain bf16 MFMA, grouped by expert ----
    expert1_kernel<<<dim3(HID / 128, A_CAP / 128), blk, 0, stream>>>(
        a_bf, W1t, b1, assign_token, offs, zrow, hid);
    expert2_kernel<<<dim3(D_OUT / 128, A_CAP / 128), blk, 0, stream>>>(
        hid, W2t, offs, exp_out);
    combine_kernel<<<N_TOK, blk, 0, stream>>>(exp_out, slot_of, route_e, route_w, b2, out);
}

// Round 6
// 558.042 us; speedup vs baseline: 3.0004x; 1.2253x over previous
//
#include <hip/hip_runtime.h>
#include <hip/hip_bf16.h>
#include <math.h>

#define N_TOK   16384
#define D_IN    1024
#define D_MODEL 1024
#define HID     256
#define NEXP    10
#define D_OUT   1024

// Expert routing: pad each expert's list to a multiple of EPAD so every
// 128-row tile is single-expert. Static capacity => static grid (graph-safe).
#define EPAD 128
#define A_CAP (2*N_TOK + NEXP*EPAD)   // 34048 = 266 * 128

typedef __attribute__((ext_vector_type(8))) __bf16 bf16x8;
typedef __attribute__((ext_vector_type(4))) float floatx4;

// ---------------------------------------------------------------------------
// XCD-chunked block swizzle (bijective): R8 confirmed — FETCH 290MB -> 77MB
// (~ideal) on the main GEMM. Keep on all MFMA kernels.
// ---------------------------------------------------------------------------
__device__ __forceinline__ int xcd_chunk(int orig, int nwg)
{
    const int q = nwg >> 3, r = nwg & 7;
    const int c = orig & 7, j = orig >> 3;
    return (c < r ? c * (q + 1) : r * (q + 1) + (c - r) * q) + j;
}

// ---------------------------------------------------------------------------
// LDS tile layout (per 128x64-short tile): row = 128 bytes = 8 chunks of 16B.
// Chunk g of row r is stored at position g ^ (r&7); staging applies the inverse
// swizzle on the per-lane *global* source address, so the LDS store is simply
// rowgroup_base + lane*16B.
// ---------------------------------------------------------------------------
__device__ __forceinline__ bf16x8 lds_frag(const short* base, int row, int chunk)
{
    return *(const bf16x8*)(base + row * 64 + (chunk << 3));
}

// plain bf16: tile covers K-step 64 (chunks 0..7 = k 0..63)
__device__ __forceinline__ void tile_plain(const short* As, const short* Bs,
                                           int wm, int wn, int lane, floatx4 acc[4][4])
{
    const int m15 = lane & 15, quad = lane >> 4, sw = m15 & 7;
#pragma unroll
    for (int kk = 0; kk < 2; ++kk) {
        bf16x8 af[4], bfr[4];
#pragma unroll
        for (int i = 0; i < 4; ++i)
            af[i] = lds_frag(As, wm * 64 + i * 16 + m15, ((kk << 2) + quad) ^ sw);
#pragma unroll
        for (int j = 0; j < 4; ++j)
            bfr[j] = lds_frag(Bs, wn * 64 + j * 16 + m15, ((kk << 2) + quad) ^ sw);
#pragma unroll
        for (int i = 0; i < 4; ++i)
#pragma unroll
            for (int j = 0; j < 4; ++j)
                acc[i][j] = __builtin_amdgcn_mfma_f32_16x16x32_bf16(af[i], bfr[j],
                                                                    acc[i][j], 0, 0, 0);
    }
}

// split bf16: tile covers K-step 32; chunks 0..3 = hi plane, 4..7 = lo plane.
// acc += Ah*Bh + Ah*Bl + Al*Bh  (Al*Bl ~ 2^-18, dropped)
__device__ __forceinline__ void tile_split(const short* As, const short* Bs,
                                           int wm, int wn, int lane, floatx4 acc[4][4])
{
    const int m15 = lane & 15, quad = lane >> 4, sw = m15 & 7;
    bf16x8 ah[4], al[4], bh[4], bl[4];
#pragma unroll
    for (int i = 0; i < 4; ++i) {
        int r = wm * 64 + i * 16 + m15;
        ah[i] = lds_frag(As, r, quad ^ sw);
        al[i] = lds_frag(As, r, (4 + quad) ^ sw);
    }
#pragma unroll
    for (int j = 0; j < 4; ++j) {
        int r = wn * 64 + j * 16 + m15;
        bh[j] = lds_frag(Bs, r, quad ^ sw);
        bl[j] = lds_frag(Bs, r, (4 + quad) ^ sw);
    }
#pragma unroll
    for (int i = 0; i < 4; ++i)
#pragma unroll
        for (int j = 0; j < 4; ++j) {
            floatx4 c = acc[i][j];
            c = __builtin_amdgcn_mfma_f32_16x16x32_bf16(ah[i], bh[j], c, 0, 0, 0);
            c = __builtin_amdgcn_mfma_f32_16x16x32_bf16(ah[i], bl[j], c, 0, 0, 0);
            c = __builtin_amdgcn_mfma_f32_16x16x32_bf16(al[i], bh[j], c, 0, 0, 0);
            acc[i][j] = c;
        }
}

// ---------------------------------------------------------------------------
// Split-bf16 GEMM: C = A @ Bt^T + bias, inputs as hi/lo bf16 planes [M][K] and
// [N][K]; output hi (+ optional lo) bf16 planes. ~fp32 accuracy.
// R9: also used (at grid 8x8) for the weight-product passes Pt=(Wv@Wo)^T and
// Mt=(Wp@Wv@Wo)^T that collapse the 3-GEMM main chain into 1 (R8: each big
// GEMM is at the 877TF structural ceiling -> remove 2 of 3 algorithmically).
// ---------------------------------------------------------------------------
__global__ __launch_bounds__(256)
void gemm_split_kernel(const __hip_bfloat16* Ahi_, const __hip_bfloat16* Alo_,
                       const __hip_bfloat16* Bhi_, const __hip_bfloat16* Blo_,
                       const float* __restrict__ bias,
                       __hip_bfloat16* Chi_, __hip_bfloat16* Clo_, int K, int N)
{
    __shared__ __align__(16) short As[128 * 64];
    __shared__ __align__(16) short Bs[128 * 64];
    const short* Ahi = (const short*)Ahi_;
    const short* Alo = (const short*)Alo_;
    const short* Bhi = (const short*)Bhi_;
    const short* Blo = (const short*)Blo_;

    const int tid = threadIdx.x, lane = tid & 63, w = tid >> 6;
    const int wm = w & 1, wn = w >> 1;
    // logical tile from swizzled id: contiguous logical ids share a row-tile
    const int lin = blockIdx.y * gridDim.x + blockIdx.x;
    const int lgc = xcd_chunk(lin, gridDim.x * gridDim.y);
    const int row0 = (lgc / gridDim.x) * 128, col0 = (lgc % gridDim.x) * 128;
    const int lr = lane >> 3;
    const int g = (lane & 7) ^ lr;          // swizzled source chunk (const per lane)
    const int plane = g >> 2, colel = (g & 3) * 8;

    const short* pA[4];
    const short* pB[4];
#pragma unroll
    for (int i = 0; i < 4; ++i) {
        int r = w * 32 + i * 8 + lr;
        pA[i] = (plane ? Alo : Ahi) + (size_t)(row0 + r) * K + colel;
        pB[i] = (plane ? Blo : Bhi) + (size_t)(col0 + r) * K + colel;
    }

    floatx4 acc[4][4];
#pragma unroll
    for (int i = 0; i < 4; ++i)
#pragma unroll
        for (int j = 0; j < 4; ++j) acc[i][j] = (floatx4)(0.f);

    // prologue: prefetch K-step 0
    bf16x8 va[4], vb[4];
#pragma unroll
    for (int i = 0; i < 4; ++i) {
        va[i] = *(const bf16x8*)(pA[i]);
        vb[i] = *(const bf16x8*)(pB[i]);
    }

    for (int k0 = 0; k0 < K; k0 += 32) {
        __syncthreads();
#pragma unroll
        for (int i = 0; i < 4; ++i) {
            *(bf16x8*)(&As[(w * 32 + i * 8) * 64 + lane * 8]) = va[i];
            *(bf16x8*)(&Bs[(w * 32 + i * 8) * 64 + lane * 8]) = vb[i];
        }
        __syncthreads();
        if (k0 + 32 < K) {
#pragma unroll
            for (int i = 0; i < 4; ++i) {
                va[i] = *(const bf16x8*)(pA[i] + k0 + 32);
                vb[i] = *(const bf16x8*)(pB[i] + k0 + 32);
            }
        }
        tile_split(As, Bs, wm, wn, lane, acc);
    }

    const int m15 = lane & 15, quad = lane >> 4;
#pragma unroll
    for (int i = 0; i < 4; ++i) {
#pragma unroll
        for (int t = 0; t < 4; ++t) {
            int row = row0 + wm * 64 + i * 16 + quad * 4 + t;
            size_t rb = (size_t)row * N;
#pragma unroll
            for (int j = 0; j < 4; ++j) {
                int col = col0 + wn * 64 + j * 16 + m15;
                float v = acc[i][j][t] + bias[col];
                __hip_bfloat16 hi = __float2bfloat16(v);
                Chi_[rb + col] = hi;
                if (Clo_) Clo_[rb + col] = __float2bfloat16(v - __bfloat162float(hi));
            }
        }
    }
}

// ---------------------------------------------------------------------------
// Expert layer 1: hid[slot] = relu(a[token(slot)] @ W1t[e]^T + b1[e])
// ---------------------------------------------------------------------------
__global__ __launch_bounds__(256)
void expert1_kernel(const __hip_bfloat16* a_, const __hip_bfloat16* W1t_,
                    const float* __restrict__ b1,
                    const int* __restrict__ assign_token, const int* __restrict__ offs,
                    const __hip_bfloat16* zrow_, __hip_bfloat16* hid_)
{
    __shared__ __align__(16) short As[128 * 64];
    __shared__ __align__(16) short Bs[128 * 64];
    const short* A = (const short*)a_;
    const short* zrow = (const short*)zrow_;

    const int tid = threadIdx.x, lane = tid & 63, w = tid >> 6;
    const int wm = w & 1, wn = w >> 1;
    const int lin = blockIdx.y * gridDim.x + blockIdx.x;
    const int lgc = xcd_chunk(lin, gridDim.x * gridDim.y);
    const int row0 = (lgc / gridDim.x) * 128, col0 = (lgc % gridDim.x) * 128;
    const int lr = lane >> 3, g = (lane & 7) ^ lr, colel = g * 8;

    int e = NEXP - 1;
    for (int q = 0; q < NEXP; ++q) { if (row0 < offs[q + 1]) { e = q; break; } }
    const short* B = (const short*)W1t_ + (size_t)e * HID * D_MODEL;

    const short* pA[4];
    const short* pB[4];
#pragma unroll
    for (int i = 0; i < 4; ++i) {
        int r = w * 32 + i * 8 + lr;
        int tok = assign_token[row0 + r];
        pA[i] = (tok >= 0 ? A + (size_t)tok * D_MODEL : zrow) + colel;
        pB[i] = B + (size_t)(col0 + r) * D_MODEL + colel;
    }

    floatx4 acc[4][4];
#pragma unroll
    for (int i = 0; i < 4; ++i)
#pragma unroll
        for (int j = 0; j < 4; ++j) acc[i][j] = (floatx4)(0.f);

    bf16x8 va[4], vb[4];
#pragma unroll
    for (int i = 0; i < 4; ++i) {
        va[i] = *(const bf16x8*)(pA[i]);
        vb[i] = *(const bf16x8*)(pB[i]);
    }

    for (int k0 = 0; k0 < D_MODEL; k0 += 64) {
        __syncthreads();
#pragma unroll
        for (int i = 0; i < 4; ++i) {
            *(bf16x8*)(&As[(w * 32 + i * 8) * 64 + lane * 8]) = va[i];
            *(bf16x8*)(&Bs[(w * 32 + i * 8) * 64 + lane * 8]) = vb[i];
        }
        __syncthreads();
        if (k0 + 64 < D_MODEL) {
#pragma unroll
            for (int i = 0; i < 4; ++i) {
                va[i] = *(const bf16x8*)(pA[i] + k0 + 64);
                vb[i] = *(const bf16x8*)(pB[i] + k0 + 64);
            }
        }
        tile_plain(As, Bs, wm, wn, lane, acc);
    }

    const int m15 = lane & 15, quad = lane >> 4;
#pragma unroll
    for (int i = 0; i < 4; ++i) {
#pragma unroll
        for (int t = 0; t < 4; ++t) {
            int row = row0 + wm * 64 + i * 16 + quad * 4 + t;
            size_t rb = (size_t)row * HID;
#pragma unroll
            for (int j = 0; j < 4; ++j) {
                int col = col0 + wn * 64 + j * 16 + m15;
                float v = acc[i][j][t] + b1[(size_t)e * HID + col];
                hid_[rb + col] = __float2bfloat16(fmaxf(v, 0.f));
            }
        }
    }
}

// ---------------------------------------------------------------------------
// Expert layer 2: exp_out[slot] = hid[slot] @ W2t[e]^T
// ---------------------------------------------------------------------------
__global__ __launch_bounds__(256)
void expert2_kernel(const __hip_bfloat16* hid_, const __hip_bfloat16* W2t_,
                    const int* __restrict__ offs, __hip_bfloat16* exp_out_)
{
    __shared__ __align__(16) short As[128 * 64];
    __shared__ __align__(16) short Bs[128 * 64];
    const short* A = (const short*)hid_;

    const int tid = threadIdx.x, lane = tid & 63, w = tid >> 6;
    const int wm = w & 1, wn = w >> 1;
    const int lin = blockIdx.y * gridDim.x + blockIdx.x;
    const int lgc = xcd_chunk(lin, gridDim.x * gridDim.y);
    const int row0 = (lgc / gridDim.x) * 128, col0 = (lgc % gridDim.x) * 128;
    const int lr = lane >> 3, g = (lane & 7) ^ lr, colel = g * 8;

    int e = NEXP - 1;
    for (int q = 0; q < NEXP; ++q) { if (row0 < offs[q + 1]) { e = q; break; } }
    const short* B = (const short*)W2t_ + (size_t)e * D_OUT * HID;

    const short* pA[4];
    const short* pB[4];
#pragma unroll
    for (int i = 0; i < 4; ++i) {
        int r = w * 32 + i * 8 + lr;
        pA[i] = A + (size_t)(row0 + r) * HID + colel;
        pB[i] = B + (size_t)(col0 + r) * HID + colel;
    }

    floatx4 acc[4][4];
#pragma unroll
    for (int i = 0; i < 4; ++i)
#pragma unroll
        for (int j = 0; j < 4; ++j) acc[i][j] = (floatx4)(0.f);

    bf16x8 va[4], vb[4];
#pragma unroll
    for (int i = 0; i < 4; ++i) {
        va[i] = *(const bf16x8*)(pA[i]);
        vb[i] = *(const bf16x8*)(pB[i]);
    }

    for (int k0 = 0; k0 < HID; k0 += 64) {
        __syncthreads();
#pragma unroll
        for (int i = 0; i < 4; ++i) {
            *(bf16x8*)(&As[(w * 32 + i * 8) * 64 + lane * 8]) = va[i];
            *(bf16x8*)(&Bs[(w * 32 + i * 8) * 64 + lane * 8]) = vb[i];
        }
        __syncthreads();
        if (k0 + 64 < HID) {
#pragma unroll
            for (int i = 0; i < 4; ++i) {
                va[i] = *(const bf16x8*)(pA[i] + k0 + 64);
                vb[i] = *(const bf16x8*)(pB[i] + k0 + 64);
            }
        }
        tile_plain(As, Bs, wm, wn, lane, acc);
    }

    const int m15 = lane & 15, quad = lane >> 4;
#pragma unroll
    for (int i = 0; i < 4; ++i) {
#pragma unroll
        for (int t = 0; t < 4; ++t) {
            int row = row0 + wm * 64 + i * 16 + quad * 4 + t;
            size_t rb = (size_t)row * D_OUT;
#pragma unroll
            for (int j = 0; j < 4; ++j) {
                int col = col0 + wn * 64 + j * 16 + m15;
                exp_out_[rb + col] = __float2bfloat16(acc[i][j][t]);
            }
        }
    }
}

// ---------------------------------------------------------------------------
// FUSED x-convert + gate (atomic-free). One token per wave.
// ---------------------------------------------------------------------------
__global__ __launch_bounds__(256)
void convert_gate_kernel(const float* __restrict__ x, const float* __restrict__ MgT,
                         const float* __restrict__ bgeff,
                         __hip_bfloat16* __restrict__ x_hi, __hip_bfloat16* __restrict__ x_lo,
                         int* __restrict__ route_e, float* __restrict__ route_w)
{
    const int wave = threadIdx.x >> 6, lane = threadIdx.x & 63;
    const int n = blockIdx.x * 4 + wave;
    const float* xrow = x + (size_t)n * D_IN;

    float4 v[4];
#pragma unroll
    for (int it = 0; it < 4; ++it)
        v[it] = *(const float4*)(xrow + it * 256 + lane * 4);

    float p[NEXP];
#pragma unroll
    for (int e = 0; e < NEXP; ++e) p[e] = 0.f;

#pragma unroll
    for (int it = 0; it < 4; ++it) {
        const int d = it * 256 + lane * 4;
        union { __hip_bfloat16 b[4]; short4 s; } uh, ul;
        uh.b[0] = __float2bfloat16(v[it].x); ul.b[0] = __float2bfloat16(v[it].x - __bfloat162float(uh.b[0]));
        uh.b[1] = __float2bfloat16(v[it].y); ul.b[1] = __float2bfloat16(v[it].y - __bfloat162float(uh.b[1]));
        uh.b[2] = __float2bfloat16(v[it].z); ul.b[2] = __float2bfloat16(v[it].z - __bfloat162float(uh.b[2]));
        uh.b[3] = __float2bfloat16(v[it].w); ul.b[3] = __float2bfloat16(v[it].w - __bfloat162float(uh.b[3]));
        *(short4*)(x_hi + (size_t)n * D_IN + d) = uh.s;
        *(short4*)(x_lo + (size_t)n * D_IN + d) = ul.s;
#pragma unroll
        for (int e = 0; e < NEXP; ++e) {
            const float4 m = *(const float4*)(MgT + (size_t)e * 1024 + d);
            p[e] += v[it].x * m.x + v[it].y * m.y + v[it].z * m.z + v[it].w * m.w;
        }
    }

#pragma unroll
    for (int e = 0; e < NEXP; ++e) {
        float t = p[e];
        for (int off = 32; off > 0; off >>= 1) t += __shfl_down(t, off);
        p[e] = t;
    }
    if (lane == 0) {
        float lg[NEXP];
#pragma unroll
        for (int e = 0; e < NEXP; ++e) lg[e] = p[e] + bgeff[e];
        int e0 = 0; float v0 = lg[0];
        for (int e = 1; e < NEXP; ++e) if (lg[e] > v0) { v0 = lg[e]; e0 = e; }
        int e1 = -1; float v1 = -3.0e38f;
        for (int e = 0; e < NEXP; ++e) {
            if (e == e0) continue;
            if (lg[e] > v1) { v1 = lg[e]; e1 = e; }
        }
        float w0 = 1.f / (1.f + expf(v1 - v0));   // softmax + top-2 renorm
        float w1 = 1.f - w0;
        route_e[n * 2]     = e0;
        route_e[n * 2 + 1] = e1;
        route_w[n * 2]     = w0;
        route_w[n * 2 + 1] = w1;
    }
}

// ---------------------------------------------------------------------------
// Histogram of route_e into counts[NEXP] (LDS histogram, 640 global atomics).
// ---------------------------------------------------------------------------
__global__ __launch_bounds__(256)
void count_kernel(const int* __restrict__ route_e, int* __restrict__ counts)
{
    __shared__ int h[NEXP];
    if (threadIdx.x < NEXP) h[threadIdx.x] = 0;
    __syncthreads();
    const int i = blockIdx.x * 512 + threadIdx.x;   // 64 blocks * 512 = 32768
    atomicAdd(&h[route_e[i]], 1);
    atomicAdd(&h[route_e[i + 256]], 1);
    __syncthreads();
    if (threadIdx.x < NEXP) atomicAdd(&counts[threadIdx.x], h[threadIdx.x]);
}

// ---------------------------------------------------------------------------
// fp32 [R][C] -> transposed bf16 [C][R] hi (+ optional lo); batched over z.
// ---------------------------------------------------------------------------
__global__ __launch_bounds__(256)
void transpose_cvt_kernel(const float* __restrict__ in, __hip_bfloat16* out_hi,
                          __hip_bfloat16* out_lo, int R, int C)
{
    __shared__ float t[32][33];
    const size_t zoff = (size_t)blockIdx.z * R * C;
    in += zoff; out_hi += zoff; if (out_lo) out_lo += zoff;
    const int c0 = blockIdx.x * 32, r0 = blockIdx.y * 32;
    const int tx = threadIdx.x & 31, ty = threadIdx.x >> 5;
#pragma unroll
    for (int i = 0; i < 4; ++i)
        t[ty + i * 8][tx] = in[(size_t)(r0 + ty + i * 8) * C + (c0 + tx)];
    __syncthreads();
#pragma unroll
    for (int i = 0; i < 4; ++i) {
        float v = t[tx][ty + i * 8];
        size_t o = (size_t)(c0 + ty + i * 8) * R + (r0 + tx);
        __hip_bfloat16 hi = __float2bfloat16(v);
        out_hi[o] = hi;
        if (out_lo) out_lo[o] = __float2bfloat16(v - __bfloat162float(hi));
    }
}

// ---------------------------------------------------------------------------
// R9: plain (non-transposing) fp32 -> hi/lo bf16 planes, float4-vectorized.
// Used for row-major Wv and Wp operands of the weight-product passes.
// ---------------------------------------------------------------------------
__global__ __launch_bounds__(256)
void convert_plain_kernel(const float* __restrict__ in,
                          __hip_bfloat16* __restrict__ out_hi,
                          __hip_bfloat16* __restrict__ out_lo)
{
    const int i = blockIdx.x * 256 + threadIdx.x;
    const float4 v = ((const float4*)in)[i];
    union { __hip_bfloat16 b[4]; short4 s; } uh, ul;
    uh.b[0] = __float2bfloat16(v.x); ul.b[0] = __float2bfloat16(v.x - __bfloat162float(uh.b[0]));
    uh.b[1] = __float2bfloat16(v.y); ul.b[1] = __float2bfloat16(v.y - __bfloat162float(uh.b[1]));
    uh.b[2] = __float2bfloat16(v.z); ul.b[2] = __float2bfloat16(v.z - __bfloat162float(uh.b[2]));
    uh.b[3] = __float2bfloat16(v.w); ul.b[3] = __float2bfloat16(v.w - __bfloat162float(uh.b[3]));
    ((short4*)out_hi)[i] = uh.s;
    ((short4*)out_lo)[i] = ul.s;
}

// ---------------------------------------------------------------------------
// R9: folded main-chain bias  beff2[n] = bp@(Wv@Wo)[:,n] + bv@Wo[:,n] + bo[n]
// using hi+lo reconstruction of Pt=(Wv@Wo)^T and Wot=Wo^T. One wave per n.
// ---------------------------------------------------------------------------
__global__ __launch_bounds__(256)
void bias2_kernel(const float* __restrict__ bp, const float* __restrict__ bv,
                  const float* __restrict__ bo,
                  const __hip_bfloat16* __restrict__ Pt_hi,
                  const __hip_bfloat16* __restrict__ Pt_lo,
                  const __hip_bfloat16* __restrict__ Wot_hi,
                  const __hip_bfloat16* __restrict__ Wot_lo,
                  float* __restrict__ beff2)
{
    const int wave = threadIdx.x >> 6, lane = threadIdx.x & 63;
    const int n = blockIdx.x * 4 + wave;
    float acc = 0.f;
    for (int k = lane; k < D_MODEL; k += 64) {
        const size_t o = (size_t)n * D_MODEL + k;
        float pt = __bfloat162float(Pt_hi[o]) + __bfloat162float(Pt_lo[o]);
        float wo = __bfloat162float(Wot_hi[o]) + __bfloat162float(Wot_lo[o]);
        acc += bp[k] * pt + bv[k] * wo;
    }
    for (int off = 32; off > 0; off >>= 1) acc += __shfl_down(acc, off);
    if (lane == 0) beff2[n] = acc + bo[n];
}

// ---------------------------------------------------------------------------
// Thin fp32 GEMM for gate-matrix chain: Cm = A[1024][1024] @ B[1024][10];
// trans=0 -> Cm[m][10]; trans=1 -> Cm[e][1024] (transposed write for MgT).
// ---------------------------------------------------------------------------
__global__ __launch_bounds__(256)
void wchain_kernel(const float* __restrict__ A, const float* __restrict__ B,
                   float* __restrict__ Cm, int trans)
{
    const int wave = threadIdx.x >> 6, lane = threadIdx.x & 63;
    const int m = blockIdx.x * 4 + wave;
    float acc[NEXP];
#pragma unroll
    for (int e = 0; e < NEXP; ++e) acc[e] = 0.f;
    const float* ar = A + (size_t)m * 1024;
    for (int d = lane; d < 1024; d += 64) {
        float av = ar[d];
        const float* br = B + (size_t)d * NEXP;
#pragma unroll
        for (int e = 0; e < NEXP; ++e) acc[e] += av * br[e];
    }
#pragma unroll
    for (int e = 0; e < NEXP; ++e) {
        float v = acc[e];
        for (int off = 32; off > 0; off >>= 1) v += __shfl_down(v, off);
        if (lane == 0) Cm[trans ? ((size_t)e * 1024 + m) : ((size_t)m * NEXP + e)] = v;
    }
}

// ---------------------------------------------------------------------------
// bg_eff = bg + bo@Wg + bv@t1 + bp@t2    (single block)
// ---------------------------------------------------------------------------
__global__ __launch_bounds__(256)
void bias_eff_kernel(const float* __restrict__ bp, const float* __restrict__ bv,
                     const float* __restrict__ bo, const float* __restrict__ bg,
                     const float* __restrict__ Wg, const float* __restrict__ t1,
                     const float* __restrict__ t2, float* __restrict__ bgeff)
{
    __shared__ float red[256];
    const int tid = threadIdx.x;
    float acc[NEXP];
#pragma unroll
    for (int e = 0; e < NEXP; ++e) acc[e] = 0.f;
    for (int d = tid; d < 1024; d += 256) {
        float o = bo[d], v = bv[d], p = bp[d];
#pragma unroll
        for (int e = 0; e < NEXP; ++e)
            acc[e] += o * Wg[d * NEXP + e] + v * t1[d * NEXP + e] + p * t2[d * NEXP + e];
    }
    for (int e = 0; e < NEXP; ++e) {
        red[tid] = acc[e];
        __syncthreads();
        for (int s = 128; s > 0; s >>= 1) {
            if (tid < s) red[tid] += red[tid + s];
            __syncthreads();
        }
        if (tid == 0) bgeff[e] = red[0] + bg[e];
        __syncthreads();
    }
}

// ---------------------------------------------------------------------------
__global__ __launch_bounds__(256)
void init_kernel(int* __restrict__ counts, int* __restrict__ cursors,
                 int* __restrict__ assign_token, int* __restrict__ zrow_i,
                 float* __restrict__ fzero)
{
    int i = blockIdx.x * 256 + threadIdx.x;
    if (i < NEXP) { counts[i] = 0; cursors[i] = 0; }
    if (i < 512) zrow_i[i] = 0;                 // 1024 bf16 zeros
    if (i < 1024) fzero[i] = 0.f;               // fp32 zero bias for wt-product GEMMs
    if (i < A_CAP) assign_token[i] = -1;
}

__global__ void offsets_kernel(const int* __restrict__ counts, int* __restrict__ offs)
{
    if (threadIdx.x == 0 && blockIdx.x == 0) {
        int acc = 0;
        for (int e = 0; e < NEXP; ++e) {
            offs[e] = acc;
            acc += (counts[e] + EPAD - 1) / EPAD * EPAD;
        }
        offs[NEXP] = acc;
    }
}

// ---------------------------------------------------------------------------
// Scatter with WAVE-AGGREGATED cursor atomics (R6): <=10 atomics/wave via
// ballot+popcount vs 32768 contended return-value atomics before.
// ---------------------------------------------------------------------------
__global__ __launch_bounds__(256)
void scatter_kernel(const int* __restrict__ route_e,
                    const int* __restrict__ offs, int* __restrict__ cursors,
                    int* __restrict__ assign_token, int* __restrict__ slot_of)
{
    const int i = blockIdx.x * 256 + threadIdx.x;
    const int lane = threadIdx.x & 63;
    const int e = route_e[i];
    int slot = 0;
#pragma unroll
    for (int q = 0; q < NEXP; ++q) {
        unsigned long long mask = __ballot(e == q);
        if (e == q) {
            const int leader = (int)__ffsll((long long)mask) - 1;
            const int rank = (int)__popcll(mask & ((1ull << lane) - 1ull));
            int base = 0;
            if (lane == leader) base = atomicAdd(&cursors[q], (int)__popcll(mask));
            base = __shfl(base, leader);
            slot = offs[q] + base + rank;
        }
    }
    assign_token[slot] = i >> 1;
    slot_of[i] = slot;
}

// ---------------------------------------------------------------------------
// Combine (gather): out[n] = w0*(row(s0)+b2[e0]) + w1*(row(s1)+b2[e1])
// ---------------------------------------------------------------------------
__global__ __launch_bounds__(256)
void combine_kernel(const __hip_bfloat16* __restrict__ exp_out,
                    const int* __restrict__ slot_of, const int* __restrict__ route_e,
                    const float* __restrict__ route_w, const float* __restrict__ b2,
                    float* __restrict__ out)
{
    const int n = blockIdx.x;
    const int c = threadIdx.x * 4;
    const int s0 = slot_of[n * 2],  s1 = slot_of[n * 2 + 1];
    const int e0 = route_e[n * 2],  e1 = route_e[n * 2 + 1];
    const float w0 = route_w[n * 2], w1 = route_w[n * 2 + 1];

    union U { float2 f2; __hip_bfloat16 b[4]; } u0, u1;
    u0.f2 = *(const float2*)(exp_out + (size_t)s0 * D_OUT + c);
    u1.f2 = *(const float2*)(exp_out + (size_t)s1 * D_OUT + c);
    const float4 bb0 = *(const float4*)(b2 + (size_t)e0 * D_OUT + c);
    const float4 bb1 = *(const float4*)(b2 + (size_t)e1 * D_OUT + c);

    float4 o;
    o.x = w0 * (__bfloat162float(u0.b[0]) + bb0.x) + w1 * (__bfloat162float(u1.b[0]) + bb1.x);
    o.y = w0 * (__bfloat162float(u0.b[1]) + bb0.y) + w1 * (__bfloat162float(u1.b[1]) + bb1.y);
    o.z = w0 * (__bfloat162float(u0.b[2]) + bb0.z) + w1 * (__bfloat162float(u1.b[2]) + bb1.z);
    o.w = w0 * (__bfloat162float(u0.b[3]) + bb0.w) + w1 * (__bfloat162float(u1.b[3]) + bb1.w);
    *(float4*)(out + (size_t)n * D_OUT + c) = o;
}

// ---------------------------------------------------------------------------
extern "C" void kernel_launch(void* const* d_in, const int* in_sizes, int n_in,
                              void* d_out, int out_size, void* d_ws, size_t ws_size,
                              hipStream_t stream)
{
    const float* x  = (const float*)d_in[0];
    const float* Wp = (const float*)d_in[2];
    const float* bp = (const float*)d_in[3];
    const float* Wv = (const float*)d_in[4];
    const float* bv = (const float*)d_in[5];
    const float* Wo = (const float*)d_in[6];
    const float* bo = (const float*)d_in[7];
    const float* Wg = (const float*)d_in[8];
    const float* bg = (const float*)d_in[9];
    const float* W1 = (const float*)d_in[10];
    const float* b1 = (const float*)d_in[11];
    const float* W2 = (const float*)d_in[12];
    const float* b2 = (const float*)d_in[13];
    float* out = (float*)d_out;

    // ---- workspace layout (bytes); lifetime-based aliasing ----
    // R9: main chain collapsed to ONE gemm (a = x@M + beff2, M = Wp@Wv@Wo),
    // so h/hv buffers are gone; freed weight slots host Pt/Mt planes.
    char* W = (char*)d_ws;
    typedef __hip_bfloat16 bf;
    bf* x_hi  = (bf*)(W + 0);                  // [N,D]  dead after main gemm
    bf* x_lo  = (bf*)(W + 33554432);           //        dead after main gemm
    bf* a_bf  = (bf*)(W + 100663296);          // [N,D] hi only; read by expert1
    bf* exp_out = (bf*)(W + 0);                // [A_CAP,D_OUT] 69.7MB; x dead by then
    bf* hid   = (bf*)(W + 69730304);           // [A_CAP,HID]
    // weight-product scratch (dead before experts run; region 84..96 MiB)
    bf* Wvr_hi = (bf*)(W + 88080384);          // Wv row-major hi/lo (pass A operand)
    bf* Wvr_lo = (bf*)(W + 90177536);
    bf* Wpr_hi = (bf*)(W + 92274688);          // Wp row-major hi/lo (pass B operand)
    bf* Wpr_lo = (bf*)(W + 94371840);
    float* fzero = (float*)(W + 96468992);     // 1024 fp32 zeros (bias for passes)
    float* beff2 = (float*)(W + 96473088);     // folded main-chain bias [1024]
    // weights / products (alive whole run)
    bf* Pt_hi  = (bf*)(W + 134217728);         // (Wv@Wo)^T hi/lo   (ex-Wpt slots)
    bf* Pt_lo  = (bf*)(W + 136314880);
    bf* Mt_hi  = (bf*)(W + 138412032);         // (Wp@Wv@Wo)^T hi/lo (ex-Wvt slots)
    bf* Mt_lo  = (bf*)(W + 140509184);
    bf* Wot_hi = (bf*)(W + 142606336);
    bf* Wot_lo = (bf*)(W + 144703488);
    bf* W1t    = (bf*)(W + 146800640);         // [E][HID][D]
    bf* W2t    = (bf*)(W + 152043520);         // [E][D_OUT][HID]
    // small buffers
    bf*    zrow         = (bf*)(W + 157286400);       // 1024 bf16 zeros
    int*   route_e      = (int*)(W + 157288448);
    float* route_w      = (float*)(W + 157419520);
    int*   slot_of      = (int*)(W + 157550592);
    int*   assign_token = (int*)(W + 157681664);
    int*   counts       = (int*)(W + 157817856);
    int*   offs         = (int*)(W + 157817920);
    int*   cursors      = (int*)(W + 157817984);
    float* MgT          = (float*)(W + 157818048);    // [10][1024] transposed
    float* t1           = (float*)(W + 157859008);
    float* t2           = (float*)(W + 157899968);
    float* bgeff        = (float*)(W + 157940928);

    dim3 blk(256);

    // ---- init first (also zeros fzero used as bias by the product passes) ----
    init_kernel<<<(A_CAP + 255) / 256, blk, 0, stream>>>(counts, cursors, assign_token,
                                                         (int*)zrow, fzero);

    // ---- weight conversions ----
    transpose_cvt_kernel<<<dim3(32, 32, 1), blk, 0, stream>>>(Wo, Wot_hi, Wot_lo, D_MODEL, D_MODEL);
    convert_plain_kernel<<<1024, blk, 0, stream>>>(Wv, Wvr_hi, Wvr_lo);
    convert_plain_kernel<<<1024, blk, 0, stream>>>(Wp, Wpr_hi, Wpr_lo);
    transpose_cvt_kernel<<<dim3(HID / 32, D_MODEL / 32, NEXP), blk, 0, stream>>>(W1, W1t, nullptr, D_MODEL, HID);
    transpose_cvt_kernel<<<dim3(D_OUT / 32, HID / 32, NEXP), blk, 0, stream>>>(W2, W2t, nullptr, HID, D_OUT);

    // ---- gate matrix chain (fp32, exactness-preserving associativity) ----
    wchain_kernel<<<256, blk, 0, stream>>>(Wo, Wg, t1, 0);   // t1 = Wo@Wg
    wchain_kernel<<<256, blk, 0, stream>>>(Wv, t1, t2, 0);   // t2 = Wv@t1
    wchain_kernel<<<256, blk, 0, stream>>>(Wp, t2, MgT, 1);  // MgT = (Wp@t2)^T
    bias_eff_kernel<<<1, blk, 0, stream>>>(bp, bv, bo, bg, Wg, t1, t2, bgeff);

    // ---- weight-product passes (split-bf16, hi/lo outputs, grid 8x8) ----
    // Pt[n][k] = (Wv@Wo)[k][n] :  A = Wot (Wo^T), Bt = Wv row-major
    dim3 pgrid(D_MODEL / 128, D_MODEL / 128);   // (8, 8)
    gemm_split_kernel<<<pgrid, blk, 0, stream>>>(Wot_hi, Wot_lo, Wvr_hi, Wvr_lo, fzero,
                                                 Pt_hi, Pt_lo, D_MODEL, D_MODEL);
    // Mt[n][k'] = (Wp@Wv@Wo)[k'][n] :  A = Pt, Bt = Wp row-major
    gemm_split_kernel<<<pgrid, blk, 0, stream>>>(Pt_hi, Pt_lo, Wpr_hi, Wpr_lo, fzero,
                                                 Mt_hi, Mt_lo, D_MODEL, D_IN);
    // folded bias: beff2 = bp@(Wv@Wo) + bv@Wo + bo
    bias2_kernel<<<D_MODEL / 4, blk, 0, stream>>>(bp, bv, bo, Pt_hi, Pt_lo,
                                                  Wot_hi, Wot_lo, beff2);

    // ---- fused convert/gate (atomic-free) + count + scatter ----
    convert_gate_kernel<<<N_TOK / 4, blk, 0, stream>>>(x, MgT, bgeff, x_hi, x_lo,
                                                       route_e, route_w);
    count_kernel<<<2 * N_TOK / 512, blk, 0, stream>>>(route_e, counts);
    offsets_kernel<<<1, 64, 0, stream>>>(counts, offs);
    scatter_kernel<<<2 * N_TOK / 256, blk, 0, stream>>>(route_e, offs, cursors,
                                                        assign_token, slot_of);

    // ---- main chain: ONE split-bf16 GEMM  a = x@M + beff2 ----
    dim3 cgrid(D_MODEL / 128, N_TOK / 128);   // (8, 128)
    gemm_split_kernel<<<cgrid, blk, 0, stream>>>(x_hi, x_lo, Mt_hi, Mt_lo, beff2,
                                                 a_bf, nullptr, D_IN, D_MODEL);

    // ---- experts: plain bf16 MFMA, grouped by expert ----
    expert1_kernel<<<dim3(HID / 128, A_CAP / 128), blk, 0, stream>>>(
        a_bf, W1t, b1, assign_token, offs, zrow, hid);
    expert2_kernel<<<dim3(D_OUT / 128, A_CAP / 128), blk, 0, stream>>>(
        hid, W2t, offs, exp_out);
    combine_kernel<<<N_TOK, blk, 0, stream>>>(exp_out, slot_of, route_e, route_w, b2, out);
}

// Round 7
// 536.019 us; speedup vs baseline: 3.1237x; 1.0411x over previous
//
#include <hip/hip_runtime.h>
#include <hip/hip_bf16.h>
#include <math.h>

#define N_TOK   16384
#define D_IN    1024
#define D_MODEL 1024
#define HID     256
#define NEXP    10
#define D_OUT   1024

// Expert routing: pad each expert's list to a multiple of EPAD so every
// 128-row tile is single-expert. Static capacity => static grid (graph-safe).
#define EPAD 128
#define A_CAP (2*N_TOK + NEXP*EPAD)   // 34048 = 266 * 128

typedef __attribute__((ext_vector_type(8))) __bf16 bf16x8;
typedef __attribute__((ext_vector_type(4))) float floatx4;

// ---------------------------------------------------------------------------
// XCD-chunked block swizzle (bijective): R8 confirmed — FETCH 290MB -> 77MB
// (~ideal) on the big GEMM. Keep on all MFMA kernels.
// ---------------------------------------------------------------------------
__device__ __forceinline__ int xcd_chunk(int orig, int nwg)
{
    const int q = nwg >> 3, r = nwg & 7;
    const int c = orig & 7, j = orig >> 3;
    return (c < r ? c * (q + 1) : r * (q + 1) + (c - r) * q) + j;
}

// ---------------------------------------------------------------------------
// LDS tile layout (per 128x64-short tile): row = 128 bytes = 8 chunks of 16B.
// Chunk g of row r is stored at position g ^ (r&7); staging applies the inverse
// swizzle on the per-lane *global* source address, so the LDS store is simply
// rowgroup_base + lane*16B.
// ---------------------------------------------------------------------------
__device__ __forceinline__ bf16x8 lds_frag(const short* base, int row, int chunk)
{
    return *(const bf16x8*)(base + row * 64 + (chunk << 3));
}

// plain bf16: tile covers K-step 64 (chunks 0..7 = k 0..63)
__device__ __forceinline__ void tile_plain(const short* As, const short* Bs,
                                           int wm, int wn, int lane, floatx4 acc[4][4])
{
    const int m15 = lane & 15, quad = lane >> 4, sw = m15 & 7;
#pragma unroll
    for (int kk = 0; kk < 2; ++kk) {
        bf16x8 af[4], bfr[4];
#pragma unroll
        for (int i = 0; i < 4; ++i)
            af[i] = lds_frag(As, wm * 64 + i * 16 + m15, ((kk << 2) + quad) ^ sw);
#pragma unroll
        for (int j = 0; j < 4; ++j)
            bfr[j] = lds_frag(Bs, wn * 64 + j * 16 + m15, ((kk << 2) + quad) ^ sw);
#pragma unroll
        for (int i = 0; i < 4; ++i)
#pragma unroll
            for (int j = 0; j < 4; ++j)
                acc[i][j] = __builtin_amdgcn_mfma_f32_16x16x32_bf16(af[i], bfr[j],
                                                                    acc[i][j], 0, 0, 0);
    }
}

// split bf16: tile covers K-step 32; chunks 0..3 = hi plane, 4..7 = lo plane.
// acc += Ah*Bh + Ah*Bl + Al*Bh  (Al*Bl ~ 2^-18, dropped)
__device__ __forceinline__ void tile_split(const short* As, const short* Bs,
                                           int wm, int wn, int lane, floatx4 acc[4][4])
{
    const int m15 = lane & 15, quad = lane >> 4, sw = m15 & 7;
    bf16x8 ah[4], al[4], bh[4], bl[4];
#pragma unroll
    for (int i = 0; i < 4; ++i) {
        int r = wm * 64 + i * 16 + m15;
        ah[i] = lds_frag(As, r, quad ^ sw);
        al[i] = lds_frag(As, r, (4 + quad) ^ sw);
    }
#pragma unroll
    for (int j = 0; j < 4; ++j) {
        int r = wn * 64 + j * 16 + m15;
        bh[j] = lds_frag(Bs, r, quad ^ sw);
        bl[j] = lds_frag(Bs, r, (4 + quad) ^ sw);
    }
#pragma unroll
    for (int i = 0; i < 4; ++i)
#pragma unroll
        for (int j = 0; j < 4; ++j) {
            floatx4 c = acc[i][j];
            c = __builtin_amdgcn_mfma_f32_16x16x32_bf16(ah[i], bh[j], c, 0, 0, 0);
            c = __builtin_amdgcn_mfma_f32_16x16x32_bf16(ah[i], bl[j], c, 0, 0, 0);
            c = __builtin_amdgcn_mfma_f32_16x16x32_bf16(al[i], bh[j], c, 0, 0, 0);
            acc[i][j] = c;
        }
}

// ---------------------------------------------------------------------------
// Split-bf16 GEMM: C = A @ Bt^T + bias, inputs as hi/lo bf16 planes [M][K] and
// [N][K]; output hi (+ optional lo) bf16 planes. ~fp32 accuracy.
// R10: z-batched via zsA/zsB/zsC strides (blockIdx.z) for the per-expert
// W1eff pass; plain calls use grid.z=1, strides 0. Used ONLY for weight
// products now — the N_TOK-sized main GEMM is deleted (folded into expert1:
// hid = relu(x@(M@W1[e]) + b1eff[e]), same associativity lever as R9).
// ---------------------------------------------------------------------------
__global__ __launch_bounds__(256)
void gemm_split_kernel(const __hip_bfloat16* Ahi_, const __hip_bfloat16* Alo_,
                       const __hip_bfloat16* Bhi_, const __hip_bfloat16* Blo_,
                       const float* __restrict__ bias,
                       __hip_bfloat16* Chi_, __hip_bfloat16* Clo_, int K, int N,
                       size_t zsA, size_t zsB, size_t zsC)
{
    __shared__ __align__(16) short As[128 * 64];
    __shared__ __align__(16) short Bs[128 * 64];
    const short* Ahi = (const short*)Ahi_;
    const short* Alo = (const short*)Alo_;
    const short* Bhi = (const short*)Bhi_;
    const short* Blo = (const short*)Blo_;

    const int tid = threadIdx.x, lane = tid & 63, w = tid >> 6;
    const int wm = w & 1, wn = w >> 1;
    const size_t zA = (size_t)blockIdx.z * zsA;
    const size_t zB = (size_t)blockIdx.z * zsB;
    const size_t zC = (size_t)blockIdx.z * zsC;
    // logical tile from swizzled id: contiguous logical ids share a row-tile
    const int lin = blockIdx.y * gridDim.x + blockIdx.x;
    const int lgc = xcd_chunk(lin, gridDim.x * gridDim.y);
    const int row0 = (lgc / gridDim.x) * 128, col0 = (lgc % gridDim.x) * 128;
    const int lr = lane >> 3;
    const int g = (lane & 7) ^ lr;          // swizzled source chunk (const per lane)
    const int plane = g >> 2, colel = (g & 3) * 8;

    const short* pA[4];
    const short* pB[4];
#pragma unroll
    for (int i = 0; i < 4; ++i) {
        int r = w * 32 + i * 8 + lr;
        pA[i] = (plane ? Alo : Ahi) + zA + (size_t)(row0 + r) * K + colel;
        pB[i] = (plane ? Blo : Bhi) + zB + (size_t)(col0 + r) * K + colel;
    }

    floatx4 acc[4][4];
#pragma unroll
    for (int i = 0; i < 4; ++i)
#pragma unroll
        for (int j = 0; j < 4; ++j) acc[i][j] = (floatx4)(0.f);

    // prologue: prefetch K-step 0
    bf16x8 va[4], vb[4];
#pragma unroll
    for (int i = 0; i < 4; ++i) {
        va[i] = *(const bf16x8*)(pA[i]);
        vb[i] = *(const bf16x8*)(pB[i]);
    }

    for (int k0 = 0; k0 < K; k0 += 32) {
        __syncthreads();
#pragma unroll
        for (int i = 0; i < 4; ++i) {
            *(bf16x8*)(&As[(w * 32 + i * 8) * 64 + lane * 8]) = va[i];
            *(bf16x8*)(&Bs[(w * 32 + i * 8) * 64 + lane * 8]) = vb[i];
        }
        __syncthreads();
        if (k0 + 32 < K) {
#pragma unroll
            for (int i = 0; i < 4; ++i) {
                va[i] = *(const bf16x8*)(pA[i] + k0 + 32);
                vb[i] = *(const bf16x8*)(pB[i] + k0 + 32);
            }
        }
        tile_split(As, Bs, wm, wn, lane, acc);
    }

    const int m15 = lane & 15, quad = lane >> 4;
#pragma unroll
    for (int i = 0; i < 4; ++i) {
#pragma unroll
        for (int t = 0; t < 4; ++t) {
            int row = row0 + wm * 64 + i * 16 + quad * 4 + t;
            size_t rb = zC + (size_t)row * N;
#pragma unroll
            for (int j = 0; j < 4; ++j) {
                int col = col0 + wn * 64 + j * 16 + m15;
                float v = acc[i][j][t] + bias[col];
                __hip_bfloat16 hi = __float2bfloat16(v);
                Chi_[rb + col] = hi;
                if (Clo_) Clo_[rb + col] = __float2bfloat16(v - __bfloat162float(hi));
            }
        }
    }
}

// ---------------------------------------------------------------------------
// Expert layer 1 (R10): hid[slot] = relu(x[token] @ W1eff[e] + b1eff[e])
// SPLIT-bf16 on gathered x hi/lo planes vs W1eff hi/lo — replaces the old
// (main-GEMM -> a_bf -> plain expert1) path. Precision is better than before:
// no intermediate bf16 rounding of 'a'.
// ---------------------------------------------------------------------------
__global__ __launch_bounds__(256)
void expert1_kernel(const __hip_bfloat16* x_hi_, const __hip_bfloat16* x_lo_,
                    const __hip_bfloat16* W1e_hi_, const __hip_bfloat16* W1e_lo_,
                    const float* __restrict__ b1eff,
                    const int* __restrict__ assign_token, const int* __restrict__ offs,
                    const __hip_bfloat16* zrow_, __hip_bfloat16* hid_)
{
    __shared__ __align__(16) short As[128 * 64];
    __shared__ __align__(16) short Bs[128 * 64];
    const short* Xhi = (const short*)x_hi_;
    const short* Xlo = (const short*)x_lo_;
    const short* zrow = (const short*)zrow_;

    const int tid = threadIdx.x, lane = tid & 63, w = tid >> 6;
    const int wm = w & 1, wn = w >> 1;
    const int lin = blockIdx.y * gridDim.x + blockIdx.x;
    const int lgc = xcd_chunk(lin, gridDim.x * gridDim.y);
    const int row0 = (lgc / gridDim.x) * 128, col0 = (lgc % gridDim.x) * 128;
    const int lr = lane >> 3;
    const int g = (lane & 7) ^ lr;
    const int plane = g >> 2, colel = (g & 3) * 8;

    int e = NEXP - 1;
    for (int q = 0; q < NEXP; ++q) { if (row0 < offs[q + 1]) { e = q; break; } }
    const short* Bh = (const short*)W1e_hi_ + (size_t)e * HID * D_IN;
    const short* Bl = (const short*)W1e_lo_ + (size_t)e * HID * D_IN;

    const short* pA[4];
    const short* pB[4];
#pragma unroll
    for (int i = 0; i < 4; ++i) {
        int r = w * 32 + i * 8 + lr;
        int tok = assign_token[row0 + r];
        pA[i] = (tok >= 0 ? (plane ? Xlo : Xhi) + (size_t)tok * D_IN : zrow) + colel;
        pB[i] = (plane ? Bl : Bh) + (size_t)(col0 + r) * D_IN + colel;
    }

    floatx4 acc[4][4];
#pragma unroll
    for (int i = 0; i < 4; ++i)
#pragma unroll
        for (int j = 0; j < 4; ++j) acc[i][j] = (floatx4)(0.f);

    bf16x8 va[4], vb[4];
#pragma unroll
    for (int i = 0; i < 4; ++i) {
        va[i] = *(const bf16x8*)(pA[i]);
        vb[i] = *(const bf16x8*)(pB[i]);
    }

    for (int k0 = 0; k0 < D_IN; k0 += 32) {
        __syncthreads();
#pragma unroll
        for (int i = 0; i < 4; ++i) {
            *(bf16x8*)(&As[(w * 32 + i * 8) * 64 + lane * 8]) = va[i];
            *(bf16x8*)(&Bs[(w * 32 + i * 8) * 64 + lane * 8]) = vb[i];
        }
        __syncthreads();
        if (k0 + 32 < D_IN) {
#pragma unroll
            for (int i = 0; i < 4; ++i) {
                va[i] = *(const bf16x8*)(pA[i] + k0 + 32);
                vb[i] = *(const bf16x8*)(pB[i] + k0 + 32);
            }
        }
        tile_split(As, Bs, wm, wn, lane, acc);
    }

    const int m15 = lane & 15, quad = lane >> 4;
#pragma unroll
    for (int i = 0; i < 4; ++i) {
#pragma unroll
        for (int t = 0; t < 4; ++t) {
            int row = row0 + wm * 64 + i * 16 + quad * 4 + t;
            size_t rb = (size_t)row * HID;
#pragma unroll
            for (int j = 0; j < 4; ++j) {
                int col = col0 + wn * 64 + j * 16 + m15;
                float v = acc[i][j][t] + b1eff[(size_t)e * HID + col];
                hid_[rb + col] = __float2bfloat16(fmaxf(v, 0.f));
            }
        }
    }
}

// ---------------------------------------------------------------------------
// Expert layer 2: exp_out[slot] = hid[slot] @ W2t[e]^T
// ---------------------------------------------------------------------------
__global__ __launch_bounds__(256)
void expert2_kernel(const __hip_bfloat16* hid_, const __hip_bfloat16* W2t_,
                    const int* __restrict__ offs, __hip_bfloat16* exp_out_)
{
    __shared__ __align__(16) short As[128 * 64];
    __shared__ __align__(16) short Bs[128 * 64];
    const short* A = (const short*)hid_;

    const int tid = threadIdx.x, lane = tid & 63, w = tid >> 6;
    const int wm = w & 1, wn = w >> 1;
    const int lin = blockIdx.y * gridDim.x + blockIdx.x;
    const int lgc = xcd_chunk(lin, gridDim.x * gridDim.y);
    const int row0 = (lgc / gridDim.x) * 128, col0 = (lgc % gridDim.x) * 128;
    const int lr = lane >> 3, g = (lane & 7) ^ lr, colel = g * 8;

    int e = NEXP - 1;
    for (int q = 0; q < NEXP; ++q) { if (row0 < offs[q + 1]) { e = q; break; } }
    const short* B = (const short*)W2t_ + (size_t)e * D_OUT * HID;

    const short* pA[4];
    const short* pB[4];
#pragma unroll
    for (int i = 0; i < 4; ++i) {
        int r = w * 32 + i * 8 + lr;
        pA[i] = A + (size_t)(row0 + r) * HID + colel;
        pB[i] = B + (size_t)(col0 + r) * HID + colel;
    }

    floatx4 acc[4][4];
#pragma unroll
    for (int i = 0; i < 4; ++i)
#pragma unroll
        for (int j = 0; j < 4; ++j) acc[i][j] = (floatx4)(0.f);

    bf16x8 va[4], vb[4];
#pragma unroll
    for (int i = 0; i < 4; ++i) {
        va[i] = *(const bf16x8*)(pA[i]);
        vb[i] = *(const bf16x8*)(pB[i]);
    }

    for (int k0 = 0; k0 < HID; k0 += 64) {
        __syncthreads();
#pragma unroll
        for (int i = 0; i < 4; ++i) {
            *(bf16x8*)(&As[(w * 32 + i * 8) * 64 + lane * 8]) = va[i];
            *(bf16x8*)(&Bs[(w * 32 + i * 8) * 64 + lane * 8]) = vb[i];
        }
        __syncthreads();
        if (k0 + 64 < HID) {
#pragma unroll
            for (int i = 0; i < 4; ++i) {
                va[i] = *(const bf16x8*)(pA[i] + k0 + 64);
                vb[i] = *(const bf16x8*)(pB[i] + k0 + 64);
            }
        }
        tile_plain(As, Bs, wm, wn, lane, acc);
    }

    const int m15 = lane & 15, quad = lane >> 4;
#pragma unroll
    for (int i = 0; i < 4; ++i) {
#pragma unroll
        for (int t = 0; t < 4; ++t) {
            int row = row0 + wm * 64 + i * 16 + quad * 4 + t;
            size_t rb = (size_t)row * D_OUT;
#pragma unroll
            for (int j = 0; j < 4; ++j) {
                int col = col0 + wn * 64 + j * 16 + m15;
                exp_out_[rb + col] = __float2bfloat16(acc[i][j][t]);
            }
        }
    }
}

// ---------------------------------------------------------------------------
// FUSED x-convert + gate (atomic-free). One token per wave.
// ---------------------------------------------------------------------------
__global__ __launch_bounds__(256)
void convert_gate_kernel(const float* __restrict__ x, const float* __restrict__ MgT,
                         const float* __restrict__ bgeff,
                         __hip_bfloat16* __restrict__ x_hi, __hip_bfloat16* __restrict__ x_lo,
                         int* __restrict__ route_e, float* __restrict__ route_w)
{
    const int wave = threadIdx.x >> 6, lane = threadIdx.x & 63;
    const int n = blockIdx.x * 4 + wave;
    const float* xrow = x + (size_t)n * D_IN;

    float4 v[4];
#pragma unroll
    for (int it = 0; it < 4; ++it)
        v[it] = *(const float4*)(xrow + it * 256 + lane * 4);

    float p[NEXP];
#pragma unroll
    for (int e = 0; e < NEXP; ++e) p[e] = 0.f;

#pragma unroll
    for (int it = 0; it < 4; ++it) {
        const int d = it * 256 + lane * 4;
        union { __hip_bfloat16 b[4]; short4 s; } uh, ul;
        uh.b[0] = __float2bfloat16(v[it].x); ul.b[0] = __float2bfloat16(v[it].x - __bfloat162float(uh.b[0]));
        uh.b[1] = __float2bfloat16(v[it].y); ul.b[1] = __float2bfloat16(v[it].y - __bfloat162float(uh.b[1]));
        uh.b[2] = __float2bfloat16(v[it].z); ul.b[2] = __float2bfloat16(v[it].z - __bfloat162float(uh.b[2]));
        uh.b[3] = __float2bfloat16(v[it].w); ul.b[3] = __float2bfloat16(v[it].w - __bfloat162float(uh.b[3]));
        *(short4*)(x_hi + (size_t)n * D_IN + d) = uh.s;
        *(short4*)(x_lo + (size_t)n * D_IN + d) = ul.s;
#pragma unroll
        for (int e = 0; e < NEXP; ++e) {
            const float4 m = *(const float4*)(MgT + (size_t)e * 1024 + d);
            p[e] += v[it].x * m.x + v[it].y * m.y + v[it].z * m.z + v[it].w * m.w;
        }
    }

#pragma unroll
    for (int e = 0; e < NEXP; ++e) {
        float t = p[e];
        for (int off = 32; off > 0; off >>= 1) t += __shfl_down(t, off);
        p[e] = t;
    }
    if (lane == 0) {
        float lg[NEXP];
#pragma unroll
        for (int e = 0; e < NEXP; ++e) lg[e] = p[e] + bgeff[e];
        int e0 = 0; float v0 = lg[0];
        for (int e = 1; e < NEXP; ++e) if (lg[e] > v0) { v0 = lg[e]; e0 = e; }
        int e1 = -1; float v1 = -3.0e38f;
        for (int e = 0; e < NEXP; ++e) {
            if (e == e0) continue;
            if (lg[e] > v1) { v1 = lg[e]; e1 = e; }
        }
        float w0 = 1.f / (1.f + expf(v1 - v0));   // softmax + top-2 renorm
        float w1 = 1.f - w0;
        route_e[n * 2]     = e0;
        route_e[n * 2 + 1] = e1;
        route_w[n * 2]     = w0;
        route_w[n * 2 + 1] = w1;
    }
}

// ---------------------------------------------------------------------------
// Histogram of route_e into counts[NEXP] (LDS histogram, 640 global atomics).
// ---------------------------------------------------------------------------
__global__ __launch_bounds__(256)
void count_kernel(const int* __restrict__ route_e, int* __restrict__ counts)
{
    __shared__ int h[NEXP];
    if (threadIdx.x < NEXP) h[threadIdx.x] = 0;
    __syncthreads();
    const int i = blockIdx.x * 512 + threadIdx.x;   // 64 blocks * 512 = 32768
    atomicAdd(&h[route_e[i]], 1);
    atomicAdd(&h[route_e[i + 256]], 1);
    __syncthreads();
    if (threadIdx.x < NEXP) atomicAdd(&counts[threadIdx.x], h[threadIdx.x]);
}

// ---------------------------------------------------------------------------
// fp32 [R][C] -> transposed bf16 [C][R] hi (+ optional lo); batched over z.
// ---------------------------------------------------------------------------
__global__ __launch_bounds__(256)
void transpose_cvt_kernel(const float* __restrict__ in, __hip_bfloat16* out_hi,
                          __hip_bfloat16* out_lo, int R, int C)
{
    __shared__ float t[32][33];
    const size_t zoff = (size_t)blockIdx.z * R * C;
    in += zoff; out_hi += zoff; if (out_lo) out_lo += zoff;
    const int c0 = blockIdx.x * 32, r0 = blockIdx.y * 32;
    const int tx = threadIdx.x & 31, ty = threadIdx.x >> 5;
#pragma unroll
    for (int i = 0; i < 4; ++i)
        t[ty + i * 8][tx] = in[(size_t)(r0 + ty + i * 8) * C + (c0 + tx)];
    __syncthreads();
#pragma unroll
    for (int i = 0; i < 4; ++i) {
        float v = t[tx][ty + i * 8];
        size_t o = (size_t)(c0 + ty + i * 8) * R + (r0 + tx);
        __hip_bfloat16 hi = __float2bfloat16(v);
        out_hi[o] = hi;
        if (out_lo) out_lo[o] = __float2bfloat16(v - __bfloat162float(hi));
    }
}

// ---------------------------------------------------------------------------
// Plain (non-transposing) fp32 -> hi/lo bf16 planes, float4-vectorized.
// ---------------------------------------------------------------------------
__global__ __launch_bounds__(256)
void convert_plain_kernel(const float* __restrict__ in,
                          __hip_bfloat16* __restrict__ out_hi,
                          __hip_bfloat16* __restrict__ out_lo)
{
    const int i = blockIdx.x * 256 + threadIdx.x;
    const float4 v = ((const float4*)in)[i];
    union { __hip_bfloat16 b[4]; short4 s; } uh, ul;
    uh.b[0] = __float2bfloat16(v.x); ul.b[0] = __float2bfloat16(v.x - __bfloat162float(uh.b[0]));
    uh.b[1] = __float2bfloat16(v.y); ul.b[1] = __float2bfloat16(v.y - __bfloat162float(uh.b[1]));
    uh.b[2] = __float2bfloat16(v.z); ul.b[2] = __float2bfloat16(v.z - __bfloat162float(uh.b[2]));
    uh.b[3] = __float2bfloat16(v.w); ul.b[3] = __float2bfloat16(v.w - __bfloat162float(uh.b[3]));
    ((short4*)out_hi)[i] = uh.s;
    ((short4*)out_lo)[i] = ul.s;
}

// ---------------------------------------------------------------------------
// Folded main-chain bias  beff2[n] = bp@(Wv@Wo)[:,n] + bv@Wo[:,n] + bo[n]
// using hi+lo reconstruction of Pt=(Wv@Wo)^T and Wot=Wo^T. One wave per n.
// ---------------------------------------------------------------------------
__global__ __launch_bounds__(256)
void bias2_kernel(const float* __restrict__ bp, const float* __restrict__ bv,
                  const float* __restrict__ bo,
                  const __hip_bfloat16* __restrict__ Pt_hi,
                  const __hip_bfloat16* __restrict__ Pt_lo,
                  const __hip_bfloat16* __restrict__ Wot_hi,
                  const __hip_bfloat16* __restrict__ Wot_lo,
                  float* __restrict__ beff2)
{
    const int wave = threadIdx.x >> 6, lane = threadIdx.x & 63;
    const int n = blockIdx.x * 4 + wave;
    float acc = 0.f;
    for (int k = lane; k < D_MODEL; k += 64) {
        const size_t o = (size_t)n * D_MODEL + k;
        float pt = __bfloat162float(Pt_hi[o]) + __bfloat162float(Pt_lo[o]);
        float wo = __bfloat162float(Wot_hi[o]) + __bfloat162float(Wot_lo[o]);
        acc += bp[k] * pt + bv[k] * wo;
    }
    for (int off = 32; off > 0; off >>= 1) acc += __shfl_down(acc, off);
    if (lane == 0) beff2[n] = acc + bo[n];
}

// ---------------------------------------------------------------------------
// R10: b1eff[e][h] = beff2 @ W1[e][:,h] + b1[e][h], via W1t hi+lo (~fp32).
// One wave per output (n = e*HID + h), 2560 outputs -> 640 blocks.
// ---------------------------------------------------------------------------
__global__ __launch_bounds__(256)
void b1eff_kernel(const float* __restrict__ beff2,
                  const __hip_bfloat16* __restrict__ W1t_hi,
                  const __hip_bfloat16* __restrict__ W1t_lo,
                  const float* __restrict__ b1, float* __restrict__ b1eff)
{
    const int wave = threadIdx.x >> 6, lane = threadIdx.x & 63;
    const int n = blockIdx.x * 4 + wave;     // [0, NEXP*HID)
    const size_t base = (size_t)n * D_MODEL;
    float acc = 0.f;
    for (int k = lane; k < D_MODEL; k += 64)
        acc += beff2[k] * (__bfloat162float(W1t_hi[base + k]) +
                           __bfloat162float(W1t_lo[base + k]));
    for (int off = 32; off > 0; off >>= 1) acc += __shfl_down(acc, off);
    if (lane == 0) b1eff[n] = acc + b1[n];
}

// ---------------------------------------------------------------------------
// Thin fp32 GEMM for gate-matrix chain: Cm = A[1024][1024] @ B[1024][10];
// trans=0 -> Cm[m][10]; trans=1 -> Cm[e][1024] (transposed write for MgT).
// ---------------------------------------------------------------------------
__global__ __launch_bounds__(256)
void wchain_kernel(const float* __restrict__ A, const float* __restrict__ B,
                   float* __restrict__ Cm, int trans)
{
    const int wave = threadIdx.x >> 6, lane = threadIdx.x & 63;
    const int m = blockIdx.x * 4 + wave;
    float acc[NEXP];
#pragma unroll
    for (int e = 0; e < NEXP; ++e) acc[e] = 0.f;
    const float* ar = A + (size_t)m * 1024;
    for (int d = lane; d < 1024; d += 64) {
        float av = ar[d];
        const float* br = B + (size_t)d * NEXP;
#pragma unroll
        for (int e = 0; e < NEXP; ++e) acc[e] += av * br[e];
    }
#pragma unroll
    for (int e = 0; e < NEXP; ++e) {
        float v = acc[e];
        for (int off = 32; off > 0; off >>= 1) v += __shfl_down(v, off);
        if (lane == 0) Cm[trans ? ((size_t)e * 1024 + m) : ((size_t)m * NEXP + e)] = v;
    }
}

// ---------------------------------------------------------------------------
// bg_eff = bg + bo@Wg + bv@t1 + bp@t2    (single block)
// ---------------------------------------------------------------------------
__global__ __launch_bounds__(256)
void bias_eff_kernel(const float* __restrict__ bp, const float* __restrict__ bv,
                     const float* __restrict__ bo, const float* __restrict__ bg,
                     const float* __restrict__ Wg, const float* __restrict__ t1,
                     const float* __restrict__ t2, float* __restrict__ bgeff)
{
    __shared__ float red[256];
    const int tid = threadIdx.x;
    float acc[NEXP];
#pragma unroll
    for (int e = 0; e < NEXP; ++e) acc[e] = 0.f;
    for (int d = tid; d < 1024; d += 256) {
        float o = bo[d], v = bv[d], p = bp[d];
#pragma unroll
        for (int e = 0; e < NEXP; ++e)
            acc[e] += o * Wg[d * NEXP + e] + v * t1[d * NEXP + e] + p * t2[d * NEXP + e];
    }
    for (int e = 0; e < NEXP; ++e) {
        red[tid] = acc[e];
        __syncthreads();
        for (int s = 128; s > 0; s >>= 1) {
            if (tid < s) red[tid] += red[tid + s];
            __syncthreads();
        }
        if (tid == 0) bgeff[e] = red[0] + bg[e];
        __syncthreads();
    }
}

// ---------------------------------------------------------------------------
__global__ __launch_bounds__(256)
void init_kernel(int* __restrict__ counts, int* __restrict__ cursors,
                 int* __restrict__ assign_token, int* __restrict__ zrow_i,
                 float* __restrict__ fzero)
{
    int i = blockIdx.x * 256 + threadIdx.x;
    if (i < NEXP) { counts[i] = 0; cursors[i] = 0; }
    if (i < 512) zrow_i[i] = 0;                 // 1024 bf16 zeros
    if (i < 1024) fzero[i] = 0.f;               // fp32 zero bias for wt-product GEMMs
    if (i < A_CAP) assign_token[i] = -1;
}

__global__ void offsets_kernel(const int* __restrict__ counts, int* __restrict__ offs)
{
    if (threadIdx.x == 0 && blockIdx.x == 0) {
        int acc = 0;
        for (int e = 0; e < NEXP; ++e) {
            offs[e] = acc;
            acc += (counts[e] + EPAD - 1) / EPAD * EPAD;
        }
        offs[NEXP] = acc;
    }
}

// ---------------------------------------------------------------------------
// Scatter with WAVE-AGGREGATED cursor atomics (R6): <=10 atomics/wave via
// ballot+popcount vs 32768 contended return-value atomics before.
// ---------------------------------------------------------------------------
__global__ __launch_bounds__(256)
void scatter_kernel(const int* __restrict__ route_e,
                    const int* __restrict__ offs, int* __restrict__ cursors,
                    int* __restrict__ assign_token, int* __restrict__ slot_of)
{
    const int i = blockIdx.x * 256 + threadIdx.x;
    const int lane = threadIdx.x & 63;
    const int e = route_e[i];
    int slot = 0;
#pragma unroll
    for (int q = 0; q < NEXP; ++q) {
        unsigned long long mask = __ballot(e == q);
        if (e == q) {
            const int leader = (int)__ffsll((long long)mask) - 1;
            const int rank = (int)__popcll(mask & ((1ull << lane) - 1ull));
            int base = 0;
            if (lane == leader) base = atomicAdd(&cursors[q], (int)__popcll(mask));
            base = __shfl(base, leader);
            slot = offs[q] + base + rank;
        }
    }
    assign_token[slot] = i >> 1;
    slot_of[i] = slot;
}

// ---------------------------------------------------------------------------
// Combine (gather): out[n] = w0*(row(s0)+b2[e0]) + w1*(row(s1)+b2[e1])
// ---------------------------------------------------------------------------
__global__ __launch_bounds__(256)
void combine_kernel(const __hip_bfloat16* __restrict__ exp_out,
                    const int* __restrict__ slot_of, const int* __restrict__ route_e,
                    const float* __restrict__ route_w, const float* __restrict__ b2,
                    float* __restrict__ out)
{
    const int n = blockIdx.x;
    const int c = threadIdx.x * 4;
    const int s0 = slot_of[n * 2],  s1 = slot_of[n * 2 + 1];
    const int e0 = route_e[n * 2],  e1 = route_e[n * 2 + 1];
    const float w0 = route_w[n * 2], w1 = route_w[n * 2 + 1];

    union U { float2 f2; __hip_bfloat16 b[4]; } u0, u1;
    u0.f2 = *(const float2*)(exp_out + (size_t)s0 * D_OUT + c);
    u1.f2 = *(const float2*)(exp_out + (size_t)s1 * D_OUT + c);
    const float4 bb0 = *(const float4*)(b2 + (size_t)e0 * D_OUT + c);
    const float4 bb1 = *(const float4*)(b2 + (size_t)e1 * D_OUT + c);

    float4 o;
    o.x = w0 * (__bfloat162float(u0.b[0]) + bb0.x) + w1 * (__bfloat162float(u1.b[0]) + bb1.x);
    o.y = w0 * (__bfloat162float(u0.b[1]) + bb0.y) + w1 * (__bfloat162float(u1.b[1]) + bb1.y);
    o.z = w0 * (__bfloat162float(u0.b[2]) + bb0.z) + w1 * (__bfloat162float(u1.b[2]) + bb1.z);
    o.w = w0 * (__bfloat162float(u0.b[3]) + bb0.w) + w1 * (__bfloat162float(u1.b[3]) + bb1.w);
    *(float4*)(out + (size_t)n * D_OUT + c) = o;
}

// ---------------------------------------------------------------------------
extern "C" void kernel_launch(void* const* d_in, const int* in_sizes, int n_in,
                              void* d_out, int out_size, void* d_ws, size_t ws_size,
                              hipStream_t stream)
{
    const float* x  = (const float*)d_in[0];
    const float* Wp = (const float*)d_in[2];
    const float* bp = (const float*)d_in[3];
    const float* Wv = (const float*)d_in[4];
    const float* bv = (const float*)d_in[5];
    const float* Wo = (const float*)d_in[6];
    const float* bo = (const float*)d_in[7];
    const float* Wg = (const float*)d_in[8];
    const float* bg = (const float*)d_in[9];
    const float* W1 = (const float*)d_in[10];
    const float* b1 = (const float*)d_in[11];
    const float* W2 = (const float*)d_in[12];
    const float* b2 = (const float*)d_in[13];
    float* out = (float*)d_out;

    // ---- workspace layout (bytes); lifetime-based aliasing ----
    // R10: N_TOK main GEMM deleted (folded into expert1 via W1eff = M@W1[e]).
    // x planes now live until expert1 completes; exp_out (written by expert2,
    // strictly after) may alias them.
    char* W = (char*)d_ws;
    typedef __hip_bfloat16 bf;
    bf* x_hi  = (bf*)(W + 0);                  // [N,D]  read by expert1 (gather)
    bf* x_lo  = (bf*)(W + 33554432);
    bf* exp_out = (bf*)(W + 0);                // [A_CAP,D_OUT] 69.7MB (post-expert1)
    bf* hid   = (bf*)(W + 69730304);           // [A_CAP,HID] ends ~87.2MB
    // weight-product scratch (88..100MB)
    bf* Wvr_hi = (bf*)(W + 88080384);          // Wv row-major hi/lo
    bf* Wvr_lo = (bf*)(W + 90177536);
    bf* Wpr_hi = (bf*)(W + 92274688);          // Wp row-major hi/lo
    bf* Wpr_lo = (bf*)(W + 94371840);
    float* fzero = (float*)(W + 96468992);     // 1024 fp32 zeros
    float* beff2 = (float*)(W + 96473088);     // folded main-chain bias [1024]
    // R10 new (100..117MB)
    bf* W1t_lo   = (bf*)(W + 100663296);       // [E][HID][D] lo plane (5.24MB)
    bf* W1eff_hi = (bf*)(W + 105906176);       // (M@W1[e])^T hi  [E][HID][D_IN]
    bf* W1eff_lo = (bf*)(W + 111149056);       //                lo
    float* b1eff = (float*)(W + 116391936);    // [E][HID] fp32
    // weights / products (alive whole run)
    bf* Pt_hi  = (bf*)(W + 134217728);         // (Wv@Wo)^T hi/lo
    bf* Pt_lo  = (bf*)(W + 136314880);
    bf* Mrow_hi = (bf*)(W + 138412032);        // M = Wp@Wv@Wo ROW-major hi/lo
    bf* Mrow_lo = (bf*)(W + 140509184);
    bf* Wot_hi = (bf*)(W + 142606336);
    bf* Wot_lo = (bf*)(W + 144703488);
    bf* W1t    = (bf*)(W + 146800640);         // [E][HID][D] hi plane
    bf* W2t    = (bf*)(W + 152043520);         // [E][D_OUT][HID]
    // small buffers
    bf*    zrow         = (bf*)(W + 157286400);       // 1024 bf16 zeros
    int*   route_e      = (int*)(W + 157288448);
    float* route_w      = (float*)(W + 157419520);
    int*   slot_of      = (int*)(W + 157550592);
    int*   assign_token = (int*)(W + 157681664);
    int*   counts       = (int*)(W + 157817856);
    int*   offs         = (int*)(W + 157817920);
    int*   cursors      = (int*)(W + 157817984);
    float* MgT          = (float*)(W + 157818048);    // [10][1024] transposed
    float* t1           = (float*)(W + 157859008);
    float* t2           = (float*)(W + 157899968);
    float* bgeff        = (float*)(W + 157940928);

    dim3 blk(256);

    // ---- init first (zeros fzero used as bias by the product passes) ----
    init_kernel<<<(A_CAP + 255) / 256, blk, 0, stream>>>(counts, cursors, assign_token,
                                                         (int*)zrow, fzero);

    // ---- weight conversions ----
    transpose_cvt_kernel<<<dim3(32, 32, 1), blk, 0, stream>>>(Wo, Wot_hi, Wot_lo, D_MODEL, D_MODEL);
    convert_plain_kernel<<<1024, blk, 0, stream>>>(Wv, Wvr_hi, Wvr_lo);
    convert_plain_kernel<<<1024, blk, 0, stream>>>(Wp, Wpr_hi, Wpr_lo);
    transpose_cvt_kernel<<<dim3(HID / 32, D_MODEL / 32, NEXP), blk, 0, stream>>>(W1, W1t, W1t_lo, D_MODEL, HID);
    transpose_cvt_kernel<<<dim3(D_OUT / 32, HID / 32, NEXP), blk, 0, stream>>>(W2, W2t, nullptr, HID, D_OUT);

    // ---- gate matrix chain (fp32, exactness-preserving associativity) ----
    wchain_kernel<<<256, blk, 0, stream>>>(Wo, Wg, t1, 0);   // t1 = Wo@Wg
    wchain_kernel<<<256, blk, 0, stream>>>(Wv, t1, t2, 0);   // t2 = Wv@t1
    wchain_kernel<<<256, blk, 0, stream>>>(Wp, t2, MgT, 1);  // MgT = (Wp@t2)^T
    bias_eff_kernel<<<1, blk, 0, stream>>>(bp, bv, bo, bg, Wg, t1, t2, bgeff);

    // ---- weight-product passes (split-bf16, hi/lo outputs) ----
    dim3 pgrid(D_MODEL / 128, D_MODEL / 128, 1);   // (8, 8)
    // Pt[n][k] = (Wv@Wo)[k][n] :  A = Wot, Bt = Wv row-major
    gemm_split_kernel<<<pgrid, blk, 0, stream>>>(Wot_hi, Wot_lo, Wvr_hi, Wvr_lo, fzero,
                                                 Pt_hi, Pt_lo, D_MODEL, D_MODEL, 0, 0, 0);
    // Mrow[k'][k] = (Wp@Wv@Wo)[k'][k] :  A = Wp row-major, Bt = Pt
    gemm_split_kernel<<<pgrid, blk, 0, stream>>>(Wpr_hi, Wpr_lo, Pt_hi, Pt_lo, fzero,
                                                 Mrow_hi, Mrow_lo, D_MODEL, D_MODEL, 0, 0, 0);
    // folded main-chain bias: beff2 = bp@(Wv@Wo) + bv@Wo + bo
    bias2_kernel<<<D_MODEL / 4, blk, 0, stream>>>(bp, bv, bo, Pt_hi, Pt_lo,
                                                  Wot_hi, Wot_lo, beff2);
    // b1eff[e] = beff2@W1[e] + b1[e]
    b1eff_kernel<<<NEXP * HID / 4, blk, 0, stream>>>(beff2, W1t, W1t_lo, b1, b1eff);
    // W1eff_t[e][h][k'] = (M@W1[e])^T :  A = W1t[e] (hi/lo), Bt = Mrow, batched z=e
    dim3 wgrid(D_IN / 128, HID / 128, NEXP);       // (8, 2, 10)
    gemm_split_kernel<<<wgrid, blk, 0, stream>>>(W1t, W1t_lo, Mrow_hi, Mrow_lo, fzero,
                                                 W1eff_hi, W1eff_lo, D_MODEL, D_IN,
                                                 (size_t)HID * D_MODEL, 0,
                                                 (size_t)HID * D_IN);

    // ---- fused convert/gate (atomic-free) + count + scatter ----
    convert_gate_kernel<<<N_TOK / 4, blk, 0, stream>>>(x, MgT, bgeff, x_hi, x_lo,
                                                       route_e, route_w);
    count_kernel<<<2 * N_TOK / 512, blk, 0, stream>>>(route_e, counts);
    offsets_kernel<<<1, 64, 0, stream>>>(counts, offs);
    scatter_kernel<<<2 * N_TOK / 256, blk, 0, stream>>>(route_e, offs, cursors,
                                                        assign_token, slot_of);

    // ---- experts: layer1 split-bf16 on gathered x (main GEMM folded in) ----
    expert1_kernel<<<dim3(HID / 128, A_CAP / 128), blk, 0, stream>>>(
        x_hi, x_lo, W1eff_hi, W1eff_lo, b1eff, assign_token, offs, zrow, hid);
    expert2_kernel<<<dim3(D_OUT / 128, A_CAP / 128), blk, 0, stream>>>(
        hid, W2t, offs, exp_out);
    combine_kernel<<<N_TOK, blk, 0, stream>>>(exp_out, slot_of, route_e, route_w, b2, out);
}

// Round 8
// 524.798 us; speedup vs baseline: 3.1905x; 1.0214x over previous
//
#include <hip/hip_runtime.h>
#include <hip/hip_bf16.h>
#include <math.h>

#define N_TOK   16384
#define D_IN    1024
#define D_MODEL 1024
#define HID     256
#define NEXP    10
#define D_OUT   1024

// Expert routing: pad each expert's list to a multiple of EPAD so every
// 128-row tile is single-expert. Static capacity => static grid (graph-safe).
#define EPAD 128
#define A_CAP (2*N_TOK + NEXP*EPAD)   // 34048 = 266 * 128

typedef __attribute__((ext_vector_type(8))) __bf16 bf16x8;
typedef __attribute__((ext_vector_type(4))) float floatx4;

// ---------------------------------------------------------------------------
// XCD-chunked block swizzle (bijective): R8 confirmed — FETCH 290MB -> 77MB
// (~ideal) on the big GEMM. Keep on all MFMA kernels.
// ---------------------------------------------------------------------------
__device__ __forceinline__ int xcd_chunk(int orig, int nwg)
{
    const int q = nwg >> 3, r = nwg & 7;
    const int c = orig & 7, j = orig >> 3;
    return (c < r ? c * (q + 1) : r * (q + 1) + (c - r) * q) + j;
}

// ---------------------------------------------------------------------------
// LDS tile layout (per 128x64-short tile): row = 128 bytes = 8 chunks of 16B.
// Chunk g of row r is stored at position g ^ (r&7); staging applies the inverse
// swizzle on the per-lane *global* source address, so the LDS store is simply
// rowgroup_base + lane*16B.
// ---------------------------------------------------------------------------
__device__ __forceinline__ bf16x8 lds_frag(const short* base, int row, int chunk)
{
    return *(const bf16x8*)(base + row * 64 + (chunk << 3));
}

// plain bf16: tile covers K-step 64 (chunks 0..7 = k 0..63)
__device__ __forceinline__ void tile_plain(const short* As, const short* Bs,
                                           int wm, int wn, int lane, floatx4 acc[4][4])
{
    const int m15 = lane & 15, quad = lane >> 4, sw = m15 & 7;
#pragma unroll
    for (int kk = 0; kk < 2; ++kk) {
        bf16x8 af[4], bfr[4];
#pragma unroll
        for (int i = 0; i < 4; ++i)
            af[i] = lds_frag(As, wm * 64 + i * 16 + m15, ((kk << 2) + quad) ^ sw);
#pragma unroll
        for (int j = 0; j < 4; ++j)
            bfr[j] = lds_frag(Bs, wn * 64 + j * 16 + m15, ((kk << 2) + quad) ^ sw);
#pragma unroll
        for (int i = 0; i < 4; ++i)
#pragma unroll
            for (int j = 0; j < 4; ++j)
                acc[i][j] = __builtin_amdgcn_mfma_f32_16x16x32_bf16(af[i], bfr[j],
                                                                    acc[i][j], 0, 0, 0);
    }
}

// split bf16 (3-term): tile covers K-step 32; chunks 0..3 = hi, 4..7 = lo.
// acc += Ah*Bh + Ah*Bl + Al*Bh  (Al*Bl ~ 2^-18, dropped)
__device__ __forceinline__ void tile_split(const short* As, const short* Bs,
                                           int wm, int wn, int lane, floatx4 acc[4][4])
{
    const int m15 = lane & 15, quad = lane >> 4, sw = m15 & 7;
    bf16x8 ah[4], al[4], bh[4], bl[4];
#pragma unroll
    for (int i = 0; i < 4; ++i) {
        int r = wm * 64 + i * 16 + m15;
        ah[i] = lds_frag(As, r, quad ^ sw);
        al[i] = lds_frag(As, r, (4 + quad) ^ sw);
    }
#pragma unroll
    for (int j = 0; j < 4; ++j) {
        int r = wn * 64 + j * 16 + m15;
        bh[j] = lds_frag(Bs, r, quad ^ sw);
        bl[j] = lds_frag(Bs, r, (4 + quad) ^ sw);
    }
#pragma unroll
    for (int i = 0; i < 4; ++i)
#pragma unroll
        for (int j = 0; j < 4; ++j) {
            floatx4 c = acc[i][j];
            c = __builtin_amdgcn_mfma_f32_16x16x32_bf16(ah[i], bh[j], c, 0, 0, 0);
            c = __builtin_amdgcn_mfma_f32_16x16x32_bf16(ah[i], bl[j], c, 0, 0, 0);
            c = __builtin_amdgcn_mfma_f32_16x16x32_bf16(al[i], bh[j], c, 0, 0, 0);
            acc[i][j] = c;
        }
}

// R11: 2-term split (A split, B hi-only): acc += Ah*Bh + Al*Bh.
// Drops the Ah*Bl term (~3e-4 rms on hid, below the bf16-storage floor that
// pins absmax at 2^-10). 32 MFMA per K-step vs 48 -> -33% MFMA on expert1.
// Bs chunks 4..7 are staged but never read.
__device__ __forceinline__ void tile_split_a(const short* As, const short* Bs,
                                             int wm, int wn, int lane, floatx4 acc[4][4])
{
    const int m15 = lane & 15, quad = lane >> 4, sw = m15 & 7;
    bf16x8 ah[4], al[4], bh[4];
#pragma unroll
    for (int i = 0; i < 4; ++i) {
        int r = wm * 64 + i * 16 + m15;
        ah[i] = lds_frag(As, r, quad ^ sw);
        al[i] = lds_frag(As, r, (4 + quad) ^ sw);
    }
#pragma unroll
    for (int j = 0; j < 4; ++j) {
        int r = wn * 64 + j * 16 + m15;
        bh[j] = lds_frag(Bs, r, quad ^ sw);
    }
#pragma unroll
    for (int i = 0; i < 4; ++i)
#pragma unroll
        for (int j = 0; j < 4; ++j) {
            floatx4 c = acc[i][j];
            c = __builtin_amdgcn_mfma_f32_16x16x32_bf16(ah[i], bh[j], c, 0, 0, 0);
            c = __builtin_amdgcn_mfma_f32_16x16x32_bf16(al[i], bh[j], c, 0, 0, 0);
            acc[i][j] = c;
        }
}

// ---------------------------------------------------------------------------
// Split-bf16 GEMM: C = A @ Bt^T + bias, inputs as hi/lo bf16 planes [M][K] and
// [N][K]; output hi (+ optional lo) bf16 planes. ~fp32 accuracy.
// z-batched via zsA/zsB/zsC strides (blockIdx.z) for the per-expert W1eff
// pass; plain calls use grid.z=1, strides 0. Weight products only.
// ---------------------------------------------------------------------------
__global__ __launch_bounds__(256)
void gemm_split_kernel(const __hip_bfloat16* Ahi_, const __hip_bfloat16* Alo_,
                       const __hip_bfloat16* Bhi_, const __hip_bfloat16* Blo_,
                       const float* __restrict__ bias,
                       __hip_bfloat16* Chi_, __hip_bfloat16* Clo_, int K, int N,
                       size_t zsA, size_t zsB, size_t zsC)
{
    __shared__ __align__(16) short As[128 * 64];
    __shared__ __align__(16) short Bs[128 * 64];
    const short* Ahi = (const short*)Ahi_;
    const short* Alo = (const short*)Alo_;
    const short* Bhi = (const short*)Bhi_;
    const short* Blo = (const short*)Blo_;

    const int tid = threadIdx.x, lane = tid & 63, w = tid >> 6;
    const int wm = w & 1, wn = w >> 1;
    const size_t zA = (size_t)blockIdx.z * zsA;
    const size_t zB = (size_t)blockIdx.z * zsB;
    const size_t zC = (size_t)blockIdx.z * zsC;
    const int lin = blockIdx.y * gridDim.x + blockIdx.x;
    const int lgc = xcd_chunk(lin, gridDim.x * gridDim.y);
    const int row0 = (lgc / gridDim.x) * 128, col0 = (lgc % gridDim.x) * 128;
    const int lr = lane >> 3;
    const int g = (lane & 7) ^ lr;          // swizzled source chunk (const per lane)
    const int plane = g >> 2, colel = (g & 3) * 8;

    const short* pA[4];
    const short* pB[4];
#pragma unroll
    for (int i = 0; i < 4; ++i) {
        int r = w * 32 + i * 8 + lr;
        pA[i] = (plane ? Alo : Ahi) + zA + (size_t)(row0 + r) * K + colel;
        pB[i] = (plane ? Blo : Bhi) + zB + (size_t)(col0 + r) * K + colel;
    }

    floatx4 acc[4][4];
#pragma unroll
    for (int i = 0; i < 4; ++i)
#pragma unroll
        for (int j = 0; j < 4; ++j) acc[i][j] = (floatx4)(0.f);

    // prologue: prefetch K-step 0
    bf16x8 va[4], vb[4];
#pragma unroll
    for (int i = 0; i < 4; ++i) {
        va[i] = *(const bf16x8*)(pA[i]);
        vb[i] = *(const bf16x8*)(pB[i]);
    }

    for (int k0 = 0; k0 < K; k0 += 32) {
        __syncthreads();
#pragma unroll
        for (int i = 0; i < 4; ++i) {
            *(bf16x8*)(&As[(w * 32 + i * 8) * 64 + lane * 8]) = va[i];
            *(bf16x8*)(&Bs[(w * 32 + i * 8) * 64 + lane * 8]) = vb[i];
        }
        __syncthreads();
        if (k0 + 32 < K) {
#pragma unroll
            for (int i = 0; i < 4; ++i) {
                va[i] = *(const bf16x8*)(pA[i] + k0 + 32);
                vb[i] = *(const bf16x8*)(pB[i] + k0 + 32);
            }
        }
        tile_split(As, Bs, wm, wn, lane, acc);
    }

    const int m15 = lane & 15, quad = lane >> 4;
#pragma unroll
    for (int i = 0; i < 4; ++i) {
#pragma unroll
        for (int t = 0; t < 4; ++t) {
            int row = row0 + wm * 64 + i * 16 + quad * 4 + t;
            size_t rb = zC + (size_t)row * N;
#pragma unroll
            for (int j = 0; j < 4; ++j) {
                int col = col0 + wn * 64 + j * 16 + m15;
                float v = acc[i][j][t] + bias[col];
                __hip_bfloat16 hi = __float2bfloat16(v);
                Chi_[rb + col] = hi;
                if (Clo_) Clo_[rb + col] = __float2bfloat16(v - __bfloat162float(hi));
            }
        }
    }
}

// ---------------------------------------------------------------------------
// Expert layer 1 (R11): hid[slot] = relu(x[token] @ W1eff[e] + b1eff[e])
// 2-term split (x hi/lo vs W1eff hi only) — see tile_split_a. The Blo_ arg
// receives W1eff_hi as an inert dummy (staged into unread LDS chunks).
// ---------------------------------------------------------------------------
__global__ __launch_bounds__(256)
void expert1_kernel(const __hip_bfloat16* x_hi_, const __hip_bfloat16* x_lo_,
                    const __hip_bfloat16* W1e_hi_, const __hip_bfloat16* W1e_lo_,
                    const float* __restrict__ b1eff,
                    const int* __restrict__ assign_token, const int* __restrict__ offs,
                    const __hip_bfloat16* zrow_, __hip_bfloat16* hid_)
{
    __shared__ __align__(16) short As[128 * 64];
    __shared__ __align__(16) short Bs[128 * 64];
    const short* Xhi = (const short*)x_hi_;
    const short* Xlo = (const short*)x_lo_;
    const short* zrow = (const short*)zrow_;

    const int tid = threadIdx.x, lane = tid & 63, w = tid >> 6;
    const int wm = w & 1, wn = w >> 1;
    const int lin = blockIdx.y * gridDim.x + blockIdx.x;
    const int lgc = xcd_chunk(lin, gridDim.x * gridDim.y);
    const int row0 = (lgc / gridDim.x) * 128, col0 = (lgc % gridDim.x) * 128;
    const int lr = lane >> 3;
    const int g = (lane & 7) ^ lr;
    const int plane = g >> 2, colel = (g & 3) * 8;

    int e = NEXP - 1;
    for (int q = 0; q < NEXP; ++q) { if (row0 < offs[q + 1]) { e = q; break; } }
    const short* Bh = (const short*)W1e_hi_ + (size_t)e * HID * D_IN;
    const short* Bl = (const short*)W1e_lo_ + (size_t)e * HID * D_IN;

    const short* pA[4];
    const short* pB[4];
#pragma unroll
    for (int i = 0; i < 4; ++i) {
        int r = w * 32 + i * 8 + lr;
        int tok = assign_token[row0 + r];
        pA[i] = (tok >= 0 ? (plane ? Xlo : Xhi) + (size_t)tok * D_IN : zrow) + colel;
        pB[i] = (plane ? Bl : Bh) + (size_t)(col0 + r) * D_IN + colel;
    }

    floatx4 acc[4][4];
#pragma unroll
    for (int i = 0; i < 4; ++i)
#pragma unroll
        for (int j = 0; j < 4; ++j) acc[i][j] = (floatx4)(0.f);

    bf16x8 va[4], vb[4];
#pragma unroll
    for (int i = 0; i < 4; ++i) {
        va[i] = *(const bf16x8*)(pA[i]);
        vb[i] = *(const bf16x8*)(pB[i]);
    }

    for (int k0 = 0; k0 < D_IN; k0 += 32) {
        __syncthreads();
#pragma unroll
        for (int i = 0; i < 4; ++i) {
            *(bf16x8*)(&As[(w * 32 + i * 8) * 64 + lane * 8]) = va[i];
            *(bf16x8*)(&Bs[(w * 32 + i * 8) * 64 + lane * 8]) = vb[i];
        }
        __syncthreads();
        if (k0 + 32 < D_IN) {
#pragma unroll
            for (int i = 0; i < 4; ++i) {
                va[i] = *(const bf16x8*)(pA[i] + k0 + 32);
                vb[i] = *(const bf16x8*)(pB[i] + k0 + 32);
            }
        }
        tile_split_a(As, Bs, wm, wn, lane, acc);
    }

    const int m15 = lane & 15, quad = lane >> 4;
#pragma unroll
    for (int i = 0; i < 4; ++i) {
#pragma unroll
        for (int t = 0; t < 4; ++t) {
            int row = row0 + wm * 64 + i * 16 + quad * 4 + t;
            size_t rb = (size_t)row * HID;
#pragma unroll
            for (int j = 0; j < 4; ++j) {
                int col = col0 + wn * 64 + j * 16 + m15;
                float v = acc[i][j][t] + b1eff[(size_t)e * HID + col];
                hid_[rb + col] = __float2bfloat16(fmaxf(v, 0.f));
            }
        }
    }
}

// ---------------------------------------------------------------------------
// Expert layer 2: exp_out[slot] = hid[slot] @ W2t[e]^T
// ---------------------------------------------------------------------------
__global__ __launch_bounds__(256)
void expert2_kernel(const __hip_bfloat16* hid_, const __hip_bfloat16* W2t_,
                    const int* __restrict__ offs, __hip_bfloat16* exp_out_)
{
    __shared__ __align__(16) short As[128 * 64];
    __shared__ __align__(16) short Bs[128 * 64];
    const short* A = (const short*)hid_;

    const int tid = threadIdx.x, lane = tid & 63, w = tid >> 6;
    const int wm = w & 1, wn = w >> 1;
    const int lin = blockIdx.y * gridDim.x + blockIdx.x;
    const int lgc = xcd_chunk(lin, gridDim.x * gridDim.y);
    const int row0 = (lgc / gridDim.x) * 128, col0 = (lgc % gridDim.x) * 128;
    const int lr = lane >> 3, g = (lane & 7) ^ lr, colel = g * 8;

    int e = NEXP - 1;
    for (int q = 0; q < NEXP; ++q) { if (row0 < offs[q + 1]) { e = q; break; } }
    const short* B = (const short*)W2t_ + (size_t)e * D_OUT * HID;

    const short* pA[4];
    const short* pB[4];
#pragma unroll
    for (int i = 0; i < 4; ++i) {
        int r = w * 32 + i * 8 + lr;
        pA[i] = A + (size_t)(row0 + r) * HID + colel;
        pB[i] = B + (size_t)(col0 + r) * HID + colel;
    }

    floatx4 acc[4][4];
#pragma unroll
    for (int i = 0; i < 4; ++i)
#pragma unroll
        for (int j = 0; j < 4; ++j) acc[i][j] = (floatx4)(0.f);

    bf16x8 va[4], vb[4];
#pragma unroll
    for (int i = 0; i < 4; ++i) {
        va[i] = *(const bf16x8*)(pA[i]);
        vb[i] = *(const bf16x8*)(pB[i]);
    }

    for (int k0 = 0; k0 < HID; k0 += 64) {
        __syncthreads();
#pragma unroll
        for (int i = 0; i < 4; ++i) {
            *(bf16x8*)(&As[(w * 32 + i * 8) * 64 + lane * 8]) = va[i];
            *(bf16x8*)(&Bs[(w * 32 + i * 8) * 64 + lane * 8]) = vb[i];
        }
        __syncthreads();
        if (k0 + 64 < HID) {
#pragma unroll
            for (int i = 0; i < 4; ++i) {
                va[i] = *(const bf16x8*)(pA[i] + k0 + 64);
                vb[i] = *(const bf16x8*)(pB[i] + k0 + 64);
            }
        }
        tile_plain(As, Bs, wm, wn, lane, acc);
    }

    const int m15 = lane & 15, quad = lane >> 4;
#pragma unroll
    for (int i = 0; i < 4; ++i) {
#pragma unroll
        for (int t = 0; t < 4; ++t) {
            int row = row0 + wm * 64 + i * 16 + quad * 4 + t;
            size_t rb = (size_t)row * D_OUT;
#pragma unroll
            for (int j = 0; j < 4; ++j) {
                int col = col0 + wn * 64 + j * 16 + m15;
                exp_out_[rb + col] = __float2bfloat16(acc[i][j][t]);
            }
        }
    }
}

// ---------------------------------------------------------------------------
// FUSED x-convert + gate (atomic-free). One token per wave.
// ---------------------------------------------------------------------------
__global__ __launch_bounds__(256)
void convert_gate_kernel(const float* __restrict__ x, const float* __restrict__ MgT,
                         const float* __restrict__ bgeff,
                         __hip_bfloat16* __restrict__ x_hi, __hip_bfloat16* __restrict__ x_lo,
                         int* __restrict__ route_e, float* __restrict__ route_w)
{
    const int wave = threadIdx.x >> 6, lane = threadIdx.x & 63;
    const int n = blockIdx.x * 4 + wave;
    const float* xrow = x + (size_t)n * D_IN;

    float4 v[4];
#pragma unroll
    for (int it = 0; it < 4; ++it)
        v[it] = *(const float4*)(xrow + it * 256 + lane * 4);

    float p[NEXP];
#pragma unroll
    for (int e = 0; e < NEXP; ++e) p[e] = 0.f;

#pragma unroll
    for (int it = 0; it < 4; ++it) {
        const int d = it * 256 + lane * 4;
        union { __hip_bfloat16 b[4]; short4 s; } uh, ul;
        uh.b[0] = __float2bfloat16(v[it].x); ul.b[0] = __float2bfloat16(v[it].x - __bfloat162float(uh.b[0]));
        uh.b[1] = __float2bfloat16(v[it].y); ul.b[1] = __float2bfloat16(v[it].y - __bfloat162float(uh.b[1]));
        uh.b[2] = __float2bfloat16(v[it].z); ul.b[2] = __float2bfloat16(v[it].z - __bfloat162float(uh.b[2]));
        uh.b[3] = __float2bfloat16(v[it].w); ul.b[3] = __float2bfloat16(v[it].w - __bfloat162float(uh.b[3]));
        *(short4*)(x_hi + (size_t)n * D_IN + d) = uh.s;
        *(short4*)(x_lo + (size_t)n * D_IN + d) = ul.s;
#pragma unroll
        for (int e = 0; e < NEXP; ++e) {
            const float4 m = *(const float4*)(MgT + (size_t)e * 1024 + d);
            p[e] += v[it].x * m.x + v[it].y * m.y + v[it].z * m.z + v[it].w * m.w;
        }
    }

#pragma unroll
    for (int e = 0; e < NEXP; ++e) {
        float t = p[e];
        for (int off = 32; off > 0; off >>= 1) t += __shfl_down(t, off);
        p[e] = t;
    }
    if (lane == 0) {
        float lg[NEXP];
#pragma unroll
        for (int e = 0; e < NEXP; ++e) lg[e] = p[e] + bgeff[e];
        int e0 = 0; float v0 = lg[0];
        for (int e = 1; e < NEXP; ++e) if (lg[e] > v0) { v0 = lg[e]; e0 = e; }
        int e1 = -1; float v1 = -3.0e38f;
        for (int e = 0; e < NEXP; ++e) {
            if (e == e0) continue;
            if (lg[e] > v1) { v1 = lg[e]; e1 = e; }
        }
        float w0 = 1.f / (1.f + expf(v1 - v0));   // softmax + top-2 renorm
        float w1 = 1.f - w0;
        route_e[n * 2]     = e0;
        route_e[n * 2 + 1] = e1;
        route_w[n * 2]     = w0;
        route_w[n * 2 + 1] = w1;
    }
}

// ---------------------------------------------------------------------------
// Histogram of route_e into counts[NEXP] (LDS histogram, 640 global atomics).
// ---------------------------------------------------------------------------
__global__ __launch_bounds__(256)
void count_kernel(const int* __restrict__ route_e, int* __restrict__ counts)
{
    __shared__ int h[NEXP];
    if (threadIdx.x < NEXP) h[threadIdx.x] = 0;
    __syncthreads();
    const int i = blockIdx.x * 512 + threadIdx.x;   // 64 blocks * 512 = 32768
    atomicAdd(&h[route_e[i]], 1);
    atomicAdd(&h[route_e[i + 256]], 1);
    __syncthreads();
    if (threadIdx.x < NEXP) atomicAdd(&counts[threadIdx.x], h[threadIdx.x]);
}

// ---------------------------------------------------------------------------
// fp32 [R][C] -> transposed bf16 [C][R] hi (+ optional lo); batched over z.
// ---------------------------------------------------------------------------
__global__ __launch_bounds__(256)
void transpose_cvt_kernel(const float* __restrict__ in, __hip_bfloat16* out_hi,
                          __hip_bfloat16* out_lo, int R, int C)
{
    __shared__ float t[32][33];
    const size_t zoff = (size_t)blockIdx.z * R * C;
    in += zoff; out_hi += zoff; if (out_lo) out_lo += zoff;
    const int c0 = blockIdx.x * 32, r0 = blockIdx.y * 32;
    const int tx = threadIdx.x & 31, ty = threadIdx.x >> 5;
#pragma unroll
    for (int i = 0; i < 4; ++i)
        t[ty + i * 8][tx] = in[(size_t)(r0 + ty + i * 8) * C + (c0 + tx)];
    __syncthreads();
#pragma unroll
    for (int i = 0; i < 4; ++i) {
        float v = t[tx][ty + i * 8];
        size_t o = (size_t)(c0 + ty + i * 8) * R + (r0 + tx);
        __hip_bfloat16 hi = __float2bfloat16(v);
        out_hi[o] = hi;
        if (out_lo) out_lo[o] = __float2bfloat16(v - __bfloat162float(hi));
    }
}

// ---------------------------------------------------------------------------
// Plain (non-transposing) fp32 -> hi/lo bf16 planes, float4-vectorized.
// ---------------------------------------------------------------------------
__global__ __launch_bounds__(256)
void convert_plain_kernel(const float* __restrict__ in,
                          __hip_bfloat16* __restrict__ out_hi,
                          __hip_bfloat16* __restrict__ out_lo)
{
    const int i = blockIdx.x * 256 + threadIdx.x;
    const float4 v = ((const float4*)in)[i];
    union { __hip_bfloat16 b[4]; short4 s; } uh, ul;
    uh.b[0] = __float2bfloat16(v.x); ul.b[0] = __float2bfloat16(v.x - __bfloat162float(uh.b[0]));
    uh.b[1] = __float2bfloat16(v.y); ul.b[1] = __float2bfloat16(v.y - __bfloat162float(uh.b[1]));
    uh.b[2] = __float2bfloat16(v.z); ul.b[2] = __float2bfloat16(v.z - __bfloat162float(uh.b[2]));
    uh.b[3] = __float2bfloat16(v.w); ul.b[3] = __float2bfloat16(v.w - __bfloat162float(uh.b[3]));
    ((short4*)out_hi)[i] = uh.s;
    ((short4*)out_lo)[i] = ul.s;
}

// ---------------------------------------------------------------------------
// Folded main-chain bias  beff2[n] = bp@(Wv@Wo)[:,n] + bv@Wo[:,n] + bo[n]
// using hi+lo reconstruction of Pt=(Wv@Wo)^T and Wot=Wo^T. One wave per n.
// ---------------------------------------------------------------------------
__global__ __launch_bounds__(256)
void bias2_kernel(const float* __restrict__ bp, const float* __restrict__ bv,
                  const float* __restrict__ bo,
                  const __hip_bfloat16* __restrict__ Pt_hi,
                  const __hip_bfloat16* __restrict__ Pt_lo,
                  const __hip_bfloat16* __restrict__ Wot_hi,
                  const __hip_bfloat16* __restrict__ Wot_lo,
                  float* __restrict__ beff2)
{
    const int wave = threadIdx.x >> 6, lane = threadIdx.x & 63;
    const int n = blockIdx.x * 4 + wave;
    float acc = 0.f;
    for (int k = lane; k < D_MODEL; k += 64) {
        const size_t o = (size_t)n * D_MODEL + k;
        float pt = __bfloat162float(Pt_hi[o]) + __bfloat162float(Pt_lo[o]);
        float wo = __bfloat162float(Wot_hi[o]) + __bfloat162float(Wot_lo[o]);
        acc += bp[k] * pt + bv[k] * wo;
    }
    for (int off = 32; off > 0; off >>= 1) acc += __shfl_down(acc, off);
    if (lane == 0) beff2[n] = acc + bo[n];
}

// ---------------------------------------------------------------------------
// b1eff[e][h] = beff2 @ W1[e][:,h] + b1[e][h], via W1t hi+lo (~fp32).
// One wave per output (n = e*HID + h), 2560 outputs -> 640 blocks.
// ---------------------------------------------------------------------------
__global__ __launch_bounds__(256)
void b1eff_kernel(const float* __restrict__ beff2,
                  const __hip_bfloat16* __restrict__ W1t_hi,
                  const __hip_bfloat16* __restrict__ W1t_lo,
                  const float* __restrict__ b1, float* __restrict__ b1eff)
{
    const int wave = threadIdx.x >> 6, lane = threadIdx.x & 63;
    const int n = blockIdx.x * 4 + wave;     // [0, NEXP*HID)
    const size_t base = (size_t)n * D_MODEL;
    float acc = 0.f;
    for (int k = lane; k < D_MODEL; k += 64)
        acc += beff2[k] * (__bfloat162float(W1t_hi[base + k]) +
                           __bfloat162float(W1t_lo[base + k]));
    for (int off = 32; off > 0; off >>= 1) acc += __shfl_down(acc, off);
    if (lane == 0) b1eff[n] = acc + b1[n];
}

// ---------------------------------------------------------------------------
// Thin fp32 GEMM for gate-matrix chain: Cm = A[1024][1024] @ B[1024][10];
// trans=0 -> Cm[m][10]; trans=1 -> Cm[e][1024] (transposed write for MgT).
// ---------------------------------------------------------------------------
__global__ __launch_bounds__(256)
void wchain_kernel(const float* __restrict__ A, const float* __restrict__ B,
                   float* __restrict__ Cm, int trans)
{
    const int wave = threadIdx.x >> 6, lane = threadIdx.x & 63;
    const int m = blockIdx.x * 4 + wave;
    float acc[NEXP];
#pragma unroll
    for (int e = 0; e < NEXP; ++e) acc[e] = 0.f;
    const float* ar = A + (size_t)m * 1024;
    for (int d = lane; d < 1024; d += 64) {
        float av = ar[d];
        const float* br = B + (size_t)d * NEXP;
#pragma unroll
        for (int e = 0; e < NEXP; ++e) acc[e] += av * br[e];
    }
#pragma unroll
    for (int e = 0; e < NEXP; ++e) {
        float v = acc[e];
        for (int off = 32; off > 0; off >>= 1) v += __shfl_down(v, off);
        if (lane == 0) Cm[trans ? ((size_t)e * 1024 + m) : ((size_t)m * NEXP + e)] = v;
    }
}

// ---------------------------------------------------------------------------
// bg_eff = bg + bo@Wg + bv@t1 + bp@t2    (single block)
// ---------------------------------------------------------------------------
__global__ __launch_bounds__(256)
void bias_eff_kernel(const float* __restrict__ bp, const float* __restrict__ bv,
                     const float* __restrict__ bo, const float* __restrict__ bg,
                     const float* __restrict__ Wg, const float* __restrict__ t1,
                     const float* __restrict__ t2, float* __restrict__ bgeff)
{
    __shared__ float red[256];
    const int tid = threadIdx.x;
    float acc[NEXP];
#pragma unroll
    for (int e = 0; e < NEXP; ++e) acc[e] = 0.f;
    for (int d = tid; d < 1024; d += 256) {
        float o = bo[d], v = bv[d], p = bp[d];
#pragma unroll
        for (int e = 0; e < NEXP; ++e)
            acc[e] += o * Wg[d * NEXP + e] + v * t1[d * NEXP + e] + p * t2[d * NEXP + e];
    }
    for (int e = 0; e < NEXP; ++e) {
        red[tid] = acc[e];
        __syncthreads();
        for (int s = 128; s > 0; s >>= 1) {
            if (tid < s) red[tid] += red[tid + s];
            __syncthreads();
        }
        if (tid == 0) bgeff[e] = red[0] + bg[e];
        __syncthreads();
    }
}

// ---------------------------------------------------------------------------
__global__ __launch_bounds__(256)
void init_kernel(int* __restrict__ counts, int* __restrict__ cursors,
                 int* __restrict__ assign_token, int* __restrict__ zrow_i,
                 float* __restrict__ fzero)
{
    int i = blockIdx.x * 256 + threadIdx.x;
    if (i < NEXP) { counts[i] = 0; cursors[i] = 0; }
    if (i < 512) zrow_i[i] = 0;                 // 1024 bf16 zeros
    if (i < 1024) fzero[i] = 0.f;               // fp32 zero bias for wt-product GEMMs
    if (i < A_CAP) assign_token[i] = -1;
}

__global__ void offsets_kernel(const int* __restrict__ counts, int* __restrict__ offs)
{
    if (threadIdx.x == 0 && blockIdx.x == 0) {
        int acc = 0;
        for (int e = 0; e < NEXP; ++e) {
            offs[e] = acc;
            acc += (counts[e] + EPAD - 1) / EPAD * EPAD;
        }
        offs[NEXP] = acc;
    }
}

// ---------------------------------------------------------------------------
// Scatter with WAVE-AGGREGATED cursor atomics (R6): <=10 atomics/wave via
// ballot+popcount vs 32768 contended return-value atomics before.
// ---------------------------------------------------------------------------
__global__ __launch_bounds__(256)
void scatter_kernel(const int* __restrict__ route_e,
                    const int* __restrict__ offs, int* __restrict__ cursors,
                    int* __restrict__ assign_token, int* __restrict__ slot_of)
{
    const int i = blockIdx.x * 256 + threadIdx.x;
    const int lane = threadIdx.x & 63;
    const int e = route_e[i];
    int slot = 0;
#pragma unroll
    for (int q = 0; q < NEXP; ++q) {
        unsigned long long mask = __ballot(e == q);
        if (e == q) {
            const int leader = (int)__ffsll((long long)mask) - 1;
            const int rank = (int)__popcll(mask & ((1ull << lane) - 1ull));
            int base = 0;
            if (lane == leader) base = atomicAdd(&cursors[q], (int)__popcll(mask));
            base = __shfl(base, leader);
            slot = offs[q] + base + rank;
        }
    }
    assign_token[slot] = i >> 1;
    slot_of[i] = slot;
}

// ---------------------------------------------------------------------------
// Combine (gather): out[n] = w0*(row(s0)+b2[e0]) + w1*(row(s1)+b2[e1])
// ---------------------------------------------------------------------------
__global__ __launch_bounds__(256)
void combine_kernel(const __hip_bfloat16* __restrict__ exp_out,
                    const int* __restrict__ slot_of, const int* __restrict__ route_e,
                    const float* __restrict__ route_w, const float* __restrict__ b2,
                    float* __restrict__ out)
{
    const int n = blockIdx.x;
    const int c = threadIdx.x * 4;
    const int s0 = slot_of[n * 2],  s1 = slot_of[n * 2 + 1];
    const int e0 = route_e[n * 2],  e1 = route_e[n * 2 + 1];
    const float w0 = route_w[n * 2], w1 = route_w[n * 2 + 1];

    union U { float2 f2; __hip_bfloat16 b[4]; } u0, u1;
    u0.f2 = *(const float2*)(exp_out + (size_t)s0 * D_OUT + c);
    u1.f2 = *(const float2*)(exp_out + (size_t)s1 * D_OUT + c);
    const float4 bb0 = *(const float4*)(b2 + (size_t)e0 * D_OUT + c);
    const float4 bb1 = *(const float4*)(b2 + (size_t)e1 * D_OUT + c);

    float4 o;
    o.x = w0 * (__bfloat162float(u0.b[0]) + bb0.x) + w1 * (__bfloat162float(u1.b[0]) + bb1.x);
    o.y = w0 * (__bfloat162float(u0.b[1]) + bb0.y) + w1 * (__bfloat162float(u1.b[1]) + bb1.y);
    o.z = w0 * (__bfloat162float(u0.b[2]) + bb0.z) + w1 * (__bfloat162float(u1.b[2]) + bb1.z);
    o.w = w0 * (__bfloat162float(u0.b[3]) + bb0.w) + w1 * (__bfloat162float(u1.b[3]) + bb1.w);
    *(float4*)(out + (size_t)n * D_OUT + c) = o;
}

// ---------------------------------------------------------------------------
extern "C" void kernel_launch(void* const* d_in, const int* in_sizes, int n_in,
                              void* d_out, int out_size, void* d_ws, size_t ws_size,
                              hipStream_t stream)
{
    const float* x  = (const float*)d_in[0];
    const float* Wp = (const float*)d_in[2];
    const float* bp = (const float*)d_in[3];
    const float* Wv = (const float*)d_in[4];
    const float* bv = (const float*)d_in[5];
    const float* Wo = (const float*)d_in[6];
    const float* bo = (const float*)d_in[7];
    const float* Wg = (const float*)d_in[8];
    const float* bg = (const float*)d_in[9];
    const float* W1 = (const float*)d_in[10];
    const float* b1 = (const float*)d_in[11];
    const float* W2 = (const float*)d_in[12];
    const float* b2 = (const float*)d_in[13];
    float* out = (float*)d_out;

    // ---- workspace layout (bytes); lifetime-based aliasing ----
    char* W = (char*)d_ws;
    typedef __hip_bfloat16 bf;
    bf* x_hi  = (bf*)(W + 0);                  // [N,D]  read by expert1 (gather)
    bf* x_lo  = (bf*)(W + 33554432);
    bf* exp_out = (bf*)(W + 0);                // [A_CAP,D_OUT] 69.7MB (post-expert1)
    bf* hid   = (bf*)(W + 69730304);           // [A_CAP,HID] ends ~87.2MB
    // weight-product scratch (88..100MB)
    bf* Wvr_hi = (bf*)(W + 88080384);          // Wv row-major hi/lo
    bf* Wvr_lo = (bf*)(W + 90177536);
    bf* Wpr_hi = (bf*)(W + 92274688);          // Wp row-major hi/lo
    bf* Wpr_lo = (bf*)(W + 94371840);
    float* fzero = (float*)(W + 96468992);     // 1024 fp32 zeros
    float* beff2 = (float*)(W + 96473088);     // folded main-chain bias [1024]
    // (100..117MB)
    bf* W1t_lo   = (bf*)(W + 100663296);       // [E][HID][D] lo plane (5.24MB)
    bf* W1eff_hi = (bf*)(W + 105906176);       // (M@W1[e])^T hi  [E][HID][D_IN]
    float* b1eff = (float*)(W + 116391936);    // [E][HID] fp32
    // weights / products (alive whole run)
    bf* Pt_hi  = (bf*)(W + 134217728);         // (Wv@Wo)^T hi/lo
    bf* Pt_lo  = (bf*)(W + 136314880);
    bf* Mrow_hi = (bf*)(W + 138412032);        // M = Wp@Wv@Wo ROW-major hi/lo
    bf* Mrow_lo = (bf*)(W + 140509184);
    bf* Wot_hi = (bf*)(W + 142606336);
    bf* Wot_lo = (bf*)(W + 144703488);
    bf* W1t    = (bf*)(W + 146800640);         // [E][HID][D] hi plane
    bf* W2t    = (bf*)(W + 152043520);         // [E][D_OUT][HID]
    // small buffers
    bf*    zrow         = (bf*)(W + 157286400);       // 1024 bf16 zeros
    int*   route_e      = (int*)(W + 157288448);
    float* route_w      = (float*)(W + 157419520);
    int*   slot_of      = (int*)(W + 157550592);
    int*   assign_token = (int*)(W + 157681664);
    int*   counts       = (int*)(W + 157817856);
    int*   offs         = (int*)(W + 157817920);
    int*   cursors      = (int*)(W + 157817984);
    float* MgT          = (float*)(W + 157818048);    // [10][1024] transposed
    float* t1           = (float*)(W + 157859008);
    float* t2           = (float*)(W + 157899968);
    float* bgeff        = (float*)(W + 157940928);

    dim3 blk(256);

    // ---- init first (zeros fzero used as bias by the product passes) ----
    init_kernel<<<(A_CAP + 255) / 256, blk, 0, stream>>>(counts, cursors, assign_token,
                                                         (int*)zrow, fzero);

    // ---- weight conversions ----
    transpose_cvt_kernel<<<dim3(32, 32, 1), blk, 0, stream>>>(Wo, Wot_hi, Wot_lo, D_MODEL, D_MODEL);
    convert_plain_kernel<<<1024, blk, 0, stream>>>(Wv, Wvr_hi, Wvr_lo);
    convert_plain_kernel<<<1024, blk, 0, stream>>>(Wp, Wpr_hi, Wpr_lo);
    transpose_cvt_kernel<<<dim3(HID / 32, D_MODEL / 32, NEXP), blk, 0, stream>>>(W1, W1t, W1t_lo, D_MODEL, HID);
    transpose_cvt_kernel<<<dim3(D_OUT / 32, HID / 32, NEXP), blk, 0, stream>>>(W2, W2t, nullptr, HID, D_OUT);

    // ---- gate matrix chain (fp32, exactness-preserving associativity) ----
    wchain_kernel<<<256, blk, 0, stream>>>(Wo, Wg, t1, 0);   // t1 = Wo@Wg
    wchain_kernel<<<256, blk, 0, stream>>>(Wv, t1, t2, 0);   // t2 = Wv@t1
    wchain_kernel<<<256, blk, 0, stream>>>(Wp, t2, MgT, 1);  // MgT = (Wp@t2)^T
    bias_eff_kernel<<<1, blk, 0, stream>>>(bp, bv, bo, bg, Wg, t1, t2, bgeff);

    // ---- weight-product passes (split-bf16, hi/lo outputs) ----
    dim3 pgrid(D_MODEL / 128, D_MODEL / 128, 1);   // (8, 8)
    // Pt[n][k] = (Wv@Wo)[k][n] :  A = Wot, Bt = Wv row-major
    gemm_split_kernel<<<pgrid, blk, 0, stream>>>(Wot_hi, Wot_lo, Wvr_hi, Wvr_lo, fzero,
                                                 Pt_hi, Pt_lo, D_MODEL, D_MODEL, 0, 0, 0);
    // Mrow[k'][k] = (Wp@Wv@Wo)[k'][k] :  A = Wp row-major, Bt = Pt
    gemm_split_kernel<<<pgrid, blk, 0, stream>>>(Wpr_hi, Wpr_lo, Pt_hi, Pt_lo, fzero,
                                                 Mrow_hi, Mrow_lo, D_MODEL, D_MODEL, 0, 0, 0);
    // folded main-chain bias: beff2 = bp@(Wv@Wo) + bv@Wo + bo
    bias2_kernel<<<D_MODEL / 4, blk, 0, stream>>>(bp, bv, bo, Pt_hi, Pt_lo,
                                                  Wot_hi, Wot_lo, beff2);
    // b1eff[e] = beff2@W1[e] + b1[e]
    b1eff_kernel<<<NEXP * HID / 4, blk, 0, stream>>>(beff2, W1t, W1t_lo, b1, b1eff);
    // W1eff_t[e][h][k'] = (M@W1[e])^T : A = W1t[e] (hi/lo), Bt = Mrow, z=e.
    // R11: hi plane only (lo dropped — expert1 uses 2-term split).
    dim3 wgrid(D_IN / 128, HID / 128, NEXP);       // (8, 2, 10)
    gemm_split_kernel<<<wgrid, blk, 0, stream>>>(W1t, W1t_lo, Mrow_hi, Mrow_lo, fzero,
                                                 W1eff_hi, nullptr, D_MODEL, D_IN,
                                                 (size_t)HID * D_MODEL, 0,
                                                 (size_t)HID * D_IN);

    // ---- fused convert/gate (atomic-free) + count + scatter ----
    convert_gate_kernel<<<N_TOK / 4, blk, 0, stream>>>(x, MgT, bgeff, x_hi, x_lo,
                                                       route_e, route_w);
    count_kernel<<<2 * N_TOK / 512, blk, 0, stream>>>(route_e, counts);
    offsets_kernel<<<1, 64, 0, stream>>>(counts, offs);
    scatter_kernel<<<2 * N_TOK / 256, blk, 0, stream>>>(route_e, offs, cursors,
                                                        assign_token, slot_of);

    // ---- experts: layer1 2-term split on gathered x ----
    expert1_kernel<<<dim3(HID / 128, A_CAP / 128), blk, 0, stream>>>(
        x_hi, x_lo, W1eff_hi, W1eff_hi /*dummy lo, unread*/, b1eff,
        assign_token, offs, zrow, hid);
    expert2_kernel<<<dim3(D_OUT / 128, A_CAP / 128), blk, 0, stream>>>(
        hid, W2t, offs, exp_out);
    combine_kernel<<<N_TOK, blk, 0, stream>>>(exp_out, slot_of, route_e, route_w, b2, out);
}

// Round 9
// 520.794 us; speedup vs baseline: 3.2150x; 1.0077x over previous
//
#include <hip/hip_runtime.h>
#include <hip/hip_bf16.h>
#include <math.h>

#define N_TOK   16384
#define D_IN    1024
#define D_MODEL 1024
#define HID     256
#define NEXP    10
#define D_OUT   1024

// Expert routing: pad each expert's list to a multiple of EPAD so every
// row tile is single-expert. Static capacity => static grid (graph-safe).
#define EPAD 128
#define A_CAP (2*N_TOK + NEXP*EPAD)   // 34048 = 266 * 128 = 532 * 64

typedef __attribute__((ext_vector_type(8))) __bf16 bf16x8;
typedef __attribute__((ext_vector_type(4))) float floatx4;

// ---------------------------------------------------------------------------
// XCD-chunked block swizzle (bijective): R8 confirmed — FETCH 290MB -> 77MB
// (~ideal) on the big GEMM. Keep on all MFMA kernels.
// ---------------------------------------------------------------------------
__device__ __forceinline__ int xcd_chunk(int orig, int nwg)
{
    const int q = nwg >> 3, r = nwg & 7;
    const int c = orig & 7, j = orig >> 3;
    return (c < r ? c * (q + 1) : r * (q + 1) + (c - r) * q) + j;
}

// ---------------------------------------------------------------------------
// LDS tile layout (per Nx64-short tile): row = 128 bytes = 8 chunks of 16B.
// Chunk g of row r is stored at position g ^ (r&7); staging applies the inverse
// swizzle on the per-lane *global* source address, so the LDS store is simply
// rowgroup_base + lane*16B.
// ---------------------------------------------------------------------------
__device__ __forceinline__ bf16x8 lds_frag(const short* base, int row, int chunk)
{
    return *(const bf16x8*)(base + row * 64 + (chunk << 3));
}

// plain bf16: tile covers K-step 64 (chunks 0..7 = k 0..63)
__device__ __forceinline__ void tile_plain(const short* As, const short* Bs,
                                           int wm, int wn, int lane, floatx4 acc[4][4])
{
    const int m15 = lane & 15, quad = lane >> 4, sw = m15 & 7;
#pragma unroll
    for (int kk = 0; kk < 2; ++kk) {
        bf16x8 af[4], bfr[4];
#pragma unroll
        for (int i = 0; i < 4; ++i)
            af[i] = lds_frag(As, wm * 64 + i * 16 + m15, ((kk << 2) + quad) ^ sw);
#pragma unroll
        for (int j = 0; j < 4; ++j)
            bfr[j] = lds_frag(Bs, wn * 64 + j * 16 + m15, ((kk << 2) + quad) ^ sw);
#pragma unroll
        for (int i = 0; i < 4; ++i)
#pragma unroll
            for (int j = 0; j < 4; ++j)
                acc[i][j] = __builtin_amdgcn_mfma_f32_16x16x32_bf16(af[i], bfr[j],
                                                                    acc[i][j], 0, 0, 0);
    }
}

// split bf16 (3-term): tile covers K-step 32; chunks 0..3 = hi, 4..7 = lo.
// acc += Ah*Bh + Ah*Bl + Al*Bh  (Al*Bl ~ 2^-18, dropped)
__device__ __forceinline__ void tile_split(const short* As, const short* Bs,
                                           int wm, int wn, int lane, floatx4 acc[4][4])
{
    const int m15 = lane & 15, quad = lane >> 4, sw = m15 & 7;
    bf16x8 ah[4], al[4], bh[4], bl[4];
#pragma unroll
    for (int i = 0; i < 4; ++i) {
        int r = wm * 64 + i * 16 + m15;
        ah[i] = lds_frag(As, r, quad ^ sw);
        al[i] = lds_frag(As, r, (4 + quad) ^ sw);
    }
#pragma unroll
    for (int j = 0; j < 4; ++j) {
        int r = wn * 64 + j * 16 + m15;
        bh[j] = lds_frag(Bs, r, quad ^ sw);
        bl[j] = lds_frag(Bs, r, (4 + quad) ^ sw);
    }
#pragma unroll
    for (int i = 0; i < 4; ++i)
#pragma unroll
        for (int j = 0; j < 4; ++j) {
            floatx4 c = acc[i][j];
            c = __builtin_amdgcn_mfma_f32_16x16x32_bf16(ah[i], bh[j], c, 0, 0, 0);
            c = __builtin_amdgcn_mfma_f32_16x16x32_bf16(ah[i], bl[j], c, 0, 0, 0);
            c = __builtin_amdgcn_mfma_f32_16x16x32_bf16(al[i], bh[j], c, 0, 0, 0);
            acc[i][j] = c;
        }
}

// R12: 2-term split for the 64-row expert1 tile: A split hi/lo (2 row-frags),
// B hi-only (4 col-frags). acc[2][4], 16 MFMA per K-step-32.
__device__ __forceinline__ void tile_split_a64(const short* As, const short* Bs,
                                               int wm, int wn, int lane,
                                               floatx4 acc[2][4])
{
    const int m15 = lane & 15, quad = lane >> 4, sw = m15 & 7;
    bf16x8 ah[2], al[2], bh[4];
#pragma unroll
    for (int i = 0; i < 2; ++i) {
        int r = wm * 32 + i * 16 + m15;
        ah[i] = lds_frag(As, r, quad ^ sw);
        al[i] = lds_frag(As, r, (4 + quad) ^ sw);
    }
#pragma unroll
    for (int j = 0; j < 4; ++j) {
        int r = wn * 64 + j * 16 + m15;
        bh[j] = lds_frag(Bs, r, quad ^ sw);
    }
#pragma unroll
    for (int i = 0; i < 2; ++i)
#pragma unroll
        for (int j = 0; j < 4; ++j) {
            floatx4 c = acc[i][j];
            c = __builtin_amdgcn_mfma_f32_16x16x32_bf16(ah[i], bh[j], c, 0, 0, 0);
            c = __builtin_amdgcn_mfma_f32_16x16x32_bf16(al[i], bh[j], c, 0, 0, 0);
            acc[i][j] = c;
        }
}

// ---------------------------------------------------------------------------
// Split-bf16 GEMM: C = A @ Bt^T + bias, inputs as hi/lo bf16 planes [M][K] and
// [N][K]; output hi (+ optional lo) bf16 planes. ~fp32 accuracy.
// z-batched via zsA/zsB/zsC strides (blockIdx.z) for the per-expert W1eff
// pass; plain calls use grid.z=1, strides 0. Weight products only.
// ---------------------------------------------------------------------------
__global__ __launch_bounds__(256)
void gemm_split_kernel(const __hip_bfloat16* Ahi_, const __hip_bfloat16* Alo_,
                       const __hip_bfloat16* Bhi_, const __hip_bfloat16* Blo_,
                       const float* __restrict__ bias,
                       __hip_bfloat16* Chi_, __hip_bfloat16* Clo_, int K, int N,
                       size_t zsA, size_t zsB, size_t zsC)
{
    __shared__ __align__(16) short As[128 * 64];
    __shared__ __align__(16) short Bs[128 * 64];
    const short* Ahi = (const short*)Ahi_;
    const short* Alo = (const short*)Alo_;
    const short* Bhi = (const short*)Bhi_;
    const short* Blo = (const short*)Blo_;

    const int tid = threadIdx.x, lane = tid & 63, w = tid >> 6;
    const int wm = w & 1, wn = w >> 1;
    const size_t zA = (size_t)blockIdx.z * zsA;
    const size_t zB = (size_t)blockIdx.z * zsB;
    const size_t zC = (size_t)blockIdx.z * zsC;
    const int lin = blockIdx.y * gridDim.x + blockIdx.x;
    const int lgc = xcd_chunk(lin, gridDim.x * gridDim.y);
    const int row0 = (lgc / gridDim.x) * 128, col0 = (lgc % gridDim.x) * 128;
    const int lr = lane >> 3;
    const int g = (lane & 7) ^ lr;          // swizzled source chunk (const per lane)
    const int plane = g >> 2, colel = (g & 3) * 8;

    const short* pA[4];
    const short* pB[4];
#pragma unroll
    for (int i = 0; i < 4; ++i) {
        int r = w * 32 + i * 8 + lr;
        pA[i] = (plane ? Alo : Ahi) + zA + (size_t)(row0 + r) * K + colel;
        pB[i] = (plane ? Blo : Bhi) + zB + (size_t)(col0 + r) * K + colel;
    }

    floatx4 acc[4][4];
#pragma unroll
    for (int i = 0; i < 4; ++i)
#pragma unroll
        for (int j = 0; j < 4; ++j) acc[i][j] = (floatx4)(0.f);

    // prologue: prefetch K-step 0
    bf16x8 va[4], vb[4];
#pragma unroll
    for (int i = 0; i < 4; ++i) {
        va[i] = *(const bf16x8*)(pA[i]);
        vb[i] = *(const bf16x8*)(pB[i]);
    }

    for (int k0 = 0; k0 < K; k0 += 32) {
        __syncthreads();
#pragma unroll
        for (int i = 0; i < 4; ++i) {
            *(bf16x8*)(&As[(w * 32 + i * 8) * 64 + lane * 8]) = va[i];
            *(bf16x8*)(&Bs[(w * 32 + i * 8) * 64 + lane * 8]) = vb[i];
        }
        __syncthreads();
        if (k0 + 32 < K) {
#pragma unroll
            for (int i = 0; i < 4; ++i) {
                va[i] = *(const bf16x8*)(pA[i] + k0 + 32);
                vb[i] = *(const bf16x8*)(pB[i] + k0 + 32);
            }
        }
        tile_split(As, Bs, wm, wn, lane, acc);
    }

    const int m15 = lane & 15, quad = lane >> 4;
#pragma unroll
    for (int i = 0; i < 4; ++i) {
#pragma unroll
        for (int t = 0; t < 4; ++t) {
            int row = row0 + wm * 64 + i * 16 + quad * 4 + t;
            size_t rb = zC + (size_t)row * N;
#pragma unroll
            for (int j = 0; j < 4; ++j) {
                int col = col0 + wn * 64 + j * 16 + m15;
                float v = acc[i][j][t] + bias[col];
                __hip_bfloat16 hi = __float2bfloat16(v);
                Chi_[rb + col] = hi;
                if (Clo_) Clo_[rb + col] = __float2bfloat16(v - __bfloat162float(hi));
            }
        }
    }
}

// ---------------------------------------------------------------------------
// Expert layer 1 (R12): hid[slot] = relu(x[token] @ W1eff[e] + b1eff[e])
// 2-term split, BM=64 tile. R11's (2,266)=532-block grid gave 2.08 blocks/CU
// (OccupancyPercent 12%, MfmaUtil 19%, HBM 17% — nothing saturated: grid-
// shape latency bound). BM 128->64 doubles the grid to (2,532)=1064 blocks
// = 4.15/CU; LDS 32->24KB. EPAD=128 is a multiple of 64 so every 64-row
// tile is still single-expert. Per-output K-accumulation order unchanged
// -> bit-identical result expected.
// ---------------------------------------------------------------------------
__global__ __launch_bounds__(256)
void expert1_kernel(const __hip_bfloat16* x_hi_, const __hip_bfloat16* x_lo_,
                    const __hip_bfloat16* W1e_hi_,
                    const float* __restrict__ b1eff,
                    const int* __restrict__ assign_token, const int* __restrict__ offs,
                    const __hip_bfloat16* zrow_, __hip_bfloat16* hid_)
{
    __shared__ __align__(16) short As[64 * 64];    // 8 KB (hi+lo of 32 k-elems)
    __shared__ __align__(16) short Bs[128 * 64];   // 16 KB (hi in 0..3; 4..7 inert)
    const short* Xhi = (const short*)x_hi_;
    const short* Xlo = (const short*)x_lo_;
    const short* zrow = (const short*)zrow_;

    const int tid = threadIdx.x, lane = tid & 63, w = tid >> 6;
    const int wm = w & 1, wn = w >> 1;
    const int lin = blockIdx.y * gridDim.x + blockIdx.x;
    const int lgc = xcd_chunk(lin, gridDim.x * gridDim.y);
    const int row0 = (lgc / gridDim.x) * 64, col0 = (lgc % gridDim.x) * 128;
    const int lr = lane >> 3;
    const int g = (lane & 7) ^ lr;
    const int plane = g >> 2, colel = (g & 3) * 8;

    int e = NEXP - 1;
    for (int q = 0; q < NEXP; ++q) { if (row0 < offs[q + 1]) { e = q; break; } }
    const short* Bh = (const short*)W1e_hi_ + (size_t)e * HID * D_IN;

    const short* pA[2];
    const short* pB[4];
#pragma unroll
    for (int i = 0; i < 2; ++i) {
        int r = w * 16 + i * 8 + lr;
        int tok = assign_token[row0 + r];
        pA[i] = (tok >= 0 ? (plane ? Xlo : Xhi) + (size_t)tok * D_IN : zrow) + colel;
    }
#pragma unroll
    for (int i = 0; i < 4; ++i) {
        int r = w * 32 + i * 8 + lr;
        pB[i] = Bh + (size_t)(col0 + r) * D_IN + colel;   // plane=1 lanes re-read hi
    }

    floatx4 acc[2][4];
#pragma unroll
    for (int i = 0; i < 2; ++i)
#pragma unroll
        for (int j = 0; j < 4; ++j) acc[i][j] = (floatx4)(0.f);

    bf16x8 va[2], vb[4];
#pragma unroll
    for (int i = 0; i < 2; ++i) va[i] = *(const bf16x8*)(pA[i]);
#pragma unroll
    for (int i = 0; i < 4; ++i) vb[i] = *(const bf16x8*)(pB[i]);

    for (int k0 = 0; k0 < D_IN; k0 += 32) {
        __syncthreads();
#pragma unroll
        for (int i = 0; i < 2; ++i)
            *(bf16x8*)(&As[(w * 16 + i * 8) * 64 + lane * 8]) = va[i];
#pragma unroll
        for (int i = 0; i < 4; ++i)
            *(bf16x8*)(&Bs[(w * 32 + i * 8) * 64 + lane * 8]) = vb[i];
        __syncthreads();
        if (k0 + 32 < D_IN) {
#pragma unroll
            for (int i = 0; i < 2; ++i) va[i] = *(const bf16x8*)(pA[i] + k0 + 32);
#pragma unroll
            for (int i = 0; i < 4; ++i) vb[i] = *(const bf16x8*)(pB[i] + k0 + 32);
        }
        tile_split_a64(As, Bs, wm, wn, lane, acc);
    }

    const int m15 = lane & 15, quad = lane >> 4;
#pragma unroll
    for (int i = 0; i < 2; ++i) {
#pragma unroll
        for (int t = 0; t < 4; ++t) {
            int row = row0 + wm * 32 + i * 16 + quad * 4 + t;
            size_t rb = (size_t)row * HID;
#pragma unroll
            for (int j = 0; j < 4; ++j) {
                int col = col0 + wn * 64 + j * 16 + m15;
                float v = acc[i][j][t] + b1eff[(size_t)e * HID + col];
                hid_[rb + col] = __float2bfloat16(fmaxf(v, 0.f));
            }
        }
    }
}

// ---------------------------------------------------------------------------
// Expert layer 2: exp_out[slot] = hid[slot] @ W2t[e]^T
// ---------------------------------------------------------------------------
__global__ __launch_bounds__(256)
void expert2_kernel(const __hip_bfloat16* hid_, const __hip_bfloat16* W2t_,
                    const int* __restrict__ offs, __hip_bfloat16* exp_out_)
{
    __shared__ __align__(16) short As[128 * 64];
    __shared__ __align__(16) short Bs[128 * 64];
    const short* A = (const short*)hid_;

    const int tid = threadIdx.x, lane = tid & 63, w = tid >> 6;
    const int wm = w & 1, wn = w >> 1;
    const int lin = blockIdx.y * gridDim.x + blockIdx.x;
    const int lgc = xcd_chunk(lin, gridDim.x * gridDim.y);
    const int row0 = (lgc / gridDim.x) * 128, col0 = (lgc % gridDim.x) * 128;
    const int lr = lane >> 3, g = (lane & 7) ^ lr, colel = g * 8;

    int e = NEXP - 1;
    for (int q = 0; q < NEXP; ++q) { if (row0 < offs[q + 1]) { e = q; break; } }
    const short* B = (const short*)W2t_ + (size_t)e * D_OUT * HID;

    const short* pA[4];
    const short* pB[4];
#pragma unroll
    for (int i = 0; i < 4; ++i) {
        int r = w * 32 + i * 8 + lr;
        pA[i] = A + (size_t)(row0 + r) * HID + colel;
        pB[i] = B + (size_t)(col0 + r) * HID + colel;
    }

    floatx4 acc[4][4];
#pragma unroll
    for (int i = 0; i < 4; ++i)
#pragma unroll
        for (int j = 0; j < 4; ++j) acc[i][j] = (floatx4)(0.f);

    bf16x8 va[4], vb[4];
#pragma unroll
    for (int i = 0; i < 4; ++i) {
        va[i] = *(const bf16x8*)(pA[i]);
        vb[i] = *(const bf16x8*)(pB[i]);
    }

    for (int k0 = 0; k0 < HID; k0 += 64) {
        __syncthreads();
#pragma unroll
        for (int i = 0; i < 4; ++i) {
            *(bf16x8*)(&As[(w * 32 + i * 8) * 64 + lane * 8]) = va[i];
            *(bf16x8*)(&Bs[(w * 32 + i * 8) * 64 + lane * 8]) = vb[i];
        }
        __syncthreads();
        if (k0 + 64 < HID) {
#pragma unroll
            for (int i = 0; i < 4; ++i) {
                va[i] = *(const bf16x8*)(pA[i] + k0 + 64);
                vb[i] = *(const bf16x8*)(pB[i] + k0 + 64);
            }
        }
        tile_plain(As, Bs, wm, wn, lane, acc);
    }

    const int m15 = lane & 15, quad = lane >> 4;
#pragma unroll
    for (int i = 0; i < 4; ++i) {
#pragma unroll
        for (int t = 0; t < 4; ++t) {
            int row = row0 + wm * 64 + i * 16 + quad * 4 + t;
            size_t rb = (size_t)row * D_OUT;
#pragma unroll
            for (int j = 0; j < 4; ++j) {
                int col = col0 + wn * 64 + j * 16 + m15;
                exp_out_[rb + col] = __float2bfloat16(acc[i][j][t]);
            }
        }
    }
}

// ---------------------------------------------------------------------------
// FUSED x-convert + gate (atomic-free). One token per wave.
// ---------------------------------------------------------------------------
__global__ __launch_bounds__(256)
void convert_gate_kernel(const float* __restrict__ x, const float* __restrict__ MgT,
                         const float* __restrict__ bgeff,
                         __hip_bfloat16* __restrict__ x_hi, __hip_bfloat16* __restrict__ x_lo,
                         int* __restrict__ route_e, float* __restrict__ route_w)
{
    const int wave = threadIdx.x >> 6, lane = threadIdx.x & 63;
    const int n = blockIdx.x * 4 + wave;
    const float* xrow = x + (size_t)n * D_IN;

    float4 v[4];
#pragma unroll
    for (int it = 0; it < 4; ++it)
        v[it] = *(const float4*)(xrow + it * 256 + lane * 4);

    float p[NEXP];
#pragma unroll
    for (int e = 0; e < NEXP; ++e) p[e] = 0.f;

#pragma unroll
    for (int it = 0; it < 4; ++it) {
        const int d = it * 256 + lane * 4;
        union { __hip_bfloat16 b[4]; short4 s; } uh, ul;
        uh.b[0] = __float2bfloat16(v[it].x); ul.b[0] = __float2bfloat16(v[it].x - __bfloat162float(uh.b[0]));
        uh.b[1] = __float2bfloat16(v[it].y); ul.b[1] = __float2bfloat16(v[it].y - __bfloat162float(uh.b[1]));
        uh.b[2] = __float2bfloat16(v[it].z); ul.b[2] = __float2bfloat16(v[it].z - __bfloat162float(uh.b[2]));
        uh.b[3] = __float2bfloat16(v[it].w); ul.b[3] = __float2bfloat16(v[it].w - __bfloat162float(uh.b[3]));
        *(short4*)(x_hi + (size_t)n * D_IN + d) = uh.s;
        *(short4*)(x_lo + (size_t)n * D_IN + d) = ul.s;
#pragma unroll
        for (int e = 0; e < NEXP; ++e) {
            const float4 m = *(const float4*)(MgT + (size_t)e * 1024 + d);
            p[e] += v[it].x * m.x + v[it].y * m.y + v[it].z * m.z + v[it].w * m.w;
        }
    }

#pragma unroll
    for (int e = 0; e < NEXP; ++e) {
        float t = p[e];
        for (int off = 32; off > 0; off >>= 1) t += __shfl_down(t, off);
        p[e] = t;
    }
    if (lane == 0) {
        float lg[NEXP];
#pragma unroll
        for (int e = 0; e < NEXP; ++e) lg[e] = p[e] + bgeff[e];
        int e0 = 0; float v0 = lg[0];
        for (int e = 1; e < NEXP; ++e) if (lg[e] > v0) { v0 = lg[e]; e0 = e; }
        int e1 = -1; float v1 = -3.0e38f;
        for (int e = 0; e < NEXP; ++e) {
            if (e == e0) continue;
            if (lg[e] > v1) { v1 = lg[e]; e1 = e; }
        }
        float w0 = 1.f / (1.f + expf(v1 - v0));   // softmax + top-2 renorm
        float w1 = 1.f - w0;
        route_e[n * 2]     = e0;
        route_e[n * 2 + 1] = e1;
        route_w[n * 2]     = w0;
        route_w[n * 2 + 1] = w1;
    }
}

// ---------------------------------------------------------------------------
// Histogram of route_e into counts[NEXP] (LDS histogram, 640 global atomics).
// ---------------------------------------------------------------------------
__global__ __launch_bounds__(256)
void count_kernel(const int* __restrict__ route_e, int* __restrict__ counts)
{
    __shared__ int h[NEXP];
    if (threadIdx.x < NEXP) h[threadIdx.x] = 0;
    __syncthreads();
    const int i = blockIdx.x * 512 + threadIdx.x;   // 64 blocks * 512 = 32768
    atomicAdd(&h[route_e[i]], 1);
    atomicAdd(&h[route_e[i + 256]], 1);
    __syncthreads();
    if (threadIdx.x < NEXP) atomicAdd(&counts[threadIdx.x], h[threadIdx.x]);
}

// ---------------------------------------------------------------------------
// fp32 [R][C] -> transposed bf16 [C][R] hi (+ optional lo); batched over z.
// ---------------------------------------------------------------------------
__global__ __launch_bounds__(256)
void transpose_cvt_kernel(const float* __restrict__ in, __hip_bfloat16* out_hi,
                          __hip_bfloat16* out_lo, int R, int C)
{
    __shared__ float t[32][33];
    const size_t zoff = (size_t)blockIdx.z * R * C;
    in += zoff; out_hi += zoff; if (out_lo) out_lo += zoff;
    const int c0 = blockIdx.x * 32, r0 = blockIdx.y * 32;
    const int tx = threadIdx.x & 31, ty = threadIdx.x >> 5;
#pragma unroll
    for (int i = 0; i < 4; ++i)
        t[ty + i * 8][tx] = in[(size_t)(r0 + ty + i * 8) * C + (c0 + tx)];
    __syncthreads();
#pragma unroll
    for (int i = 0; i < 4; ++i) {
        float v = t[tx][ty + i * 8];
        size_t o = (size_t)(c0 + ty + i * 8) * R + (r0 + tx);
        __hip_bfloat16 hi = __float2bfloat16(v);
        out_hi[o] = hi;
        if (out_lo) out_lo[o] = __float2bfloat16(v - __bfloat162float(hi));
    }
}

// ---------------------------------------------------------------------------
// Plain (non-transposing) fp32 -> hi/lo bf16 planes, float4-vectorized.
// ---------------------------------------------------------------------------
__global__ __launch_bounds__(256)
void convert_plain_kernel(const float* __restrict__ in,
                          __hip_bfloat16* __restrict__ out_hi,
                          __hip_bfloat16* __restrict__ out_lo)
{
    const int i = blockIdx.x * 256 + threadIdx.x;
    const float4 v = ((const float4*)in)[i];
    union { __hip_bfloat16 b[4]; short4 s; } uh, ul;
    uh.b[0] = __float2bfloat16(v.x); ul.b[0] = __float2bfloat16(v.x - __bfloat162float(uh.b[0]));
    uh.b[1] = __float2bfloat16(v.y); ul.b[1] = __float2bfloat16(v.y - __bfloat162float(uh.b[1]));
    uh.b[2] = __float2bfloat16(v.z); ul.b[2] = __float2bfloat16(v.z - __bfloat162float(uh.b[2]));
    uh.b[3] = __float2bfloat16(v.w); ul.b[3] = __float2bfloat16(v.w - __bfloat162float(uh.b[3]));
    ((short4*)out_hi)[i] = uh.s;
    ((short4*)out_lo)[i] = ul.s;
}

// ---------------------------------------------------------------------------
// Folded main-chain bias  beff2[n] = bp@(Wv@Wo)[:,n] + bv@Wo[:,n] + bo[n]
// using hi+lo reconstruction of Pt=(Wv@Wo)^T and Wot=Wo^T. One wave per n.
// ---------------------------------------------------------------------------
__global__ __launch_bounds__(256)
void bias2_kernel(const float* __restrict__ bp, const float* __restrict__ bv,
                  const float* __restrict__ bo,
                  const __hip_bfloat16* __restrict__ Pt_hi,
                  const __hip_bfloat16* __restrict__ Pt_lo,
                  const __hip_bfloat16* __restrict__ Wot_hi,
                  const __hip_bfloat16* __restrict__ Wot_lo,
                  float* __restrict__ beff2)
{
    const int wave = threadIdx.x >> 6, lane = threadIdx.x & 63;
    const int n = blockIdx.x * 4 + wave;
    float acc = 0.f;
    for (int k = lane; k < D_MODEL; k += 64) {
        const size_t o = (size_t)n * D_MODEL + k;
        float pt = __bfloat162float(Pt_hi[o]) + __bfloat162float(Pt_lo[o]);
        float wo = __bfloat162float(Wot_hi[o]) + __bfloat162float(Wot_lo[o]);
        acc += bp[k] * pt + bv[k] * wo;
    }
    for (int off = 32; off > 0; off >>= 1) acc += __shfl_down(acc, off);
    if (lane == 0) beff2[n] = acc + bo[n];
}

// ---------------------------------------------------------------------------
// b1eff[e][h] = beff2 @ W1[e][:,h] + b1[e][h], via W1t hi+lo (~fp32).
// One wave per output (n = e*HID + h), 2560 outputs -> 640 blocks.
// ---------------------------------------------------------------------------
__global__ __launch_bounds__(256)
void b1eff_kernel(const float* __restrict__ beff2,
                  const __hip_bfloat16* __restrict__ W1t_hi,
                  const __hip_bfloat16* __restrict__ W1t_lo,
                  const float* __restrict__ b1, float* __restrict__ b1eff)
{
    const int wave = threadIdx.x >> 6, lane = threadIdx.x & 63;
    const int n = blockIdx.x * 4 + wave;     // [0, NEXP*HID)
    const size_t base = (size_t)n * D_MODEL;
    float acc = 0.f;
    for (int k = lane; k < D_MODEL; k += 64)
        acc += beff2[k] * (__bfloat162float(W1t_hi[base + k]) +
                           __bfloat162float(W1t_lo[base + k]));
    for (int off = 32; off > 0; off >>= 1) acc += __shfl_down(acc, off);
    if (lane == 0) b1eff[n] = acc + b1[n];
}

// ---------------------------------------------------------------------------
// Thin fp32 GEMM for gate-matrix chain: Cm = A[1024][1024] @ B[1024][10];
// trans=0 -> Cm[m][10]; trans=1 -> Cm[e][1024] (transposed write for MgT).
// ---------------------------------------------------------------------------
__global__ __launch_bounds__(256)
void wchain_kernel(const float* __restrict__ A, const float* __restrict__ B,
                   float* __restrict__ Cm, int trans)
{
    const int wave = threadIdx.x >> 6, lane = threadIdx.x & 63;
    const int m = blockIdx.x * 4 + wave;
    float acc[NEXP];
#pragma unroll
    for (int e = 0; e < NEXP; ++e) acc[e] = 0.f;
    const float* ar = A + (size_t)m * 1024;
    for (int d = lane; d < 1024; d += 64) {
        float av = ar[d];
        const float* br = B + (size_t)d * NEXP;
#pragma unroll
        for (int e = 0; e < NEXP; ++e) acc[e] += av * br[e];
    }
#pragma unroll
    for (int e = 0; e < NEXP; ++e) {
        float v = acc[e];
        for (int off = 32; off > 0; off >>= 1) v += __shfl_down(v, off);
        if (lane == 0) Cm[trans ? ((size_t)e * 1024 + m) : ((size_t)m * NEXP + e)] = v;
    }
}

// ---------------------------------------------------------------------------
// bg_eff = bg + bo@Wg + bv@t1 + bp@t2    (single block)
// ---------------------------------------------------------------------------
__global__ __launch_bounds__(256)
void bias_eff_kernel(const float* __restrict__ bp, const float* __restrict__ bv,
                     const float* __restrict__ bo, const float* __restrict__ bg,
                     const float* __restrict__ Wg, const float* __restrict__ t1,
                     const float* __restrict__ t2, float* __restrict__ bgeff)
{
    __shared__ float red[256];
    const int tid = threadIdx.x;
    float acc[NEXP];
#pragma unroll
    for (int e = 0; e < NEXP; ++e) acc[e] = 0.f;
    for (int d = tid; d < 1024; d += 256) {
        float o = bo[d], v = bv[d], p = bp[d];
#pragma unroll
        for (int e = 0; e < NEXP; ++e)
            acc[e] += o * Wg[d * NEXP + e] + v * t1[d * NEXP + e] + p * t2[d * NEXP + e];
    }
    for (int e = 0; e < NEXP; ++e) {
        red[tid] = acc[e];
        __syncthreads();
        for (int s = 128; s > 0; s >>= 1) {
            if (tid < s) red[tid] += red[tid + s];
            __syncthreads();
        }
        if (tid == 0) bgeff[e] = red[0] + bg[e];
        __syncthreads();
    }
}

// ---------------------------------------------------------------------------
__global__ __launch_bounds__(256)
void init_kernel(int* __restrict__ counts, int* __restrict__ cursors,
                 int* __restrict__ assign_token, int* __restrict__ zrow_i,
                 float* __restrict__ fzero)
{
    int i = blockIdx.x * 256 + threadIdx.x;
    if (i < NEXP) { counts[i] = 0; cursors[i] = 0; }
    if (i < 512) zrow_i[i] = 0;                 // 1024 bf16 zeros
    if (i < 1024) fzero[i] = 0.f;               // fp32 zero bias for wt-product GEMMs
    if (i < A_CAP) assign_token[i] = -1;
}

__global__ void offsets_kernel(const int* __restrict__ counts, int* __restrict__ offs)
{
    if (threadIdx.x == 0 && blockIdx.x == 0) {
        int acc = 0;
        for (int e = 0; e < NEXP; ++e) {
            offs[e] = acc;
            acc += (counts[e] + EPAD - 1) / EPAD * EPAD;
        }
        offs[NEXP] = acc;
    }
}

// ---------------------------------------------------------------------------
// Scatter with WAVE-AGGREGATED cursor atomics (R6): <=10 atomics/wave via
// ballot+popcount vs 32768 contended return-value atomics before.
// ---------------------------------------------------------------------------
__global__ __launch_bounds__(256)
void scatter_kernel(const int* __restrict__ route_e,
                    const int* __restrict__ offs, int* __restrict__ cursors,
                    int* __restrict__ assign_token, int* __restrict__ slot_of)
{
    const int i = blockIdx.x * 256 + threadIdx.x;
    const int lane = threadIdx.x & 63;
    const int e = route_e[i];
    int slot = 0;
#pragma unroll
    for (int q = 0; q < NEXP; ++q) {
        unsigned long long mask = __ballot(e == q);
        if (e == q) {
            const int leader = (int)__ffsll((long long)mask) - 1;
            const int rank = (int)__popcll(mask & ((1ull << lane) - 1ull));
            int base = 0;
            if (lane == leader) base = atomicAdd(&cursors[q], (int)__popcll(mask));
            base = __shfl(base, leader);
            slot = offs[q] + base + rank;
        }
    }
    assign_token[slot] = i >> 1;
    slot_of[i] = slot;
}

// ---------------------------------------------------------------------------
// Combine (gather): out[n] = w0*(row(s0)+b2[e0]) + w1*(row(s1)+b2[e1])
// ---------------------------------------------------------------------------
__global__ __launch_bounds__(256)
void combine_kernel(const __hip_bfloat16* __restrict__ exp_out,
                    const int* __restrict__ slot_of, const int* __restrict__ route_e,
                    const float* __restrict__ route_w, const float* __restrict__ b2,
                    float* __restrict__ out)
{
    const int n = blockIdx.x;
    const int c = threadIdx.x * 4;
    const int s0 = slot_of[n * 2],  s1 = slot_of[n * 2 + 1];
    const int e0 = route_e[n * 2],  e1 = route_e[n * 2 + 1];
    const float w0 = route_w[n * 2], w1 = route_w[n * 2 + 1];

    union U { float2 f2; __hip_bfloat16 b[4]; } u0, u1;
    u0.f2 = *(const float2*)(exp_out + (size_t)s0 * D_OUT + c);
    u1.f2 = *(const float2*)(exp_out + (size_t)s1 * D_OUT + c);
    const float4 bb0 = *(const float4*)(b2 + (size_t)e0 * D_OUT + c);
    const float4 bb1 = *(const float4*)(b2 + (size_t)e1 * D_OUT + c);

    float4 o;
    o.x = w0 * (__bfloat162float(u0.b[0]) + bb0.x) + w1 * (__bfloat162float(u1.b[0]) + bb1.x);
    o.y = w0 * (__bfloat162float(u0.b[1]) + bb0.y) + w1 * (__bfloat162float(u1.b[1]) + bb1.y);
    o.z = w0 * (__bfloat162float(u0.b[2]) + bb0.z) + w1 * (__bfloat162float(u1.b[2]) + bb1.z);
    o.w = w0 * (__bfloat162float(u0.b[3]) + bb0.w) + w1 * (__bfloat162float(u1.b[3]) + bb1.w);
    *(float4*)(out + (size_t)n * D_OUT + c) = o;
}

// ---------------------------------------------------------------------------
extern "C" void kernel_launch(void* const* d_in, const int* in_sizes, int n_in,
                              void* d_out, int out_size, void* d_ws, size_t ws_size,
                              hipStream_t stream)
{
    const float* x  = (const float*)d_in[0];
    const float* Wp = (const float*)d_in[2];
    const float* bp = (const float*)d_in[3];
    const float* Wv = (const float*)d_in[4];
    const float* bv = (const float*)d_in[5];
    const float* Wo = (const float*)d_in[6];
    const float* bo = (const float*)d_in[7];
    const float* Wg = (const float*)d_in[8];
    const float* bg = (const float*)d_in[9];
    const float* W1 = (const float*)d_in[10];
    const float* b1 = (const float*)d_in[11];
    const float* W2 = (const float*)d_in[12];
    const float* b2 = (const float*)d_in[13];
    float* out = (float*)d_out;

    // ---- workspace layout (bytes); lifetime-based aliasing ----
    char* W = (char*)d_ws;
    typedef __hip_bfloat16 bf;
    bf* x_hi  = (bf*)(W + 0);                  // [N,D]  read by expert1 (gather)
    bf* x_lo  = (bf*)(W + 33554432);
    bf* exp_out = (bf*)(W + 0);                // [A_CAP,D_OUT] 69.7MB (post-expert1)
    bf* hid   = (bf*)(W + 69730304);           // [A_CAP,HID] ends ~87.2MB
    // weight-product scratch (88..100MB)
    bf* Wvr_hi = (bf*)(W + 88080384);          // Wv row-major hi/lo
    bf* Wvr_lo = (bf*)(W + 90177536);
    bf* Wpr_hi = (bf*)(W + 92274688);          // Wp row-major hi/lo
    bf* Wpr_lo = (bf*)(W + 94371840);
    float* fzero = (float*)(W + 96468992);     // 1024 fp32 zeros
    float* beff2 = (float*)(W + 96473088);     // folded main-chain bias [1024]
    // (100..117MB)
    bf* W1t_lo   = (bf*)(W + 100663296);       // [E][HID][D] lo plane (5.24MB)
    bf* W1eff_hi = (bf*)(W + 105906176);       // (M@W1[e])^T hi  [E][HID][D_IN]
    float* b1eff = (float*)(W + 116391936);    // [E][HID] fp32
    // weights / products (alive whole run)
    bf* Pt_hi  = (bf*)(W + 134217728);         // (Wv@Wo)^T hi/lo
    bf* Pt_lo  = (bf*)(W + 136314880);
    bf* Mrow_hi = (bf*)(W + 138412032);        // M = Wp@Wv@Wo ROW-major hi/lo
    bf* Mrow_lo = (bf*)(W + 140509184);
    bf* Wot_hi = (bf*)(W + 142606336);
    bf* Wot_lo = (bf*)(W + 144703488);
    bf* W1t    = (bf*)(W + 146800640);         // [E][HID][D] hi plane
    bf* W2t    = (bf*)(W + 152043520);         // [E][D_OUT][HID]
    // small buffers
    bf*    zrow         = (bf*)(W + 157286400);       // 1024 bf16 zeros
    int*   route_e      = (int*)(W + 157288448);
    float* route_w      = (float*)(W + 157419520);
    int*   slot_of      = (int*)(W + 157550592);
    int*   assign_token = (int*)(W + 157681664);
    int*   counts       = (int*)(W + 157817856);
    int*   offs         = (int*)(W + 157817920);
    int*   cursors      = (int*)(W + 157817984);
    float* MgT          = (float*)(W + 157818048);    // [10][1024] transposed
    float* t1           = (float*)(W + 157859008);
    float* t2           = (float*)(W + 157899968);
    float* bgeff        = (float*)(W + 157940928);

    dim3 blk(256);

    // ---- init first (zeros fzero used as bias by the product passes) ----
    init_kernel<<<(A_CAP + 255) / 256, blk, 0, stream>>>(counts, cursors, assign_token,
                                                         (int*)zrow, fzero);

    // ---- weight conversions ----
    transpose_cvt_kernel<<<dim3(32, 32, 1), blk, 0, stream>>>(Wo, Wot_hi, Wot_lo, D_MODEL, D_MODEL);
    convert_plain_kernel<<<1024, blk, 0, stream>>>(Wv, Wvr_hi, Wvr_lo);
    convert_plain_kernel<<<1024, blk, 0, stream>>>(Wp, Wpr_hi, Wpr_lo);
    transpose_cvt_kernel<<<dim3(HID / 32, D_MODEL / 32, NEXP), blk, 0, stream>>>(W1, W1t, W1t_lo, D_MODEL, HID);
    transpose_cvt_kernel<<<dim3(D_OUT / 32, HID / 32, NEXP), blk, 0, stream>>>(W2, W2t, nullptr, HID, D_OUT);

    // ---- gate matrix chain (fp32, exactness-preserving associativity) ----
    wchain_kernel<<<256, blk, 0, stream>>>(Wo, Wg, t1, 0);   // t1 = Wo@Wg
    wchain_kernel<<<256, blk, 0, stream>>>(Wv, t1, t2, 0);   // t2 = Wv@t1
    wchain_kernel<<<256, blk, 0, stream>>>(Wp, t2, MgT, 1);  // MgT = (Wp@t2)^T
    bias_eff_kernel<<<1, blk, 0, stream>>>(bp, bv, bo, bg, Wg, t1, t2, bgeff);

    // ---- weight-product passes (split-bf16, hi/lo outputs) ----
    dim3 pgrid(D_MODEL / 128, D_MODEL / 128, 1);   // (8, 8)
    // Pt[n][k] = (Wv@Wo)[k][n] :  A = Wot, Bt = Wv row-major
    gemm_split_kernel<<<pgrid, blk, 0, stream>>>(Wot_hi, Wot_lo, Wvr_hi, Wvr_lo, fzero,
                                                 Pt_hi, Pt_lo, D_MODEL, D_MODEL, 0, 0, 0);
    // Mrow[k'][k] = (Wp@Wv@Wo)[k'][k] :  A = Wp row-major, Bt = Pt
    gemm_split_kernel<<<pgrid, blk, 0, stream>>>(Wpr_hi, Wpr_lo, Pt_hi, Pt_lo, fzero,
                                                 Mrow_hi, Mrow_lo, D_MODEL, D_MODEL, 0, 0, 0);
    // folded main-chain bias: beff2 = bp@(Wv@Wo) + bv@Wo + bo
    bias2_kernel<<<D_MODEL / 4, blk, 0, stream>>>(bp, bv, bo, Pt_hi, Pt_lo,
                                                  Wot_hi, Wot_lo, beff2);
    // b1eff[e] = beff2@W1[e] + b1[e]
    b1eff_kernel<<<NEXP * HID / 4, blk, 0, stream>>>(beff2, W1t, W1t_lo, b1, b1eff);
    // W1eff_t[e][h][k'] = (M@W1[e])^T : A = W1t[e] (hi/lo), Bt = Mrow, z=e.
    // hi plane only (expert1 uses 2-term split).
    dim3 wgrid(D_IN / 128, HID / 128, NEXP);       // (8, 2, 10)
    gemm_split_kernel<<<wgrid, blk, 0, stream>>>(W1t, W1t_lo, Mrow_hi, Mrow_lo, fzero,
                                                 W1eff_hi, nullptr, D_MODEL, D_IN,
                                                 (size_t)HID * D_MODEL, 0,
                                                 (size_t)HID * D_IN);

    // ---- fused convert/gate (atomic-free) + count + scatter ----
    convert_gate_kernel<<<N_TOK / 4, blk, 0, stream>>>(x, MgT, bgeff, x_hi, x_lo,
                                                       route_e, route_w);
    count_kernel<<<2 * N_TOK / 512, blk, 0, stream>>>(route_e, counts);
    offsets_kernel<<<1, 64, 0, stream>>>(counts, offs);
    scatter_kernel<<<2 * N_TOK / 256, blk, 0, stream>>>(route_e, offs, cursors,
                                                        assign_token, slot_of);

    // ---- experts: layer1 2-term split on gathered x, 64-row tiles ----
    expert1_kernel<<<dim3(HID / 128, A_CAP / 64), blk, 0, stream>>>(
        x_hi, x_lo, W1eff_hi, b1eff, assign_token, offs, zrow, hid);
    expert2_kernel<<<dim3(D_OUT / 128, A_CAP / 128), blk, 0, stream>>>(
        hid, W2t, offs, exp_out);
    combine_kernel<<<N_TOK, blk, 0, stream>>>(exp_out, slot_of, route_e, route_w, b2, out);
}